// Round 1
// baseline (815.712 us; speedup 1.0000x reference)
//
#include <hip/hip_runtime.h>
#include <hip/hip_bf16.h>
#include <math.h>

#define B_   2
#define L_   2048
#define D_   1024
#define H_   16
#define DK_  64
#define T_   4
#define F_   4096
#define NTOK (B_ * L_)   // 4096

typedef __bf16 bf16_t;
typedef bf16_t bf16x8 __attribute__((ext_vector_type(8)));
typedef float  f32x4  __attribute__((ext_vector_type(4)));
typedef unsigned short u16;
typedef u16 u16x8 __attribute__((ext_vector_type(8)));

static __device__ __forceinline__ u16 f2b(float f) {
    __hip_bfloat16 h = __float2bfloat16(f);
    return *reinterpret_cast<u16*>(&h);
}
static __device__ __forceinline__ float b2f(u16 u) {
    __hip_bfloat16 h;
    *reinterpret_cast<u16*>(&h) = u;
    return __bfloat162float(h);
}

// async global->LDS, 16B per lane; LDS dest must be linear (uniform base + lane*16)
static __device__ __forceinline__ void gld16(void* lds, const void* g) {
    __builtin_amdgcn_global_load_lds(
        (const __attribute__((address_space(1))) unsigned int*)g,
        (__attribute__((address_space(3))) unsigned int*)lds,
        16, 0, 0);
}

// ---------------------------------------------------------------- cast x -> bf16
__global__ void k_cast_bf16(const float* __restrict__ in, u16* __restrict__ out, int n4) {
    int i = blockIdx.x * 256 + threadIdx.x;
    if (i >= n4) return;
    float4 v = reinterpret_cast<const float4*>(in)[i];
    ushort4 o;
    o.x = f2b(v.x); o.y = f2b(v.y); o.z = f2b(v.z); o.w = f2b(v.w);
    reinterpret_cast<ushort4*>(out)[i] = o;
}

// --------------------------------------------- transpose-cast W (KxN f32) -> Wt (NxK bf16)
__global__ void k_tcast(const float* __restrict__ W, u16* __restrict__ Wt,
                        int K, int N, long sW, long sWt) {
    __shared__ float tile[32][33];
    int z = blockIdx.z;
    W  += (long)z * sW;
    Wt += (long)z * sWt;
    int n0 = blockIdx.x * 32, k0 = blockIdx.y * 32;
    int tx = threadIdx.x, ty = threadIdx.y;   // block (32,8)
#pragma unroll
    for (int i = 0; i < 4; i++)
        tile[ty + 8 * i][tx] = W[(long)(k0 + ty + 8 * i) * N + n0 + tx];
    __syncthreads();
#pragma unroll
    for (int i = 0; i < 4; i++)
        Wt[(long)(n0 + ty + 8 * i) * K + k0 + tx] = f2b(tile[tx][ty + 8 * i]);
}

// ---------------------------------------------------------------- GEMM (m97 structure)
// C[M x N] = A[M x K] * Bt[N x K]^T ; 128x128 tile, BK=32, 4 waves (2x2 of 64x64)
enum { EP_BF16 = 0, EP_F32 = 1, EP_GELU_BF16 = 2, EP_BIAS_F32 = 3 };

template <int MODE, bool AIDX, bool CIDX, bool GROUPED>
__global__ __launch_bounds__(256)
void k_gemm(const u16* __restrict__ A, const u16* __restrict__ Bt,
            void* __restrict__ Cv, const float* __restrict__ bias,
            const int* __restrict__ idxb, const int* __restrict__ boff,
            const int* __restrict__ bcnt,
            int M, int K, int lda, int ldb, int ldc,
            long strideB, int biasStride)
{
    int p0 = 0, pend = M;
    if (GROUPED) {
        int t = blockIdx.z;
        int cnt = bcnt[t];
        if ((int)blockIdx.x * 128 >= cnt) return;
        p0 = boff[t]; pend = p0 + cnt;
        Bt += (long)t * strideB;
        bias += (long)t * biasStride;
    }
    const int tid = threadIdx.x;
    const int lane = tid & 63, wid = tid >> 6;
    const int wr = wid >> 1, wc = wid & 1;
    const int lg = lane >> 4, lr = lane & 15;

    __shared__ u16 sA[128 * 32];
    __shared__ u16 sB[128 * 32];

    const int kc = tid & 3;          // 16B chunk within a 64B row
    const int r0 = tid >> 2;         // row 0..63
    long ga0, ga1;
    {
        int pa0 = p0 + blockIdx.x * 128 + r0;
        int pa1 = pa0 + 64;
        if (GROUPED) { pa0 = min(pa0, pend - 1); pa1 = min(pa1, pend - 1); }
        ga0 = AIDX ? (long)idxb[pa0] : (long)pa0;
        ga1 = AIDX ? (long)idxb[pa1] : (long)pa1;
    }
    const u16* pA0 = A + ga0 * lda + kc * 8;
    const u16* pA1 = A + ga1 * lda + kc * 8;
    long nb = (long)blockIdx.y * 128 + r0;
    const u16* pB0 = Bt + nb * ldb + kc * 8;
    const u16* pB1 = Bt + (nb + 64) * ldb + kc * 8;

    const f32x4 zero = {0.f, 0.f, 0.f, 0.f};
    f32x4 acc[4][4];
#pragma unroll
    for (int m = 0; m < 4; m++)
#pragma unroll
        for (int n = 0; n < 4; n++) acc[m][n] = zero;

    u16* dA0 = sA + tid * 8;
    u16* dA1 = sA + (256 + tid) * 8;
    u16* dB0 = sB + tid * 8;
    u16* dB1 = sB + (256 + tid) * 8;

    for (int kk = 0; kk < K; kk += 32) {
        gld16(dA0, pA0); gld16(dA1, pA1);
        gld16(dB0, pB0); gld16(dB1, pB1);
        pA0 += 32; pA1 += 32; pB0 += 32; pB1 += 32;
        __syncthreads();
        bf16x8 a[4], b[4];
#pragma unroll
        for (int m = 0; m < 4; m++)
            a[m] = *reinterpret_cast<const bf16x8*>(sA + (wr * 64 + m * 16 + lr) * 32 + lg * 8);
#pragma unroll
        for (int n = 0; n < 4; n++)
            b[n] = *reinterpret_cast<const bf16x8*>(sB + (wc * 64 + n * 16 + lr) * 32 + lg * 8);
#pragma unroll
        for (int m = 0; m < 4; m++)
#pragma unroll
            for (int n = 0; n < 4; n++)
                acc[m][n] = __builtin_amdgcn_mfma_f32_16x16x32_bf16(a[m], b[n], acc[m][n], 0, 0, 0);
        __syncthreads();
    }

#pragma unroll
    for (int m = 0; m < 4; m++) {
#pragma unroll
        for (int r = 0; r < 4; r++) {
            int prow = p0 + blockIdx.x * 128 + wr * 64 + m * 16 + 4 * lg + r;
            if (GROUPED && prow >= pend) continue;
            long crow = CIDX ? (long)idxb[prow] : (long)prow;
#pragma unroll
            for (int n = 0; n < 4; n++) {
                int col = blockIdx.y * 128 + wc * 64 + n * 16 + lr;
                float v = acc[m][n][r];
                if (MODE == EP_GELU_BF16) {
                    v += bias[col];
                    v = 0.5f * v * (1.0f + erff(v * 0.70710678118654752f));
                }
                if (MODE == EP_BIAS_F32) v += bias[col];
                long off = crow * (long)ldc + col;
                if (MODE == EP_BF16 || MODE == EP_GELU_BF16)
                    ((u16*)Cv)[off] = f2b(v);
                else
                    ((float*)Cv)[off] = v;
            }
        }
    }
}

// ---------------------------------------------------------------- attention
// cat layout: [NTOK][4096] bf16 : cols [0,1024)=Q [1024,2048)=K [2048,3072)=V [3072,4096)=U
// block = (qtile of 64 rows, head, batch); 4 waves x 16 q-rows; KBLK=64
__global__ __launch_bounds__(256)
void k_attn(const u16* __restrict__ cat, const int* __restrict__ types,
            const int* __restrict__ seql, u16* __restrict__ AG)
{
    const int qt = blockIdx.x, h = blockIdx.y, b = blockIdx.z;
    const int tid = threadIdx.x, w = tid >> 6, lane = tid & 63;
    const int lg = lane >> 4, lr = lane & 15;
    const int qbase = qt * 64;

    __shared__ u16 sK[64 * 64];        // [key][dk]
    __shared__ u16 sV[64 * 64];        // transposed: [dk][key]
    __shared__ u16 sP[4 * 16 * 64];    // per-wave P tile [16][64]
    __shared__ unsigned long long smask[2];

    const int seqlen = seql[b];

    // Q fragments held in registers for the whole block
    const long qrow = (long)(b * L_ + qbase + w * 16 + lr);
    const u16* qp = cat + qrow * 4096 + h * 64;
    bf16x8 qf0 = *reinterpret_cast<const bf16x8*>(qp + lg * 8);
    bf16x8 qf1 = *reinterpret_cast<const bf16x8*>(qp + 32 + lg * 8);

    const f32x4 zero = {0.f, 0.f, 0.f, 0.f};
    f32x4 o[4] = {zero, zero, zero, zero};
    float mrow[4] = {-1e30f, -1e30f, -1e30f, -1e30f};
    float lsum[4] = {0.f, 0.f, 0.f, 0.f};

    for (int kb = 0; kb < L_; kb += 64) {
        if (kb >= seqlen) break;   // uniform per block (b fixed)
        // stage K tile (linear, async)
        {
            int c0 = tid, c1 = 256 + tid;
            gld16(sK + c0 * 8, cat + (long)(b * L_ + kb + (c0 >> 3)) * 4096 + 1024 + h * 64 + (c0 & 7) * 8);
            gld16(sK + c1 * 8, cat + (long)(b * L_ + kb + (c1 >> 3)) * 4096 + 1024 + h * 64 + (c1 & 7) * 8);
        }
        // stage V transposed (register path)
        {
            int key = tid & 63, dkb = (tid >> 6) * 16;
            const u16* vs = cat + (long)(b * L_ + kb + key) * 4096 + 2048 + h * 64 + dkb;
            u16x8 v0 = *reinterpret_cast<const u16x8*>(vs);
            u16x8 v1 = *reinterpret_cast<const u16x8*>(vs + 8);
#pragma unroll
            for (int e = 0; e < 8; e++) sV[(dkb + e) * 64 + key] = v0[e];
#pragma unroll
            for (int e = 0; e < 8; e++) sV[(dkb + 8 + e) * 64 + key] = v1[e];
        }
        // key masks: bit j = padded / prompt
        if (w == 0) {
            int j = kb + lane;
            bool pad = (j >= seqlen);
            bool prompt = types[b * L_ + j] < 3;
            unsigned long long pm = __ballot(pad);
            unsigned long long rm = __ballot(prompt);
            if (lane == 0) { smask[0] = pm; smask[1] = rm; }
        }
        __syncthreads();
        const unsigned long long padm = smask[0], prm = smask[1];

        // S = Q K^T  (16 q-rows x 64 keys per wave)
        f32x4 s[4];
#pragma unroll
        for (int n = 0; n < 4; n++) {
            bf16x8 bk0 = *reinterpret_cast<const bf16x8*>(sK + (n * 16 + lr) * 64 + lg * 8);
            bf16x8 bk1 = *reinterpret_cast<const bf16x8*>(sK + (n * 16 + lr) * 64 + 32 + lg * 8);
            f32x4 t4 = zero;
            t4 = __builtin_amdgcn_mfma_f32_16x16x32_bf16(qf0, bk0, t4, 0, 0, 0);
            t4 = __builtin_amdgcn_mfma_f32_16x16x32_bf16(qf1, bk1, t4, 0, 0, 0);
            s[n] = t4;
        }
        // mask + scale, tile row-max
        float tmax[4] = {-1e30f, -1e30f, -1e30f, -1e30f};
#pragma unroll
        for (int n = 0; n < 4; n++) {
            int jloc = n * 16 + lr;
            int jg = kb + jloc;
#pragma unroll
            for (int r = 0; r < 4; r++) {
                int ig = qbase + w * 16 + 4 * lg + r;
                bool dead = ((padm >> jloc) & 1ull) || (jg > ig && !((prm >> jloc) & 1ull));
                float sv = dead ? -1e30f : s[n][r] * 0.125f;
                s[n][r] = sv;
                tmax[r] = fmaxf(tmax[r], sv);
            }
        }
#pragma unroll
        for (int r = 0; r < 4; r++) {
#pragma unroll
            for (int d = 1; d < 16; d <<= 1)
                tmax[r] = fmaxf(tmax[r], __shfl_xor(tmax[r], d, 64));
        }
        float corr[4], rsum[4];
#pragma unroll
        for (int r = 0; r < 4; r++) {
            float mnew = fmaxf(mrow[r], tmax[r]);
            corr[r] = __expf(mrow[r] - mnew);
            mrow[r] = mnew;
            rsum[r] = 0.f;
        }
#pragma unroll
        for (int n = 0; n < 4; n++)
#pragma unroll
            for (int r = 0; r < 4; r++) {
                float p = __expf(s[n][r] - mrow[r]);
                s[n][r] = p;
                rsum[r] += p;
            }
#pragma unroll
        for (int r = 0; r < 4; r++) {
#pragma unroll
            for (int d = 1; d < 16; d <<= 1) rsum[r] += __shfl_xor(rsum[r], d, 64);
            lsum[r] = lsum[r] * corr[r] + rsum[r];
        }
#pragma unroll
        for (int n2 = 0; n2 < 4; n2++) {
            f32x4 t4 = o[n2];
#pragma unroll
            for (int r = 0; r < 4; r++) t4[r] *= corr[r];
            o[n2] = t4;
        }
        // P -> LDS (per-wave region; within-wave dependency, compiler inserts lgkmcnt)
        u16* Pw = sP + w * 1024;
#pragma unroll
        for (int n = 0; n < 4; n++)
#pragma unroll
            for (int r = 0; r < 4; r++)
                Pw[(4 * lg + r) * 64 + n * 16 + lr] = f2b(s[n][r]);
        // PV
        bf16x8 pa0 = *reinterpret_cast<const bf16x8*>(Pw + lr * 64 + lg * 8);
        bf16x8 pa1 = *reinterpret_cast<const bf16x8*>(Pw + lr * 64 + 32 + lg * 8);
#pragma unroll
        for (int n2 = 0; n2 < 4; n2++) {
            bf16x8 vb0 = *reinterpret_cast<const bf16x8*>(sV + (n2 * 16 + lr) * 64 + lg * 8);
            bf16x8 vb1 = *reinterpret_cast<const bf16x8*>(sV + (n2 * 16 + lr) * 64 + 32 + lg * 8);
            o[n2] = __builtin_amdgcn_mfma_f32_16x16x32_bf16(pa0, vb0, o[n2], 0, 0, 0);
            o[n2] = __builtin_amdgcn_mfma_f32_16x16x32_bf16(pa1, vb1, o[n2], 0, 0, 0);
        }
        __syncthreads();
    }
    // epilogue: normalize, U-gate, store bf16
#pragma unroll
    for (int n2 = 0; n2 < 4; n2++) {
#pragma unroll
        for (int r = 0; r < 4; r++) {
            int ig = qbase + w * 16 + 4 * lg + r;
            long orow = (long)(b * L_ + ig);
            int j = n2 * 16 + lr;
            float u = b2f(cat[orow * 4096 + 3072 + h * 64 + j]);
            float val = o[n2][r] / lsum[r] * u;
            AG[orow * 1024 + h * 64 + j] = f2b(val);
        }
    }
}

// ---------------------------------------------------------------- layernorm (per token)
template <bool WB>
__global__ __launch_bounds__(256)
void k_ln(const float* __restrict__ xa, const float* __restrict__ ha,
          const float* __restrict__ g, const float* __restrict__ bb,
          const int* __restrict__ types,
          float* __restrict__ of, u16* __restrict__ ob)
{
    const int tok = blockIdx.x, tid = threadIdx.x;
    const long base = (long)tok * D_;
    float4 va = reinterpret_cast<const float4*>(xa + base)[tid];
    float4 vh = reinterpret_cast<const float4*>(ha + base)[tid];
    float v0 = va.x + vh.x, v1 = va.y + vh.y, v2 = va.z + vh.z, v3 = va.w + vh.w;
    float s = v0 + v1 + v2 + v3;
    float ss = v0 * v0 + v1 * v1 + v2 * v2 + v3 * v3;
#pragma unroll
    for (int d = 1; d < 64; d <<= 1) { s += __shfl_xor(s, d, 64); ss += __shfl_xor(ss, d, 64); }
    __shared__ float red[8];
    if ((tid & 63) == 0) { red[tid >> 6] = s; red[4 + (tid >> 6)] = ss; }
    __syncthreads();
    s  = red[0] + red[1] + red[2] + red[3];
    ss = red[4] + red[5] + red[6] + red[7];
    const float mu  = s * (1.f / D_);
    const float var = ss * (1.f / D_) - mu * mu;
    const float inv = rsqrtf(var + 1e-5f);
    const int t = types[tok];
    const float* gp = g + (long)t * D_ + tid * 4;
    const float* bp = bb + (long)t * D_ + tid * 4;
    float o0 = (v0 - mu) * inv * gp[0] + bp[0];
    float o1 = (v1 - mu) * inv * gp[1] + bp[1];
    float o2 = (v2 - mu) * inv * gp[2] + bp[2];
    float o3 = (v3 - mu) * inv * gp[3] + bp[3];
    reinterpret_cast<float4*>(of + base)[tid] = make_float4(o0, o1, o2, o3);
    if (WB) {
        ushort4 u4;
        u4.x = f2b(o0); u4.y = f2b(o1); u4.z = f2b(o2); u4.w = f2b(o3);
        reinterpret_cast<ushort4*>(ob + base)[tid] = u4;
    }
}

// ---------------------------------------------------------------- token-type bucketing
__global__ void k_count(const int* __restrict__ types, int* __restrict__ cnt) {
    int i = blockIdx.x * 256 + threadIdx.x;
    if (i < NTOK) atomicAdd(&cnt[types[i]], 1);
}
__global__ void k_scan(int* __restrict__ base) {
    // base: cnt[4], off[4], cur[4]
    if (threadIdx.x == 0) {
        int a = 0;
        for (int t = 0; t < T_; t++) { base[4 + t] = a; base[8 + t] = a; a += base[t]; }
    }
}
__global__ void k_fill(const int* __restrict__ types, int* __restrict__ cur, int* __restrict__ idxb) {
    int i = blockIdx.x * 256 + threadIdx.x;
    if (i < NTOK) {
        int p = atomicAdd(&cur[types[i]], 1);
        idxb[p] = i;
    }
}

// ---------------------------------------------------------------- launch
extern "C" void kernel_launch(void* const* d_in, const int* in_sizes, int n_in,
                              void* d_out, int out_size, void* d_ws, size_t ws_size,
                              hipStream_t stream) {
    const float* x    = (const float*)d_in[0];
    const int* types  = (const int*)d_in[1];
    const int* seql   = (const int*)d_in[2];
    const float* Wq   = (const float*)d_in[3];
    const float* Wk   = (const float*)d_in[4];
    const float* Wv   = (const float*)d_in[5];
    const float* Wu   = (const float*)d_in[6];
    const float* Wo   = (const float*)d_in[7];
    const float* ln1g = (const float*)d_in[8];
    const float* ln1b = (const float*)d_in[9];
    const float* W1   = (const float*)d_in[10];
    const float* b1   = (const float*)d_in[11];
    const float* W2   = (const float*)d_in[12];
    const float* b2   = (const float*)d_in[13];
    const float* ln2g = (const float*)d_in[14];
    const float* ln2b = (const float*)d_in[15];

    char* ws = (char*)d_ws;
    constexpr size_t OFF_WT  = 0;                                   // QKVU^T cat [4096][1024] bf16
    constexpr size_t OFF_WOT = OFF_WT  + (size_t)4096 * 1024 * 2;   // Wo^T [1024][1024] bf16
    constexpr size_t OFF_W1T = OFF_WOT + (size_t)1024 * 1024 * 2;   // W1^T [T][4096][1024] bf16
    constexpr size_t OFF_W2T = OFF_W1T + (size_t)T_ * 4096 * 1024 * 2; // W2^T [T][1024][4096] bf16
    constexpr size_t OFF_XB  = OFF_W2T + (size_t)T_ * 4096 * 1024 * 2; // x bf16 (later: AG)
    constexpr size_t OFF_CAT = OFF_XB  + (size_t)NTOK * D_ * 2;     // QKVU cat (later: FFN hidden)
    constexpr size_t OFF_H   = OFF_CAT + (size_t)NTOK * 4096 * 2;   // h f32 (later: h2)
    constexpr size_t OFF_X1  = OFF_H   + (size_t)NTOK * D_ * 4;     // x1 f32
    constexpr size_t OFF_X1B = OFF_X1  + (size_t)NTOK * D_ * 4;     // x1 bf16
    constexpr size_t OFF_INT = OFF_X1B + (size_t)NTOK * D_ * 2;     // cnt/off/cur + idx

    u16* WT   = (u16*)(ws + OFF_WT);
    u16* WOT  = (u16*)(ws + OFF_WOT);
    u16* W1T  = (u16*)(ws + OFF_W1T);
    u16* W2T  = (u16*)(ws + OFF_W2T);
    u16* XB   = (u16*)(ws + OFF_XB);      // also AG
    u16* CAT  = (u16*)(ws + OFF_CAT);     // also Hidden
    float* Hb = (float*)(ws + OFF_H);
    float* X1 = (float*)(ws + OFF_X1);
    u16* X1B  = (u16*)(ws + OFF_X1B);
    int* ibase = (int*)(ws + OFF_INT);    // cnt[4] off[4] cur[4] pad[4] idx[4096]
    int* cnt = ibase, *off = ibase + 4, *cur = ibase + 8, *idxb = ibase + 16;

    dim3 blk(256), tb(32, 8);

    // 1. casts / transposes
    k_cast_bf16<<<NTOK * D_ / 4 / 256, blk, 0, stream>>>(x, XB, NTOK * D_ / 4);
    k_tcast<<<dim3(32, 32, 1), tb, 0, stream>>>(Wq, WT + 0 * 1048576, 1024, 1024, 0, 0);
    k_tcast<<<dim3(32, 32, 1), tb, 0, stream>>>(Wk, WT + 1 * 1048576, 1024, 1024, 0, 0);
    k_tcast<<<dim3(32, 32, 1), tb, 0, stream>>>(Wv, WT + 2 * 1048576, 1024, 1024, 0, 0);
    k_tcast<<<dim3(32, 32, 1), tb, 0, stream>>>(Wu, WT + 3 * 1048576, 1024, 1024, 0, 0);
    k_tcast<<<dim3(32, 32, 1), tb, 0, stream>>>(Wo, WOT, 1024, 1024, 0, 0);
    k_tcast<<<dim3(128, 32, T_), tb, 0, stream>>>(W1, W1T, 1024, 4096, (long)1024 * 4096, (long)4096 * 1024);
    k_tcast<<<dim3(32, 128, T_), tb, 0, stream>>>(W2, W2T, 4096, 1024, (long)4096 * 1024, (long)1024 * 4096);

    // 2. QKVU = x @ [Wq|Wk|Wv|Wu]   (M=4096 N=4096 K=1024)
    k_gemm<EP_BF16, false, false, false><<<dim3(32, 32), blk, 0, stream>>>(
        XB, WT, CAT, nullptr, nullptr, nullptr, nullptr, NTOK, 1024, 1024, 1024, 4096, 0, 0);

    // 3. attention -> gated output AG (reuses XB)
    k_attn<<<dim3(L_ / 64, H_, B_), blk, 0, stream>>>(CAT, types, seql, XB);

    // 4. h = AG @ Wo   (M=4096 N=1024 K=1024), f32
    k_gemm<EP_F32, false, false, false><<<dim3(32, 8), blk, 0, stream>>>(
        XB, WOT, Hb, nullptr, nullptr, nullptr, nullptr, NTOK, 1024, 1024, 1024, 1024, 0, 0);

    // 5. x1 = LN1(x + h)
    k_ln<true><<<NTOK, blk, 0, stream>>>(x, Hb, ln1g, ln1b, types, X1, X1B);

    // 6. bucket tokens by type
    hipMemsetAsync(cnt, 0, 48, stream);
    k_count<<<NTOK / 256, blk, 0, stream>>>(types, cnt);
    k_scan<<<1, 64, 0, stream>>>(ibase);
    k_fill<<<NTOK / 256, blk, 0, stream>>>(types, cur, idxb);

    // 7. Hidden = gelu(x1[idx] @ W1[t] + b1[t])   (grouped, A indexed, C by position)
    k_gemm<EP_GELU_BF16, true, false, true><<<dim3(32, 32, T_), blk, 0, stream>>>(
        X1B, W1T, CAT, b1, idxb, off, cnt, NTOK, 1024, 1024, 1024, 4096,
        (long)4096 * 1024, 4096);

    // 8. h2 = Hidden @ W2[t] + b2[t]  (grouped, A by position, C scattered to token rows)
    k_gemm<EP_BIAS_F32, false, true, true><<<dim3(32, 8, T_), blk, 0, stream>>>(
        CAT, W2T, Hb, b2, idxb, off, cnt, NTOK, 4096, 4096, 4096, 1024,
        (long)1024 * 4096, 1024);

    // 9. out = LN2(x1 + h2)
    k_ln<false><<<NTOK, blk, 0, stream>>>(X1, Hb, ln2g, ln2b, types, (float*)d_out, nullptr);
}

// Round 2
// 784.290 us; speedup vs baseline: 1.0401x; 1.0401x over previous
//
#include <hip/hip_runtime.h>
#include <hip/hip_bf16.h>
#include <math.h>

#define B_   2
#define L_   2048
#define D_   1024
#define H_   16
#define DK_  64
#define T_   4
#define F_   4096
#define NTOK (B_ * L_)   // 4096

typedef __bf16 bf16_t;
typedef bf16_t bf16x8 __attribute__((ext_vector_type(8)));
typedef float  f32x4  __attribute__((ext_vector_type(4)));
typedef unsigned short u16;
typedef u16 u16x8 __attribute__((ext_vector_type(8)));

static __device__ __forceinline__ u16 f2b(float f) {
    __hip_bfloat16 h = __float2bfloat16(f);
    return *reinterpret_cast<u16*>(&h);
}
static __device__ __forceinline__ float b2f(u16 u) {
    __hip_bfloat16 h;
    *reinterpret_cast<u16*>(&h) = u;
    return __bfloat162float(h);
}

// async global->LDS, 16B per lane; LDS dest must be linear (uniform base + lane*16)
static __device__ __forceinline__ void gld16(void* lds, const void* g) {
    __builtin_amdgcn_global_load_lds(
        (const __attribute__((address_space(1))) unsigned int*)g,
        (__attribute__((address_space(3))) unsigned int*)lds,
        16, 0, 0);
}

// ---------------------------------------------------------------- cast x -> bf16
__global__ void k_cast_bf16(const float* __restrict__ in, u16* __restrict__ out, int n4) {
    int i = blockIdx.x * 256 + threadIdx.x;
    if (i >= n4) return;
    float4 v = reinterpret_cast<const float4*>(in)[i];
    ushort4 o;
    o.x = f2b(v.x); o.y = f2b(v.y); o.z = f2b(v.z); o.w = f2b(v.w);
    reinterpret_cast<ushort4*>(out)[i] = o;
}

// --------------------------------------------- transpose-cast W (KxN f32) -> Wt (NxK bf16)
__global__ void k_tcast(const float* __restrict__ W, u16* __restrict__ Wt,
                        int K, int N, long sW, long sWt) {
    __shared__ float tile[32][33];
    int z = blockIdx.z;
    W  += (long)z * sW;
    Wt += (long)z * sWt;
    int n0 = blockIdx.x * 32, k0 = blockIdx.y * 32;
    int tx = threadIdx.x, ty = threadIdx.y;   // block (32,8)
#pragma unroll
    for (int i = 0; i < 4; i++)
        tile[ty + 8 * i][tx] = W[(long)(k0 + ty + 8 * i) * N + n0 + tx];
    __syncthreads();
#pragma unroll
    for (int i = 0; i < 4; i++)
        Wt[(long)(n0 + ty + 8 * i) * K + k0 + tx] = f2b(tile[tx][ty + 8 * i]);
}

// ---------------------------------------------------------------- GEMM
// C[M x N] = A[M x K] * Bt[N x K]^T ; 128x128 tile, BK=32, 4 waves (2x2 of 64x64)
// 2-phase double-buffered pipeline (T3 minimum): barrier -> issue STAGE(t+1) ->
// compute tile t. In-flight loads span the whole compute phase; one barrier/iter.
enum { EP_BF16 = 0, EP_F32 = 1, EP_GELU_BF16 = 2, EP_BIAS_F32 = 3 };

template <int MODE, bool AIDX, bool CIDX, bool GROUPED>
__global__ __launch_bounds__(256)
void k_gemm(const u16* __restrict__ A, const u16* __restrict__ Bt,
            void* __restrict__ Cv, const float* __restrict__ bias,
            const int* __restrict__ idxb, const int* __restrict__ boff,
            const int* __restrict__ bcnt,
            int M, int K, int lda, int ldb, int ldc,
            long strideB, int biasStride)
{
    int p0 = 0, pend = M;
    if (GROUPED) {
        int t = blockIdx.z;
        int cnt = bcnt[t];
        if ((int)blockIdx.x * 128 >= cnt) return;
        p0 = boff[t]; pend = p0 + cnt;
        Bt += (long)t * strideB;
        bias += (long)t * biasStride;
    }
    const int tid = threadIdx.x;
    const int lane = tid & 63, wid = tid >> 6;
    const int wr = wid >> 1, wc = wid & 1;
    const int lg = lane >> 4, lr = lane & 15;

    __shared__ u16 sA[2][128 * 32];
    __shared__ u16 sB[2][128 * 32];

    const int kc = tid & 3;          // 16B chunk within a 64B row
    const int r0 = tid >> 2;         // row 0..63
    long ga0, ga1;
    {
        int pa0 = p0 + blockIdx.x * 128 + r0;
        int pa1 = pa0 + 64;
        if (GROUPED) { pa0 = min(pa0, pend - 1); pa1 = min(pa1, pend - 1); }
        ga0 = AIDX ? (long)idxb[pa0] : (long)pa0;
        ga1 = AIDX ? (long)idxb[pa1] : (long)pa1;
    }
    const u16* pA0 = A + ga0 * lda + kc * 8;
    const u16* pA1 = A + ga1 * lda + kc * 8;
    long nb = (long)blockIdx.y * 128 + r0;
    const u16* pB0 = Bt + nb * ldb + kc * 8;
    const u16* pB1 = Bt + (nb + 64) * ldb + kc * 8;

    const f32x4 zero = {0.f, 0.f, 0.f, 0.f};
    f32x4 acc[4][4];
#pragma unroll
    for (int m = 0; m < 4; m++)
#pragma unroll
        for (int n = 0; n < 4; n++) acc[m][n] = zero;

    const int nt = K >> 5;

    // prologue: stage tile 0 into buffer 0
    gld16(sA[0] + tid * 8, pA0); gld16(sA[0] + (256 + tid) * 8, pA1);
    gld16(sB[0] + tid * 8, pB0); gld16(sB[0] + (256 + tid) * 8, pB1);
    pA0 += 32; pA1 += 32; pB0 += 32; pB1 += 32;

    for (int t = 0; t < nt; t++) {
        __syncthreads();   // vmcnt(0): buf[t&1] staged; prior reads of buf[(t+1)&1] drained
        const int cur = t & 1, nxt = cur ^ 1;
        if (t + 1 < nt) {  // issue next-tile stage; lands during this compute phase
            gld16(sA[nxt] + tid * 8, pA0); gld16(sA[nxt] + (256 + tid) * 8, pA1);
            gld16(sB[nxt] + tid * 8, pB0); gld16(sB[nxt] + (256 + tid) * 8, pB1);
            pA0 += 32; pA1 += 32; pB0 += 32; pB1 += 32;
        }
        bf16x8 a[4], b[4];
#pragma unroll
        for (int m = 0; m < 4; m++)
            a[m] = *reinterpret_cast<const bf16x8*>(sA[cur] + (wr * 64 + m * 16 + lr) * 32 + lg * 8);
#pragma unroll
        for (int n = 0; n < 4; n++)
            b[n] = *reinterpret_cast<const bf16x8*>(sB[cur] + (wc * 64 + n * 16 + lr) * 32 + lg * 8);
#pragma unroll
        for (int m = 0; m < 4; m++)
#pragma unroll
            for (int n = 0; n < 4; n++)
                acc[m][n] = __builtin_amdgcn_mfma_f32_16x16x32_bf16(a[m], b[n], acc[m][n], 0, 0, 0);
    }

#pragma unroll
    for (int m = 0; m < 4; m++) {
#pragma unroll
        for (int r = 0; r < 4; r++) {
            int prow = p0 + blockIdx.x * 128 + wr * 64 + m * 16 + 4 * lg + r;
            if (GROUPED && prow >= pend) continue;
            long crow = CIDX ? (long)idxb[prow] : (long)prow;
#pragma unroll
            for (int n = 0; n < 4; n++) {
                int col = blockIdx.y * 128 + wc * 64 + n * 16 + lr;
                float v = acc[m][n][r];
                if (MODE == EP_GELU_BF16) {
                    v += bias[col];
                    v = 0.5f * v * (1.0f + erff(v * 0.70710678118654752f));
                }
                if (MODE == EP_BIAS_F32) v += bias[col];
                long off = crow * (long)ldc + col;
                if (MODE == EP_BF16 || MODE == EP_GELU_BF16)
                    ((u16*)Cv)[off] = f2b(v);
                else
                    ((float*)Cv)[off] = v;
            }
        }
    }
}

// ---------------------------------------------------------------- attention
// cat layout: [NTOK][4096] bf16 : cols [0,1024)=Q [1024,2048)=K [2048,3072)=V [3072,4096)=U
// block = (qtile of 64 rows, head, batch); 4 waves x 16 q-rows; KBLK=64
__global__ __launch_bounds__(256)
void k_attn(const u16* __restrict__ cat, const int* __restrict__ types,
            const int* __restrict__ seql, u16* __restrict__ AG)
{
    const int qt = blockIdx.x, h = blockIdx.y, b = blockIdx.z;
    const int tid = threadIdx.x, w = tid >> 6, lane = tid & 63;
    const int lg = lane >> 4, lr = lane & 15;
    const int qbase = qt * 64;

    __shared__ u16 sK[64 * 64];        // [key][dk]
    __shared__ u16 sV[64 * 64];        // transposed: [dk][key]
    __shared__ u16 sP[4 * 16 * 64];    // per-wave P tile [16][64]
    __shared__ unsigned long long smask[2];

    const int seqlen = seql[b];

    // Q fragments held in registers for the whole block
    const long qrow = (long)(b * L_ + qbase + w * 16 + lr);
    const u16* qp = cat + qrow * 4096 + h * 64;
    bf16x8 qf0 = *reinterpret_cast<const bf16x8*>(qp + lg * 8);
    bf16x8 qf1 = *reinterpret_cast<const bf16x8*>(qp + 32 + lg * 8);

    const f32x4 zero = {0.f, 0.f, 0.f, 0.f};
    f32x4 o[4] = {zero, zero, zero, zero};
    float mrow[4] = {-1e30f, -1e30f, -1e30f, -1e30f};
    float lsum[4] = {0.f, 0.f, 0.f, 0.f};

    for (int kb = 0; kb < L_; kb += 64) {
        if (kb >= seqlen) break;   // uniform per block (b fixed)
        // stage K tile (linear, async)
        {
            int c0 = tid, c1 = 256 + tid;
            gld16(sK + c0 * 8, cat + (long)(b * L_ + kb + (c0 >> 3)) * 4096 + 1024 + h * 64 + (c0 & 7) * 8);
            gld16(sK + c1 * 8, cat + (long)(b * L_ + kb + (c1 >> 3)) * 4096 + 1024 + h * 64 + (c1 & 7) * 8);
        }
        // stage V transposed (register path)
        {
            int key = tid & 63, dkb = (tid >> 6) * 16;
            const u16* vs = cat + (long)(b * L_ + kb + key) * 4096 + 2048 + h * 64 + dkb;
            u16x8 v0 = *reinterpret_cast<const u16x8*>(vs);
            u16x8 v1 = *reinterpret_cast<const u16x8*>(vs + 8);
#pragma unroll
            for (int e = 0; e < 8; e++) sV[(dkb + e) * 64 + key] = v0[e];
#pragma unroll
            for (int e = 0; e < 8; e++) sV[(dkb + 8 + e) * 64 + key] = v1[e];
        }
        // key masks: bit j = padded / prompt
        if (w == 0) {
            int j = kb + lane;
            bool pad = (j >= seqlen);
            bool prompt = types[b * L_ + j] < 3;
            unsigned long long pm = __ballot(pad);
            unsigned long long rm = __ballot(prompt);
            if (lane == 0) { smask[0] = pm; smask[1] = rm; }
        }
        __syncthreads();
        const unsigned long long padm = smask[0], prm = smask[1];

        // S = Q K^T  (16 q-rows x 64 keys per wave)
        f32x4 s[4];
#pragma unroll
        for (int n = 0; n < 4; n++) {
            bf16x8 bk0 = *reinterpret_cast<const bf16x8*>(sK + (n * 16 + lr) * 64 + lg * 8);
            bf16x8 bk1 = *reinterpret_cast<const bf16x8*>(sK + (n * 16 + lr) * 64 + 32 + lg * 8);
            f32x4 t4 = zero;
            t4 = __builtin_amdgcn_mfma_f32_16x16x32_bf16(qf0, bk0, t4, 0, 0, 0);
            t4 = __builtin_amdgcn_mfma_f32_16x16x32_bf16(qf1, bk1, t4, 0, 0, 0);
            s[n] = t4;
        }
        // mask + scale, tile row-max
        float tmax[4] = {-1e30f, -1e30f, -1e30f, -1e30f};
#pragma unroll
        for (int n = 0; n < 4; n++) {
            int jloc = n * 16 + lr;
            int jg = kb + jloc;
#pragma unroll
            for (int r = 0; r < 4; r++) {
                int ig = qbase + w * 16 + 4 * lg + r;
                bool dead = ((padm >> jloc) & 1ull) || (jg > ig && !((prm >> jloc) & 1ull));
                float sv = dead ? -1e30f : s[n][r] * 0.125f;
                s[n][r] = sv;
                tmax[r] = fmaxf(tmax[r], sv);
            }
        }
#pragma unroll
        for (int r = 0; r < 4; r++) {
#pragma unroll
            for (int d = 1; d < 16; d <<= 1)
                tmax[r] = fmaxf(tmax[r], __shfl_xor(tmax[r], d, 64));
        }
        float corr[4], rsum[4];
#pragma unroll
        for (int r = 0; r < 4; r++) {
            float mnew = fmaxf(mrow[r], tmax[r]);
            corr[r] = __expf(mrow[r] - mnew);
            mrow[r] = mnew;
            rsum[r] = 0.f;
        }
#pragma unroll
        for (int n = 0; n < 4; n++)
#pragma unroll
            for (int r = 0; r < 4; r++) {
                float p = __expf(s[n][r] - mrow[r]);
                s[n][r] = p;
                rsum[r] += p;
            }
#pragma unroll
        for (int r = 0; r < 4; r++) {
#pragma unroll
            for (int d = 1; d < 16; d <<= 1) rsum[r] += __shfl_xor(rsum[r], d, 64);
            lsum[r] = lsum[r] * corr[r] + rsum[r];
        }
#pragma unroll
        for (int n2 = 0; n2 < 4; n2++) {
            f32x4 t4 = o[n2];
#pragma unroll
            for (int r = 0; r < 4; r++) t4[r] *= corr[r];
            o[n2] = t4;
        }
        // P -> LDS (per-wave region; within-wave dependency, compiler inserts lgkmcnt)
        u16* Pw = sP + w * 1024;
#pragma unroll
        for (int n = 0; n < 4; n++)
#pragma unroll
            for (int r = 0; r < 4; r++)
                Pw[(4 * lg + r) * 64 + n * 16 + lr] = f2b(s[n][r]);
        // PV
        bf16x8 pa0 = *reinterpret_cast<const bf16x8*>(Pw + lr * 64 + lg * 8);
        bf16x8 pa1 = *reinterpret_cast<const bf16x8*>(Pw + lr * 64 + 32 + lg * 8);
#pragma unroll
        for (int n2 = 0; n2 < 4; n2++) {
            bf16x8 vb0 = *reinterpret_cast<const bf16x8*>(sV + (n2 * 16 + lr) * 64 + lg * 8);
            bf16x8 vb1 = *reinterpret_cast<const bf16x8*>(sV + (n2 * 16 + lr) * 64 + 32 + lg * 8);
            o[n2] = __builtin_amdgcn_mfma_f32_16x16x32_bf16(pa0, vb0, o[n2], 0, 0, 0);
            o[n2] = __builtin_amdgcn_mfma_f32_16x16x32_bf16(pa1, vb1, o[n2], 0, 0, 0);
        }
        __syncthreads();
    }
    // epilogue: normalize, U-gate, store bf16
#pragma unroll
    for (int n2 = 0; n2 < 4; n2++) {
#pragma unroll
        for (int r = 0; r < 4; r++) {
            int ig = qbase + w * 16 + 4 * lg + r;
            long orow = (long)(b * L_ + ig);
            int j = n2 * 16 + lr;
            float u = b2f(cat[orow * 4096 + 3072 + h * 64 + j]);
            float val = o[n2][r] / lsum[r] * u;
            AG[orow * 1024 + h * 64 + j] = f2b(val);
        }
    }
}

// ---------------------------------------------------------------- layernorm (per token)
template <bool WB>
__global__ __launch_bounds__(256)
void k_ln(const float* __restrict__ xa, const float* __restrict__ ha,
          const float* __restrict__ g, const float* __restrict__ bb,
          const int* __restrict__ types,
          float* __restrict__ of, u16* __restrict__ ob)
{
    const int tok = blockIdx.x, tid = threadIdx.x;
    const long base = (long)tok * D_;
    float4 va = reinterpret_cast<const float4*>(xa + base)[tid];
    float4 vh = reinterpret_cast<const float4*>(ha + base)[tid];
    float v0 = va.x + vh.x, v1 = va.y + vh.y, v2 = va.z + vh.z, v3 = va.w + vh.w;
    float s = v0 + v1 + v2 + v3;
    float ss = v0 * v0 + v1 * v1 + v2 * v2 + v3 * v3;
#pragma unroll
    for (int d = 1; d < 64; d <<= 1) { s += __shfl_xor(s, d, 64); ss += __shfl_xor(ss, d, 64); }
    __shared__ float red[8];
    if ((tid & 63) == 0) { red[tid >> 6] = s; red[4 + (tid >> 6)] = ss; }
    __syncthreads();
    s  = red[0] + red[1] + red[2] + red[3];
    ss = red[4] + red[5] + red[6] + red[7];
    const float mu  = s * (1.f / D_);
    const float var = ss * (1.f / D_) - mu * mu;
    const float inv = rsqrtf(var + 1e-5f);
    const int t = types[tok];
    const float* gp = g + (long)t * D_ + tid * 4;
    const float* bp = bb + (long)t * D_ + tid * 4;
    float o0 = (v0 - mu) * inv * gp[0] + bp[0];
    float o1 = (v1 - mu) * inv * gp[1] + bp[1];
    float o2 = (v2 - mu) * inv * gp[2] + bp[2];
    float o3 = (v3 - mu) * inv * gp[3] + bp[3];
    reinterpret_cast<float4*>(of + base)[tid] = make_float4(o0, o1, o2, o3);
    if (WB) {
        ushort4 u4;
        u4.x = f2b(o0); u4.y = f2b(o1); u4.z = f2b(o2); u4.w = f2b(o3);
        reinterpret_cast<ushort4*>(ob + base)[tid] = u4;
    }
}

// ---------------------------------------------------------------- token-type bucketing
__global__ void k_count(const int* __restrict__ types, int* __restrict__ cnt) {
    int i = blockIdx.x * 256 + threadIdx.x;
    if (i < NTOK) atomicAdd(&cnt[types[i]], 1);
}
__global__ void k_scan(int* __restrict__ base) {
    // base: cnt[4], off[4], cur[4]
    if (threadIdx.x == 0) {
        int a = 0;
        for (int t = 0; t < T_; t++) { base[4 + t] = a; base[8 + t] = a; a += base[t]; }
    }
}
__global__ void k_fill(const int* __restrict__ types, int* __restrict__ cur, int* __restrict__ idxb) {
    int i = blockIdx.x * 256 + threadIdx.x;
    if (i < NTOK) {
        int p = atomicAdd(&cur[types[i]], 1);
        idxb[p] = i;
    }
}

// ---------------------------------------------------------------- launch
extern "C" void kernel_launch(void* const* d_in, const int* in_sizes, int n_in,
                              void* d_out, int out_size, void* d_ws, size_t ws_size,
                              hipStream_t stream) {
    const float* x    = (const float*)d_in[0];
    const int* types  = (const int*)d_in[1];
    const int* seql   = (const int*)d_in[2];
    const float* Wq   = (const float*)d_in[3];
    const float* Wk   = (const float*)d_in[4];
    const float* Wv   = (const float*)d_in[5];
    const float* Wu   = (const float*)d_in[6];
    const float* Wo   = (const float*)d_in[7];
    const float* ln1g = (const float*)d_in[8];
    const float* ln1b = (const float*)d_in[9];
    const float* W1   = (const float*)d_in[10];
    const float* b1   = (const float*)d_in[11];
    const float* W2   = (const float*)d_in[12];
    const float* b2   = (const float*)d_in[13];
    const float* ln2g = (const float*)d_in[14];
    const float* ln2b = (const float*)d_in[15];

    char* ws = (char*)d_ws;
    constexpr size_t OFF_WT  = 0;                                   // QKVU^T cat [4096][1024] bf16
    constexpr size_t OFF_WOT = OFF_WT  + (size_t)4096 * 1024 * 2;   // Wo^T [1024][1024] bf16
    constexpr size_t OFF_W1T = OFF_WOT + (size_t)1024 * 1024 * 2;   // W1^T [T][4096][1024] bf16
    constexpr size_t OFF_W2T = OFF_W1T + (size_t)T_ * 4096 * 1024 * 2; // W2^T [T][1024][4096] bf16
    constexpr size_t OFF_XB  = OFF_W2T + (size_t)T_ * 4096 * 1024 * 2; // x bf16 (later: AG)
    constexpr size_t OFF_CAT = OFF_XB  + (size_t)NTOK * D_ * 2;     // QKVU cat (later: FFN hidden)
    constexpr size_t OFF_H   = OFF_CAT + (size_t)NTOK * 4096 * 2;   // h f32 (later: h2)
    constexpr size_t OFF_X1  = OFF_H   + (size_t)NTOK * D_ * 4;     // x1 f32
    constexpr size_t OFF_X1B = OFF_X1  + (size_t)NTOK * D_ * 4;     // x1 bf16
    constexpr size_t OFF_INT = OFF_X1B + (size_t)NTOK * D_ * 2;     // cnt/off/cur + idx

    u16* WT   = (u16*)(ws + OFF_WT);
    u16* WOT  = (u16*)(ws + OFF_WOT);
    u16* W1T  = (u16*)(ws + OFF_W1T);
    u16* W2T  = (u16*)(ws + OFF_W2T);
    u16* XB   = (u16*)(ws + OFF_XB);      // also AG
    u16* CAT  = (u16*)(ws + OFF_CAT);     // also Hidden
    float* Hb = (float*)(ws + OFF_H);
    float* X1 = (float*)(ws + OFF_X1);
    u16* X1B  = (u16*)(ws + OFF_X1B);
    int* ibase = (int*)(ws + OFF_INT);    // cnt[4] off[4] cur[4] pad[4] idx[4096]
    int* cnt = ibase, *off = ibase + 4, *cur = ibase + 8, *idxb = ibase + 16;

    dim3 blk(256), tb(32, 8);

    // 1. casts / transposes
    k_cast_bf16<<<NTOK * D_ / 4 / 256, blk, 0, stream>>>(x, XB, NTOK * D_ / 4);
    k_tcast<<<dim3(32, 32, 1), tb, 0, stream>>>(Wq, WT + 0 * 1048576, 1024, 1024, 0, 0);
    k_tcast<<<dim3(32, 32, 1), tb, 0, stream>>>(Wk, WT + 1 * 1048576, 1024, 1024, 0, 0);
    k_tcast<<<dim3(32, 32, 1), tb, 0, stream>>>(Wv, WT + 2 * 1048576, 1024, 1024, 0, 0);
    k_tcast<<<dim3(32, 32, 1), tb, 0, stream>>>(Wu, WT + 3 * 1048576, 1024, 1024, 0, 0);
    k_tcast<<<dim3(32, 32, 1), tb, 0, stream>>>(Wo, WOT, 1024, 1024, 0, 0);
    k_tcast<<<dim3(128, 32, T_), tb, 0, stream>>>(W1, W1T, 1024, 4096, (long)1024 * 4096, (long)4096 * 1024);
    k_tcast<<<dim3(32, 128, T_), tb, 0, stream>>>(W2, W2T, 4096, 1024, (long)4096 * 1024, (long)1024 * 4096);

    // 2. QKVU = x @ [Wq|Wk|Wv|Wu]   (M=4096 N=4096 K=1024)
    k_gemm<EP_BF16, false, false, false><<<dim3(32, 32), blk, 0, stream>>>(
        XB, WT, CAT, nullptr, nullptr, nullptr, nullptr, NTOK, 1024, 1024, 1024, 4096, 0, 0);

    // 3. attention -> gated output AG (reuses XB)
    k_attn<<<dim3(L_ / 64, H_, B_), blk, 0, stream>>>(CAT, types, seql, XB);

    // 4. h = AG @ Wo   (M=4096 N=1024 K=1024), f32
    k_gemm<EP_F32, false, false, false><<<dim3(32, 8), blk, 0, stream>>>(
        XB, WOT, Hb, nullptr, nullptr, nullptr, nullptr, NTOK, 1024, 1024, 1024, 1024, 0, 0);

    // 5. x1 = LN1(x + h)
    k_ln<true><<<NTOK, blk, 0, stream>>>(x, Hb, ln1g, ln1b, types, X1, X1B);

    // 6. bucket tokens by type
    hipMemsetAsync(cnt, 0, 48, stream);
    k_count<<<NTOK / 256, blk, 0, stream>>>(types, cnt);
    k_scan<<<1, 64, 0, stream>>>(ibase);
    k_fill<<<NTOK / 256, blk, 0, stream>>>(types, cur, idxb);

    // 7. Hidden = gelu(x1[idx] @ W1[t] + b1[t])   (grouped, A indexed, C by position)
    k_gemm<EP_GELU_BF16, true, false, true><<<dim3(32, 32, T_), blk, 0, stream>>>(
        X1B, W1T, CAT, b1, idxb, off, cnt, NTOK, 1024, 1024, 1024, 4096,
        (long)4096 * 1024, 4096);

    // 8. h2 = Hidden @ W2[t] + b2[t]  (grouped, A by position, C scattered to token rows)
    k_gemm<EP_BIAS_F32, false, true, true><<<dim3(32, 8, T_), blk, 0, stream>>>(
        CAT, W2T, Hb, b2, idxb, off, cnt, NTOK, 4096, 4096, 4096, 1024,
        (long)1024 * 4096, 1024);

    // 9. out = LN2(x1 + h2)
    k_ln<false><<<NTOK, blk, 0, stream>>>(X1, Hb, ln2g, ln2b, types, (float*)d_out, nullptr);
}

// Round 3
// 714.371 us; speedup vs baseline: 1.1419x; 1.0979x over previous
//
#include <hip/hip_runtime.h>
#include <hip/hip_bf16.h>
#include <math.h>

#define B_   2
#define L_   2048
#define D_   1024
#define H_   16
#define DK_  64
#define T_   4
#define F_   4096
#define NTOK (B_ * L_)   // 4096

typedef __bf16 bf16_t;
typedef bf16_t bf16x8 __attribute__((ext_vector_type(8)));
typedef float  f32x4  __attribute__((ext_vector_type(4)));
typedef unsigned short u16;
typedef u16 u16x8 __attribute__((ext_vector_type(8)));

static __device__ __forceinline__ u16 f2b(float f) {
    __hip_bfloat16 h = __float2bfloat16(f);
    return *reinterpret_cast<u16*>(&h);
}
static __device__ __forceinline__ float b2f(u16 u) {
    __hip_bfloat16 h;
    *reinterpret_cast<u16*>(&h) = u;
    return __bfloat162float(h);
}

// async global->LDS (still used by attention only)
static __device__ __forceinline__ void gld16(void* lds, const void* g) {
    __builtin_amdgcn_global_load_lds(
        (const __attribute__((address_space(1))) unsigned int*)g,
        (__attribute__((address_space(3))) unsigned int*)lds,
        16, 0, 0);
}

#define LGKM0() asm volatile("s_waitcnt lgkmcnt(0)" ::: "memory")
#define BAR()   do { __builtin_amdgcn_sched_barrier(0); \
                     __builtin_amdgcn_s_barrier();      \
                     __builtin_amdgcn_sched_barrier(0); } while (0)

// ---------------------------------------------------------------- cast x -> bf16
__global__ void k_cast_bf16(const float* __restrict__ in, u16* __restrict__ out, int n4) {
    int i = blockIdx.x * 256 + threadIdx.x;
    if (i >= n4) return;
    float4 v = reinterpret_cast<const float4*>(in)[i];
    ushort4 o;
    o.x = f2b(v.x); o.y = f2b(v.y); o.z = f2b(v.z); o.w = f2b(v.w);
    reinterpret_cast<ushort4*>(out)[i] = o;
}

// --------------------------------------------- transpose-cast W (KxN f32) -> Wt (NxK bf16)
__global__ void k_tcast(const float* __restrict__ W, u16* __restrict__ Wt,
                        int K, int N, long sW, long sWt) {
    __shared__ float tile[32][33];
    int z = blockIdx.z;
    W  += (long)z * sW;
    Wt += (long)z * sWt;
    int n0 = blockIdx.x * 32, k0 = blockIdx.y * 32;
    int tx = threadIdx.x, ty = threadIdx.y;   // block (32,8)
#pragma unroll
    for (int i = 0; i < 4; i++)
        tile[ty + 8 * i][tx] = W[(long)(k0 + ty + 8 * i) * N + n0 + tx];
    __syncthreads();
#pragma unroll
    for (int i = 0; i < 4; i++)
        Wt[(long)(n0 + ty + 8 * i) * K + k0 + tx] = f2b(tile[tx][ty + 8 * i]);
}

// ---------------------------------------------------------------- GEMM
// C[M x N] = A[M x K] * Bt[N x K]^T ; 128x128 tile, BK=32, 4 waves (2x2 of 64x64).
// Register-staged distance-2 pipeline: loads for tile t+2 are issued while tile t
// computes; ds_write lands them one iteration later. Raw s_barrier + lgkmcnt(0)
// only -- NO vmcnt(0) drain in the main loop (compiler emits counted vmcnt(4)
// before each ds_write for its own register dependencies).
enum { EP_BF16 = 0, EP_F32 = 1, EP_GELU_BF16 = 2, EP_BIAS_F32 = 3 };

template <int MODE, bool AIDX, bool CIDX, bool GROUPED>
__global__ __launch_bounds__(256, 2)
void k_gemm(const u16* __restrict__ A, const u16* __restrict__ Bt,
            void* __restrict__ Cv, const float* __restrict__ bias,
            const int* __restrict__ idxb, const int* __restrict__ boff,
            const int* __restrict__ bcnt,
            int M, int K, int lda, int ldb, int ldc,
            long strideB, int biasStride)
{
    int p0 = 0, pend = M;
    if (GROUPED) {
        int t = blockIdx.z;
        int cnt = bcnt[t];
        if ((int)blockIdx.x * 128 >= cnt) return;
        p0 = boff[t]; pend = p0 + cnt;
        Bt += (long)t * strideB;
        bias += (long)t * biasStride;
    }
    const int tid = threadIdx.x;
    const int lane = tid & 63, wid = tid >> 6;
    const int wr = wid >> 1, wc = wid & 1;
    const int lg = lane >> 4, lr = lane & 15;

    // statically named buffers: provably distinct objects for alias analysis
    __shared__ u16 sA0[128 * 32];
    __shared__ u16 sB0[128 * 32];
    __shared__ u16 sA1[128 * 32];
    __shared__ u16 sB1[128 * 32];

    const int kc = tid & 3;          // 16B chunk within a 64B row
    const int r0 = tid >> 2;         // row 0..63
    long ga0, ga1;
    {
        int pa0 = p0 + blockIdx.x * 128 + r0;
        int pa1 = pa0 + 64;
        if (GROUPED) { pa0 = min(pa0, pend - 1); pa1 = min(pa1, pend - 1); }
        ga0 = AIDX ? (long)idxb[pa0] : (long)pa0;
        ga1 = AIDX ? (long)idxb[pa1] : (long)pa1;
    }
    const u16* pA0 = A + ga0 * lda + kc * 8;
    const u16* pA1 = A + ga1 * lda + kc * 8;
    long nb = (long)blockIdx.y * 128 + r0;
    const u16* pB0 = Bt + nb * ldb + kc * 8;
    const u16* pB1 = Bt + (nb + 64) * ldb + kc * 8;

    const f32x4 zero = {0.f, 0.f, 0.f, 0.f};
    f32x4 acc[4][4];
#pragma unroll
    for (int m = 0; m < 4; m++)
#pragma unroll
        for (int n = 0; n < 4; n++) acc[m][n] = zero;

    struct Rt { u16x8 a0, a1, b0, b1; };
    auto LOADT = [&]() {
        Rt r;
        r.a0 = *reinterpret_cast<const u16x8*>(pA0);
        r.a1 = *reinterpret_cast<const u16x8*>(pA1);
        r.b0 = *reinterpret_cast<const u16x8*>(pB0);
        r.b1 = *reinterpret_cast<const u16x8*>(pB1);
        pA0 += 32; pA1 += 32; pB0 += 32; pB1 += 32;
        return r;
    };
    auto DSW = [&](u16* bA, u16* bB, const Rt& r) {
        *reinterpret_cast<u16x8*>(bA + tid * 8) = r.a0;
        *reinterpret_cast<u16x8*>(bA + (256 + tid) * 8) = r.a1;
        *reinterpret_cast<u16x8*>(bB + tid * 8) = r.b0;
        *reinterpret_cast<u16x8*>(bB + (256 + tid) * 8) = r.b1;
    };
    auto COMPUTE = [&](const u16* bA, const u16* bB) {
        bf16x8 a[4], b[4];
#pragma unroll
        for (int m = 0; m < 4; m++)
            a[m] = *reinterpret_cast<const bf16x8*>(bA + (wr * 64 + m * 16 + lr) * 32 + lg * 8);
#pragma unroll
        for (int n = 0; n < 4; n++)
            b[n] = *reinterpret_cast<const bf16x8*>(bB + (wc * 64 + n * 16 + lr) * 32 + lg * 8);
#pragma unroll
        for (int m = 0; m < 4; m++)
#pragma unroll
            for (int n = 0; n < 4; n++)
                acc[m][n] = __builtin_amdgcn_mfma_f32_16x16x32_bf16(a[m], b[n], acc[m][n], 0, 0, 0);
    };

    const int nt = K >> 5;            // 32 or 128 -- always even here

    // prologue: tile0 -> b0; tile1 stays in flight in rX
    Rt rX = LOADT();                  // tile 0
    DSW(sA0, sB0, rX);                // (one-time vmcnt(0) here is fine)
    rX = LOADT();                     // tile 1, in flight
    LGKM0(); BAR();                   // b0 visible to all waves

    for (int i = 0; i < nt / 2 - 1; i++) {
        Rt rY = LOADT();              // tile 2i+2 (consumed next half-iter's DSW)
        COMPUTE(sA0, sB0);            // tile 2i
        BAR();                        // all waves done reading b1 (prev iter)
        DSW(sA1, sB1, rX);            // tile 2i+1; compiler waits vmcnt for rX only
        LGKM0(); BAR();               // b1 ready
        rX = LOADT();                 // tile 2i+3
        COMPUTE(sA1, sB1);            // tile 2i+1
        BAR();                        // all waves done reading b0
        DSW(sA0, sB0, rY);            // tile 2i+2
        LGKM0(); BAR();               // b0 ready
    }
    // tail: tiles nt-2 (in b0) and nt-1 (in rX -> b1)
    COMPUTE(sA0, sB0);                // tile nt-2
    BAR();
    DSW(sA1, sB1, rX);                // tile nt-1
    LGKM0(); BAR();
    COMPUTE(sA1, sB1);                // tile nt-1

#pragma unroll
    for (int m = 0; m < 4; m++) {
#pragma unroll
        for (int r = 0; r < 4; r++) {
            int prow = p0 + blockIdx.x * 128 + wr * 64 + m * 16 + 4 * lg + r;
            if (GROUPED && prow >= pend) continue;
            long crow = CIDX ? (long)idxb[prow] : (long)prow;
#pragma unroll
            for (int n = 0; n < 4; n++) {
                int col = blockIdx.y * 128 + wc * 64 + n * 16 + lr;
                float v = acc[m][n][r];
                if (MODE == EP_GELU_BF16) {
                    v += bias[col];
                    v = 0.5f * v * (1.0f + erff(v * 0.70710678118654752f));
                }
                if (MODE == EP_BIAS_F32) v += bias[col];
                long off = crow * (long)ldc + col;
                if (MODE == EP_BF16 || MODE == EP_GELU_BF16)
                    ((u16*)Cv)[off] = f2b(v);
                else
                    ((float*)Cv)[off] = v;
            }
        }
    }
}

// ---------------------------------------------------------------- attention
// cat layout: [NTOK][4096] bf16 : cols [0,1024)=Q [1024,2048)=K [2048,3072)=V [3072,4096)=U
// block = (qtile of 64 rows, head, batch); 4 waves x 16 q-rows; KBLK=64
__global__ __launch_bounds__(256)
void k_attn(const u16* __restrict__ cat, const int* __restrict__ types,
            const int* __restrict__ seql, u16* __restrict__ AG)
{
    const int qt = blockIdx.x, h = blockIdx.y, b = blockIdx.z;
    const int tid = threadIdx.x, w = tid >> 6, lane = tid & 63;
    const int lg = lane >> 4, lr = lane & 15;
    const int qbase = qt * 64;

    __shared__ u16 sK[64 * 64];        // [key][dk]
    __shared__ u16 sV[64 * 64];        // transposed: [dk][key]
    __shared__ u16 sP[4 * 16 * 64];    // per-wave P tile [16][64]
    __shared__ unsigned long long smask[2];

    const int seqlen = seql[b];

    // Q fragments held in registers for the whole block
    const long qrow = (long)(b * L_ + qbase + w * 16 + lr);
    const u16* qp = cat + qrow * 4096 + h * 64;
    bf16x8 qf0 = *reinterpret_cast<const bf16x8*>(qp + lg * 8);
    bf16x8 qf1 = *reinterpret_cast<const bf16x8*>(qp + 32 + lg * 8);

    const f32x4 zero = {0.f, 0.f, 0.f, 0.f};
    f32x4 o[4] = {zero, zero, zero, zero};
    float mrow[4] = {-1e30f, -1e30f, -1e30f, -1e30f};
    float lsum[4] = {0.f, 0.f, 0.f, 0.f};

    for (int kb = 0; kb < L_; kb += 64) {
        if (kb >= seqlen) break;   // uniform per block (b fixed)
        // stage K tile (linear, async)
        {
            int c0 = tid, c1 = 256 + tid;
            gld16(sK + c0 * 8, cat + (long)(b * L_ + kb + (c0 >> 3)) * 4096 + 1024 + h * 64 + (c0 & 7) * 8);
            gld16(sK + c1 * 8, cat + (long)(b * L_ + kb + (c1 >> 3)) * 4096 + 1024 + h * 64 + (c1 & 7) * 8);
        }
        // stage V transposed (register path)
        {
            int key = tid & 63, dkb = (tid >> 6) * 16;
            const u16* vs = cat + (long)(b * L_ + kb + key) * 4096 + 2048 + h * 64 + dkb;
            u16x8 v0 = *reinterpret_cast<const u16x8*>(vs);
            u16x8 v1 = *reinterpret_cast<const u16x8*>(vs + 8);
#pragma unroll
            for (int e = 0; e < 8; e++) sV[(dkb + e) * 64 + key] = v0[e];
#pragma unroll
            for (int e = 0; e < 8; e++) sV[(dkb + 8 + e) * 64 + key] = v1[e];
        }
        // key masks: bit j = padded / prompt
        if (w == 0) {
            int j = kb + lane;
            bool pad = (j >= seqlen);
            bool prompt = types[b * L_ + j] < 3;
            unsigned long long pm = __ballot(pad);
            unsigned long long rm = __ballot(prompt);
            if (lane == 0) { smask[0] = pm; smask[1] = rm; }
        }
        __syncthreads();
        const unsigned long long padm = smask[0], prm = smask[1];

        // S = Q K^T  (16 q-rows x 64 keys per wave)
        f32x4 s[4];
#pragma unroll
        for (int n = 0; n < 4; n++) {
            bf16x8 bk0 = *reinterpret_cast<const bf16x8*>(sK + (n * 16 + lr) * 64 + lg * 8);
            bf16x8 bk1 = *reinterpret_cast<const bf16x8*>(sK + (n * 16 + lr) * 64 + 32 + lg * 8);
            f32x4 t4 = zero;
            t4 = __builtin_amdgcn_mfma_f32_16x16x32_bf16(qf0, bk0, t4, 0, 0, 0);
            t4 = __builtin_amdgcn_mfma_f32_16x16x32_bf16(qf1, bk1, t4, 0, 0, 0);
            s[n] = t4;
        }
        // mask + scale, tile row-max
        float tmax[4] = {-1e30f, -1e30f, -1e30f, -1e30f};
#pragma unroll
        for (int n = 0; n < 4; n++) {
            int jloc = n * 16 + lr;
            int jg = kb + jloc;
#pragma unroll
            for (int r = 0; r < 4; r++) {
                int ig = qbase + w * 16 + 4 * lg + r;
                bool dead = ((padm >> jloc) & 1ull) || (jg > ig && !((prm >> jloc) & 1ull));
                float sv = dead ? -1e30f : s[n][r] * 0.125f;
                s[n][r] = sv;
                tmax[r] = fmaxf(tmax[r], sv);
            }
        }
#pragma unroll
        for (int r = 0; r < 4; r++) {
#pragma unroll
            for (int d = 1; d < 16; d <<= 1)
                tmax[r] = fmaxf(tmax[r], __shfl_xor(tmax[r], d, 64));
        }
        float corr[4], rsum[4];
#pragma unroll
        for (int r = 0; r < 4; r++) {
            float mnew = fmaxf(mrow[r], tmax[r]);
            corr[r] = __expf(mrow[r] - mnew);
            mrow[r] = mnew;
            rsum[r] = 0.f;
        }
#pragma unroll
        for (int n = 0; n < 4; n++)
#pragma unroll
            for (int r = 0; r < 4; r++) {
                float p = __expf(s[n][r] - mrow[r]);
                s[n][r] = p;
                rsum[r] += p;
            }
#pragma unroll
        for (int r = 0; r < 4; r++) {
#pragma unroll
            for (int d = 1; d < 16; d <<= 1) rsum[r] += __shfl_xor(rsum[r], d, 64);
            lsum[r] = lsum[r] * corr[r] + rsum[r];
        }
#pragma unroll
        for (int n2 = 0; n2 < 4; n2++) {
            f32x4 t4 = o[n2];
#pragma unroll
            for (int r = 0; r < 4; r++) t4[r] *= corr[r];
            o[n2] = t4;
        }
        // P -> LDS (per-wave region; within-wave dependency, compiler inserts lgkmcnt)
        u16* Pw = sP + w * 1024;
#pragma unroll
        for (int n = 0; n < 4; n++)
#pragma unroll
            for (int r = 0; r < 4; r++)
                Pw[(4 * lg + r) * 64 + n * 16 + lr] = f2b(s[n][r]);
        // PV
        bf16x8 pa0 = *reinterpret_cast<const bf16x8*>(Pw + lr * 64 + lg * 8);
        bf16x8 pa1 = *reinterpret_cast<const bf16x8*>(Pw + lr * 64 + 32 + lg * 8);
#pragma unroll
        for (int n2 = 0; n2 < 4; n2++) {
            bf16x8 vb0 = *reinterpret_cast<const bf16x8*>(sV + (n2 * 16 + lr) * 64 + lg * 8);
            bf16x8 vb1 = *reinterpret_cast<const bf16x8*>(sV + (n2 * 16 + lr) * 64 + 32 + lg * 8);
            o[n2] = __builtin_amdgcn_mfma_f32_16x16x32_bf16(pa0, vb0, o[n2], 0, 0, 0);
            o[n2] = __builtin_amdgcn_mfma_f32_16x16x32_bf16(pa1, vb1, o[n2], 0, 0, 0);
        }
        __syncthreads();
    }
    // epilogue: normalize, U-gate, store bf16
#pragma unroll
    for (int n2 = 0; n2 < 4; n2++) {
#pragma unroll
        for (int r = 0; r < 4; r++) {
            int ig = qbase + w * 16 + 4 * lg + r;
            long orow = (long)(b * L_ + ig);
            int j = n2 * 16 + lr;
            float u = b2f(cat[orow * 4096 + 3072 + h * 64 + j]);
            float val = o[n2][r] / lsum[r] * u;
            AG[orow * 1024 + h * 64 + j] = f2b(val);
        }
    }
}

// ---------------------------------------------------------------- layernorm (per token)
template <bool WB>
__global__ __launch_bounds__(256)
void k_ln(const float* __restrict__ xa, const float* __restrict__ ha,
          const float* __restrict__ g, const float* __restrict__ bb,
          const int* __restrict__ types,
          float* __restrict__ of, u16* __restrict__ ob)
{
    const int tok = blockIdx.x, tid = threadIdx.x;
    const long base = (long)tok * D_;
    float4 va = reinterpret_cast<const float4*>(xa + base)[tid];
    float4 vh = reinterpret_cast<const float4*>(ha + base)[tid];
    float v0 = va.x + vh.x, v1 = va.y + vh.y, v2 = va.z + vh.z, v3 = va.w + vh.w;
    float s = v0 + v1 + v2 + v3;
    float ss = v0 * v0 + v1 * v1 + v2 * v2 + v3 * v3;
#pragma unroll
    for (int d = 1; d < 64; d <<= 1) { s += __shfl_xor(s, d, 64); ss += __shfl_xor(ss, d, 64); }
    __shared__ float red[8];
    if ((tid & 63) == 0) { red[tid >> 6] = s; red[4 + (tid >> 6)] = ss; }
    __syncthreads();
    s  = red[0] + red[1] + red[2] + red[3];
    ss = red[4] + red[5] + red[6] + red[7];
    const float mu  = s * (1.f / D_);
    const float var = ss * (1.f / D_) - mu * mu;
    const float inv = rsqrtf(var + 1e-5f);
    const int t = types[tok];
    const float* gp = g + (long)t * D_ + tid * 4;
    const float* bp = bb + (long)t * D_ + tid * 4;
    float o0 = (v0 - mu) * inv * gp[0] + bp[0];
    float o1 = (v1 - mu) * inv * gp[1] + bp[1];
    float o2 = (v2 - mu) * inv * gp[2] + bp[2];
    float o3 = (v3 - mu) * inv * gp[3] + bp[3];
    reinterpret_cast<float4*>(of + base)[tid] = make_float4(o0, o1, o2, o3);
    if (WB) {
        ushort4 u4;
        u4.x = f2b(o0); u4.y = f2b(o1); u4.z = f2b(o2); u4.w = f2b(o3);
        reinterpret_cast<ushort4*>(ob + base)[tid] = u4;
    }
}

// ---------------------------------------------------------------- token-type bucketing
__global__ void k_count(const int* __restrict__ types, int* __restrict__ cnt) {
    int i = blockIdx.x * 256 + threadIdx.x;
    if (i < NTOK) atomicAdd(&cnt[types[i]], 1);
}
__global__ void k_scan(int* __restrict__ base) {
    // base: cnt[4], off[4], cur[4]
    if (threadIdx.x == 0) {
        int a = 0;
        for (int t = 0; t < T_; t++) { base[4 + t] = a; base[8 + t] = a; a += base[t]; }
    }
}
__global__ void k_fill(const int* __restrict__ types, int* __restrict__ cur, int* __restrict__ idxb) {
    int i = blockIdx.x * 256 + threadIdx.x;
    if (i < NTOK) {
        int p = atomicAdd(&cur[types[i]], 1);
        idxb[p] = i;
    }
}

// ---------------------------------------------------------------- launch
extern "C" void kernel_launch(void* const* d_in, const int* in_sizes, int n_in,
                              void* d_out, int out_size, void* d_ws, size_t ws_size,
                              hipStream_t stream) {
    const float* x    = (const float*)d_in[0];
    const int* types  = (const int*)d_in[1];
    const int* seql   = (const int*)d_in[2];
    const float* Wq   = (const float*)d_in[3];
    const float* Wk   = (const float*)d_in[4];
    const float* Wv   = (const float*)d_in[5];
    const float* Wu   = (const float*)d_in[6];
    const float* Wo   = (const float*)d_in[7];
    const float* ln1g = (const float*)d_in[8];
    const float* ln1b = (const float*)d_in[9];
    const float* W1   = (const float*)d_in[10];
    const float* b1   = (const float*)d_in[11];
    const float* W2   = (const float*)d_in[12];
    const float* b2   = (const float*)d_in[13];
    const float* ln2g = (const float*)d_in[14];
    const float* ln2b = (const float*)d_in[15];

    char* ws = (char*)d_ws;
    constexpr size_t OFF_WT  = 0;                                   // QKVU^T cat [4096][1024] bf16
    constexpr size_t OFF_WOT = OFF_WT  + (size_t)4096 * 1024 * 2;   // Wo^T [1024][1024] bf16
    constexpr size_t OFF_W1T = OFF_WOT + (size_t)1024 * 1024 * 2;   // W1^T [T][4096][1024] bf16
    constexpr size_t OFF_W2T = OFF_W1T + (size_t)T_ * 4096 * 1024 * 2; // W2^T [T][1024][4096] bf16
    constexpr size_t OFF_XB  = OFF_W2T + (size_t)T_ * 4096 * 1024 * 2; // x bf16 (later: AG)
    constexpr size_t OFF_CAT = OFF_XB  + (size_t)NTOK * D_ * 2;     // QKVU cat (later: FFN hidden)
    constexpr size_t OFF_H   = OFF_CAT + (size_t)NTOK * 4096 * 2;   // h f32 (later: h2)
    constexpr size_t OFF_X1  = OFF_H   + (size_t)NTOK * D_ * 4;     // x1 f32
    constexpr size_t OFF_X1B = OFF_X1  + (size_t)NTOK * D_ * 4;     // x1 bf16
    constexpr size_t OFF_INT = OFF_X1B + (size_t)NTOK * D_ * 2;     // cnt/off/cur + idx

    u16* WT   = (u16*)(ws + OFF_WT);
    u16* WOT  = (u16*)(ws + OFF_WOT);
    u16* W1T  = (u16*)(ws + OFF_W1T);
    u16* W2T  = (u16*)(ws + OFF_W2T);
    u16* XB   = (u16*)(ws + OFF_XB);      // also AG
    u16* CAT  = (u16*)(ws + OFF_CAT);     // also Hidden
    float* Hb = (float*)(ws + OFF_H);
    float* X1 = (float*)(ws + OFF_X1);
    u16* X1B  = (u16*)(ws + OFF_X1B);
    int* ibase = (int*)(ws + OFF_INT);    // cnt[4] off[4] cur[4] pad[4] idx[4096]
    int* cnt = ibase, *off = ibase + 4, *cur = ibase + 8, *idxb = ibase + 16;

    dim3 blk(256), tb(32, 8);

    // 1. casts / transposes
    k_cast_bf16<<<NTOK * D_ / 4 / 256, blk, 0, stream>>>(x, XB, NTOK * D_ / 4);
    k_tcast<<<dim3(32, 32, 1), tb, 0, stream>>>(Wq, WT + 0 * 1048576, 1024, 1024, 0, 0);
    k_tcast<<<dim3(32, 32, 1), tb, 0, stream>>>(Wk, WT + 1 * 1048576, 1024, 1024, 0, 0);
    k_tcast<<<dim3(32, 32, 1), tb, 0, stream>>>(Wv, WT + 2 * 1048576, 1024, 1024, 0, 0);
    k_tcast<<<dim3(32, 32, 1), tb, 0, stream>>>(Wu, WT + 3 * 1048576, 1024, 1024, 0, 0);
    k_tcast<<<dim3(32, 32, 1), tb, 0, stream>>>(Wo, WOT, 1024, 1024, 0, 0);
    k_tcast<<<dim3(128, 32, T_), tb, 0, stream>>>(W1, W1T, 1024, 4096, (long)1024 * 4096, (long)4096 * 1024);
    k_tcast<<<dim3(32, 128, T_), tb, 0, stream>>>(W2, W2T, 4096, 1024, (long)4096 * 1024, (long)1024 * 4096);

    // 2. QKVU = x @ [Wq|Wk|Wv|Wu]   (M=4096 N=4096 K=1024)
    k_gemm<EP_BF16, false, false, false><<<dim3(32, 32), blk, 0, stream>>>(
        XB, WT, CAT, nullptr, nullptr, nullptr, nullptr, NTOK, 1024, 1024, 1024, 4096, 0, 0);

    // 3. attention -> gated output AG (reuses XB)
    k_attn<<<dim3(L_ / 64, H_, B_), blk, 0, stream>>>(CAT, types, seql, XB);

    // 4. h = AG @ Wo   (M=4096 N=1024 K=1024), f32
    k_gemm<EP_F32, false, false, false><<<dim3(32, 8), blk, 0, stream>>>(
        XB, WOT, Hb, nullptr, nullptr, nullptr, nullptr, NTOK, 1024, 1024, 1024, 1024, 0, 0);

    // 5. x1 = LN1(x + h)
    k_ln<true><<<NTOK, blk, 0, stream>>>(x, Hb, ln1g, ln1b, types, X1, X1B);

    // 6. bucket tokens by type
    hipMemsetAsync(cnt, 0, 48, stream);
    k_count<<<NTOK / 256, blk, 0, stream>>>(types, cnt);
    k_scan<<<1, 64, 0, stream>>>(ibase);
    k_fill<<<NTOK / 256, blk, 0, stream>>>(types, cur, idxb);

    // 7. Hidden = gelu(x1[idx] @ W1[t] + b1[t])   (grouped, A indexed, C by position)
    k_gemm<EP_GELU_BF16, true, false, true><<<dim3(32, 32, T_), blk, 0, stream>>>(
        X1B, W1T, CAT, b1, idxb, off, cnt, NTOK, 1024, 1024, 1024, 4096,
        (long)4096 * 1024, 4096);

    // 8. h2 = Hidden @ W2[t] + b2[t]  (grouped, A by position, C scattered to token rows)
    k_gemm<EP_BIAS_F32, false, true, true><<<dim3(32, 8, T_), blk, 0, stream>>>(
        CAT, W2T, Hb, b2, idxb, off, cnt, NTOK, 4096, 4096, 4096, 1024,
        (long)1024 * 4096, 1024);

    // 9. out = LN2(x1 + h2)
    k_ln<false><<<NTOK, blk, 0, stream>>>(X1, Hb, ln2g, ln2b, types, (float*)d_out, nullptr);
}

// Round 4
// 669.152 us; speedup vs baseline: 1.2190x; 1.0676x over previous
//
#include <hip/hip_runtime.h>
#include <hip/hip_bf16.h>
#include <math.h>

#define B_   2
#define L_   2048
#define D_   1024
#define H_   16
#define DK_  64
#define T_   4
#define F_   4096
#define NTOK (B_ * L_)   // 4096

typedef __bf16 bf16_t;
typedef bf16_t bf16x8 __attribute__((ext_vector_type(8)));
typedef float  f32x4  __attribute__((ext_vector_type(4)));
typedef unsigned short u16;
typedef u16 u16x8 __attribute__((ext_vector_type(8)));

static __device__ __forceinline__ u16 f2b(float f) {
    __hip_bfloat16 h = __float2bfloat16(f);
    return *reinterpret_cast<u16*>(&h);
}
static __device__ __forceinline__ float b2f(u16 u) {
    __hip_bfloat16 h;
    *reinterpret_cast<u16*>(&h) = u;
    return __bfloat162float(h);
}

// async global->LDS, 16B per lane; LDS dest must be linear (uniform base + lane*16)
static __device__ __forceinline__ void gld16(void* lds, const void* g) {
    __builtin_amdgcn_global_load_lds(
        (const __attribute__((address_space(1))) unsigned int*)g,
        (__attribute__((address_space(3))) unsigned int*)lds,
        16, 0, 0);
}

#define VMW(N) do { asm volatile("s_waitcnt vmcnt(" #N ")" ::: "memory"); \
                    __builtin_amdgcn_sched_barrier(0); } while (0)
#define BARR() do { __builtin_amdgcn_sched_barrier(0); \
                    __builtin_amdgcn_s_barrier();      \
                    __builtin_amdgcn_sched_barrier(0); } while (0)

// ---------------------------------------------------------------- cast x -> bf16
__global__ void k_cast_bf16(const float* __restrict__ in, u16* __restrict__ out, int n4) {
    int i = blockIdx.x * 256 + threadIdx.x;
    if (i >= n4) return;
    float4 v = reinterpret_cast<const float4*>(in)[i];
    ushort4 o;
    o.x = f2b(v.x); o.y = f2b(v.y); o.z = f2b(v.z); o.w = f2b(v.w);
    reinterpret_cast<ushort4*>(out)[i] = o;
}

// --------------------------------------------- transpose-cast W (KxN f32) -> Wt (NxK bf16)
__global__ void k_tcast(const float* __restrict__ W, u16* __restrict__ Wt,
                        int K, int N, long sW, long sWt) {
    __shared__ float tile[32][33];
    int z = blockIdx.z;
    W  += (long)z * sW;
    Wt += (long)z * sWt;
    int n0 = blockIdx.x * 32, k0 = blockIdx.y * 32;
    int tx = threadIdx.x, ty = threadIdx.y;   // block (32,8)
#pragma unroll
    for (int i = 0; i < 4; i++)
        tile[ty + 8 * i][tx] = W[(long)(k0 + ty + 8 * i) * N + n0 + tx];
    __syncthreads();
#pragma unroll
    for (int i = 0; i < 4; i++)
        Wt[(long)(n0 + ty + 8 * i) * K + k0 + tx] = f2b(tile[tx][ty + 8 * i]);
}

// ---------------------------------------------------------------- 256x256 8-wave GEMM
// C[M x N] = A[M x K] * Bt[N x K]^T ; BM=BN=256, BK=32, 512 threads (8 waves, 2x4).
// LDS: 2 buffers x 4 regions (A0,A1,B0,B1) x 8KB = 64 KB.
// Phase (qa,qb): ALL waves compute C-quadrant (qa*128, qb*128) from A-half qa,
// B-half qb only -> halves are phase-localized. Ring staging: one half of tile
// t+1 per phase (A0@q0, B0@q1, B1@q2, A1@q3) into the other buffer; counted
// s_waitcnt vmcnt(3) per phase (the needed half is the 4th-youngest in flight);
// drain 2/1/0 only in the peeled last tile. LDS chunk-XOR swizzle (chunk ^= row&3)
// applied on the pre-swizzled GLOBAL source (gld_lds writes linearly) and on the
// ds_read address.
enum { EP_BF16 = 0, EP_F32 = 1, EP_GELU_BF16 = 2, EP_BIAS_F32 = 3 };

#define PHASE(QA, QB) do {                                                        \
    const u16* Ah_ = ldsb + (QA) * 4096;                                          \
    const u16* Bh_ = ldsb + (2 + (QB)) * 4096;                                    \
    bf16x8 av[4], bv[2];                                                          \
    _Pragma("unroll")                                                             \
    for (int mfi = 0; mfi < 4; mfi++)                                             \
        av[mfi] = *reinterpret_cast<const bf16x8*>(                               \
            Ah_ + (wr2 * 64 + mfi * 16 + lr) * 32 + achnk);                       \
    _Pragma("unroll")                                                             \
    for (int nfi = 0; nfi < 2; nfi++)                                             \
        bv[nfi] = *reinterpret_cast<const bf16x8*>(                               \
            Bh_ + (wc2 * 32 + nfi * 16 + lr) * 32 + achnk);                       \
    __builtin_amdgcn_s_setprio(1);                                                \
    _Pragma("unroll")                                                             \
    for (int mfi = 0; mfi < 4; mfi++)                                             \
        _Pragma("unroll")                                                         \
        for (int nfi = 0; nfi < 2; nfi++)                                         \
            acc[QA][QB][mfi][nfi] = __builtin_amdgcn_mfma_f32_16x16x32_bf16(      \
                av[mfi], bv[nfi], acc[QA][QB][mfi][nfi], 0, 0, 0);                \
    __builtin_amdgcn_s_setprio(0);                                                \
} while (0)

template <int MODE, bool AIDX, bool CIDX, bool GROUPED>
__global__ __launch_bounds__(512, 2)
void k_gemm256(const u16* __restrict__ A, const u16* __restrict__ Bt,
               void* __restrict__ Cv, const float* __restrict__ bias,
               const int* __restrict__ idxb, const int* __restrict__ boff,
               const int* __restrict__ bcnt,
               int M, int K, int lda, int ldb, int ldc,
               long strideB, int biasStride)
{
    int p0 = 0, pend = M;
    if (GROUPED) {
        int z = blockIdx.z;
        int c = bcnt[z];
        p0 = boff[z]; pend = p0 + c;
        Bt += (long)z * strideB;
        bias += (long)z * biasStride;
    }
    // XCD-bijective block swizzle (m204), column-major tile walk
    const int gx = gridDim.x;
    const int nwg = gx * gridDim.y;
    const int id = blockIdx.y * gx + blockIdx.x;
    const int q8 = nwg >> 3, r8 = nwg & 7, xcd = id & 7, sub = id >> 3;
    const int id2 = (xcd < r8 ? xcd * (q8 + 1) : r8 * (q8 + 1) + (xcd - r8) * q8) + sub;
    const int tm = id2 % gx, tn = id2 / gx;
    if (GROUPED && tm * 256 >= (pend - p0)) return;
    const int bm = tm * 256, bn = tn * 256;

    const int tid = threadIdx.x;
    const int wid = tid >> 6, lane = tid & 63;
    const int lg = lane >> 4, lr = lane & 15;
    const int wr2 = wid >> 2, wc2 = wid & 3;      // 2x4 wave grid within a quadrant
    const int achnk = (lg ^ (lr & 3)) * 8;        // swizzled 16B chunk (u16 units)

    __shared__ u16 lds[8 * 4096];                 // 8 regions x 8KB

    // ---- staging pointers (hoisted; per-lane, source pre-swizzled) ----
    const int srow = tid >> 2;                    // 0..127
    const int schunk = (tid & 3) ^ (srow & 3);    // inverse (=same) chunk swizzle
    long ra0, ra1;
    {
        int pa0 = p0 + bm + srow, pa1 = p0 + bm + 128 + srow;
        if (GROUPED) { pa0 = min(pa0, pend - 1); pa1 = min(pa1, pend - 1); }
        ra0 = AIDX ? (long)idxb[pa0] : (long)pa0;
        ra1 = AIDX ? (long)idxb[pa1] : (long)pa1;
    }
    const u16* gA0 = A + ra0 * lda + schunk * 8;
    const u16* gA1 = A + ra1 * lda + schunk * 8;
    const u16* gB0 = Bt + (long)(bn + srow) * ldb + schunk * 8;
    const u16* gB1 = Bt + (long)(bn + 128 + srow) * ldb + schunk * 8;
    u16* const dA0 = lds + tid * 8;               // region offsets added per buf
    const int R = 4096;                           // region stride (u16)

    const f32x4 zero = {0.f, 0.f, 0.f, 0.f};
    f32x4 acc[2][2][4][2];
#pragma unroll
    for (int qa = 0; qa < 2; qa++)
#pragma unroll
        for (int qb = 0; qb < 2; qb++)
#pragma unroll
            for (int m = 0; m < 4; m++)
#pragma unroll
                for (int n = 0; n < 2; n++) acc[qa][qb][m][n] = zero;

    const int NT = K >> 5;

    // prologue: tile 0 -> buf0, ring order A0,B0,B1,A1
    gld16(dA0 + 0 * R, gA0);
    gld16(dA0 + 2 * R, gB0);
    gld16(dA0 + 3 * R, gB1);
    gld16(dA0 + 1 * R, gA1);

    for (int t = 0; t < NT - 1; t++) {
        const int buf = t & 1;
        const u16* ldsb = lds + buf * 4 * R;
        u16* dstn = dA0 + (buf ^ 1) * 4 * R;
        const long ko = (long)(t + 1) * 32;

        gld16(dstn + 0 * R, gA0 + ko);
        VMW(3); BARR();
        PHASE(0, 0);
        BARR();

        gld16(dstn + 2 * R, gB0 + ko);
        VMW(3); BARR();
        PHASE(0, 1);
        BARR();

        gld16(dstn + 3 * R, gB1 + ko);
        VMW(3); BARR();
        PHASE(1, 0);
        BARR();

        gld16(dstn + 1 * R, gA1 + ko);
        VMW(3); BARR();
        PHASE(1, 1);
        BARR();
    }
    {   // peeled last tile: no staging; draining counted waits
        const u16* ldsb = lds + ((NT - 1) & 1) * 4 * R;
        VMW(2); BARR();
        PHASE(0, 0);
        BARR();
        VMW(1); BARR();
        PHASE(0, 1);
        BARR();
        VMW(0); BARR();
        PHASE(1, 0);
        BARR();
        PHASE(1, 1);
    }

    // ---- epilogue ----
#pragma unroll
    for (int qa = 0; qa < 2; qa++) {
#pragma unroll
        for (int mfi = 0; mfi < 4; mfi++) {
#pragma unroll
            for (int r = 0; r < 4; r++) {
                int prow = p0 + bm + qa * 128 + wr2 * 64 + mfi * 16 + lg * 4 + r;
                if (GROUPED && prow >= pend) continue;
                long crow = CIDX ? (long)idxb[prow] : (long)prow;
#pragma unroll
                for (int qb = 0; qb < 2; qb++) {
#pragma unroll
                    for (int nfi = 0; nfi < 2; nfi++) {
                        int gn = bn + qb * 128 + wc2 * 32 + nfi * 16 + lr;
                        float v = acc[qa][qb][mfi][nfi][r];
                        if (MODE == EP_GELU_BF16) {
                            v += bias[gn];
                            v = 0.5f * v * (1.0f + erff(v * 0.70710678118654752f));
                        }
                        if (MODE == EP_BIAS_F32) v += bias[gn];
                        long off = crow * (long)ldc + gn;
                        if (MODE == EP_BF16 || MODE == EP_GELU_BF16)
                            ((u16*)Cv)[off] = f2b(v);
                        else
                            ((float*)Cv)[off] = v;
                    }
                }
            }
        }
    }
}

// ---------------------------------------------------------------- attention
// cat layout: [NTOK][4096] bf16 : cols [0,1024)=Q [1024,2048)=K [2048,3072)=V [3072,4096)=U
// block = (qtile of 64 rows, head, batch); 4 waves x 16 q-rows; KBLK=64
__global__ __launch_bounds__(256)
void k_attn(const u16* __restrict__ cat, const int* __restrict__ types,
            const int* __restrict__ seql, u16* __restrict__ AG)
{
    const int qt = blockIdx.x, h = blockIdx.y, b = blockIdx.z;
    const int tid = threadIdx.x, w = tid >> 6, lane = tid & 63;
    const int lg = lane >> 4, lr = lane & 15;
    const int qbase = qt * 64;

    __shared__ u16 sK[64 * 64];        // [key][dk]
    __shared__ u16 sV[64 * 64];        // transposed: [dk][key]
    __shared__ u16 sP[4 * 16 * 64];    // per-wave P tile [16][64]
    __shared__ unsigned long long smask[2];

    const int seqlen = seql[b];

    const long qrow = (long)(b * L_ + qbase + w * 16 + lr);
    const u16* qp = cat + qrow * 4096 + h * 64;
    bf16x8 qf0 = *reinterpret_cast<const bf16x8*>(qp + lg * 8);
    bf16x8 qf1 = *reinterpret_cast<const bf16x8*>(qp + 32 + lg * 8);

    const f32x4 zero = {0.f, 0.f, 0.f, 0.f};
    f32x4 o[4] = {zero, zero, zero, zero};
    float mrow[4] = {-1e30f, -1e30f, -1e30f, -1e30f};
    float lsum[4] = {0.f, 0.f, 0.f, 0.f};

    for (int kb = 0; kb < L_; kb += 64) {
        if (kb >= seqlen) break;   // uniform per block (b fixed)
        {
            int c0 = tid, c1 = 256 + tid;
            gld16(sK + c0 * 8, cat + (long)(b * L_ + kb + (c0 >> 3)) * 4096 + 1024 + h * 64 + (c0 & 7) * 8);
            gld16(sK + c1 * 8, cat + (long)(b * L_ + kb + (c1 >> 3)) * 4096 + 1024 + h * 64 + (c1 & 7) * 8);
        }
        {
            int key = tid & 63, dkb = (tid >> 6) * 16;
            const u16* vs = cat + (long)(b * L_ + kb + key) * 4096 + 2048 + h * 64 + dkb;
            u16x8 v0 = *reinterpret_cast<const u16x8*>(vs);
            u16x8 v1 = *reinterpret_cast<const u16x8*>(vs + 8);
#pragma unroll
            for (int e = 0; e < 8; e++) sV[(dkb + e) * 64 + key] = v0[e];
#pragma unroll
            for (int e = 0; e < 8; e++) sV[(dkb + 8 + e) * 64 + key] = v1[e];
        }
        if (w == 0) {
            int j = kb + lane;
            bool pad = (j >= seqlen);
            bool prompt = types[b * L_ + j] < 3;
            unsigned long long pm = __ballot(pad);
            unsigned long long rm = __ballot(prompt);
            if (lane == 0) { smask[0] = pm; smask[1] = rm; }
        }
        __syncthreads();
        const unsigned long long padm = smask[0], prm = smask[1];

        f32x4 s[4];
#pragma unroll
        for (int n = 0; n < 4; n++) {
            bf16x8 bk0 = *reinterpret_cast<const bf16x8*>(sK + (n * 16 + lr) * 64 + lg * 8);
            bf16x8 bk1 = *reinterpret_cast<const bf16x8*>(sK + (n * 16 + lr) * 64 + 32 + lg * 8);
            f32x4 t4 = zero;
            t4 = __builtin_amdgcn_mfma_f32_16x16x32_bf16(qf0, bk0, t4, 0, 0, 0);
            t4 = __builtin_amdgcn_mfma_f32_16x16x32_bf16(qf1, bk1, t4, 0, 0, 0);
            s[n] = t4;
        }
        float tmax[4] = {-1e30f, -1e30f, -1e30f, -1e30f};
#pragma unroll
        for (int n = 0; n < 4; n++) {
            int jloc = n * 16 + lr;
            int jg = kb + jloc;
#pragma unroll
            for (int r = 0; r < 4; r++) {
                int ig = qbase + w * 16 + 4 * lg + r;
                bool dead = ((padm >> jloc) & 1ull) || (jg > ig && !((prm >> jloc) & 1ull));
                float sv = dead ? -1e30f : s[n][r] * 0.125f;
                s[n][r] = sv;
                tmax[r] = fmaxf(tmax[r], sv);
            }
        }
#pragma unroll
        for (int r = 0; r < 4; r++) {
#pragma unroll
            for (int d = 1; d < 16; d <<= 1)
                tmax[r] = fmaxf(tmax[r], __shfl_xor(tmax[r], d, 64));
        }
        float corr[4], rsum[4];
#pragma unroll
        for (int r = 0; r < 4; r++) {
            float mnew = fmaxf(mrow[r], tmax[r]);
            corr[r] = __expf(mrow[r] - mnew);
            mrow[r] = mnew;
            rsum[r] = 0.f;
        }
#pragma unroll
        for (int n = 0; n < 4; n++)
#pragma unroll
            for (int r = 0; r < 4; r++) {
                float p = __expf(s[n][r] - mrow[r]);
                s[n][r] = p;
                rsum[r] += p;
            }
#pragma unroll
        for (int r = 0; r < 4; r++) {
#pragma unroll
            for (int d = 1; d < 16; d <<= 1) rsum[r] += __shfl_xor(rsum[r], d, 64);
            lsum[r] = lsum[r] * corr[r] + rsum[r];
        }
#pragma unroll
        for (int n2 = 0; n2 < 4; n2++) {
            f32x4 t4 = o[n2];
#pragma unroll
            for (int r = 0; r < 4; r++) t4[r] *= corr[r];
            o[n2] = t4;
        }
        u16* Pw = sP + w * 1024;
#pragma unroll
        for (int n = 0; n < 4; n++)
#pragma unroll
            for (int r = 0; r < 4; r++)
                Pw[(4 * lg + r) * 64 + n * 16 + lr] = f2b(s[n][r]);
        bf16x8 pa0 = *reinterpret_cast<const bf16x8*>(Pw + lr * 64 + lg * 8);
        bf16x8 pa1 = *reinterpret_cast<const bf16x8*>(Pw + lr * 64 + 32 + lg * 8);
#pragma unroll
        for (int n2 = 0; n2 < 4; n2++) {
            bf16x8 vb0 = *reinterpret_cast<const bf16x8*>(sV + (n2 * 16 + lr) * 64 + lg * 8);
            bf16x8 vb1 = *reinterpret_cast<const bf16x8*>(sV + (n2 * 16 + lr) * 64 + 32 + lg * 8);
            o[n2] = __builtin_amdgcn_mfma_f32_16x16x32_bf16(pa0, vb0, o[n2], 0, 0, 0);
            o[n2] = __builtin_amdgcn_mfma_f32_16x16x32_bf16(pa1, vb1, o[n2], 0, 0, 0);
        }
        __syncthreads();
    }
#pragma unroll
    for (int n2 = 0; n2 < 4; n2++) {
#pragma unroll
        for (int r = 0; r < 4; r++) {
            int ig = qbase + w * 16 + 4 * lg + r;
            long orow = (long)(b * L_ + ig);
            int j = n2 * 16 + lr;
            float u = b2f(cat[orow * 4096 + 3072 + h * 64 + j]);
            float val = o[n2][r] / lsum[r] * u;
            AG[orow * 1024 + h * 64 + j] = f2b(val);
        }
    }
}

// ---------------------------------------------------------------- layernorm (per token)
template <bool WB>
__global__ __launch_bounds__(256)
void k_ln(const float* __restrict__ xa, const float* __restrict__ ha,
          const float* __restrict__ g, const float* __restrict__ bb,
          const int* __restrict__ types,
          float* __restrict__ of, u16* __restrict__ ob)
{
    const int tok = blockIdx.x, tid = threadIdx.x;
    const long base = (long)tok * D_;
    float4 va = reinterpret_cast<const float4*>(xa + base)[tid];
    float4 vh = reinterpret_cast<const float4*>(ha + base)[tid];
    float v0 = va.x + vh.x, v1 = va.y + vh.y, v2 = va.z + vh.z, v3 = va.w + vh.w;
    float s = v0 + v1 + v2 + v3;
    float ss = v0 * v0 + v1 * v1 + v2 * v2 + v3 * v3;
#pragma unroll
    for (int d = 1; d < 64; d <<= 1) { s += __shfl_xor(s, d, 64); ss += __shfl_xor(ss, d, 64); }
    __shared__ float red[8];
    if ((tid & 63) == 0) { red[tid >> 6] = s; red[4 + (tid >> 6)] = ss; }
    __syncthreads();
    s  = red[0] + red[1] + red[2] + red[3];
    ss = red[4] + red[5] + red[6] + red[7];
    const float mu  = s * (1.f / D_);
    const float var = ss * (1.f / D_) - mu * mu;
    const float inv = rsqrtf(var + 1e-5f);
    const int t = types[tok];
    const float* gp = g + (long)t * D_ + tid * 4;
    const float* bp = bb + (long)t * D_ + tid * 4;
    float o0 = (v0 - mu) * inv * gp[0] + bp[0];
    float o1 = (v1 - mu) * inv * gp[1] + bp[1];
    float o2 = (v2 - mu) * inv * gp[2] + bp[2];
    float o3 = (v3 - mu) * inv * gp[3] + bp[3];
    reinterpret_cast<float4*>(of + base)[tid] = make_float4(o0, o1, o2, o3);
    if (WB) {
        ushort4 u4;
        u4.x = f2b(o0); u4.y = f2b(o1); u4.z = f2b(o2); u4.w = f2b(o3);
        reinterpret_cast<ushort4*>(ob + base)[tid] = u4;
    }
}

// ---------------------------------------------------------------- token-type bucketing
__global__ void k_count(const int* __restrict__ types, int* __restrict__ cnt) {
    int i = blockIdx.x * 256 + threadIdx.x;
    if (i < NTOK) atomicAdd(&cnt[types[i]], 1);
}
__global__ void k_scan(int* __restrict__ base) {
    if (threadIdx.x == 0) {
        int a = 0;
        for (int t = 0; t < T_; t++) { base[4 + t] = a; base[8 + t] = a; a += base[t]; }
    }
}
__global__ void k_fill(const int* __restrict__ types, int* __restrict__ cur, int* __restrict__ idxb) {
    int i = blockIdx.x * 256 + threadIdx.x;
    if (i < NTOK) {
        int p = atomicAdd(&cur[types[i]], 1);
        idxb[p] = i;
    }
}

// ---------------------------------------------------------------- launch
extern "C" void kernel_launch(void* const* d_in, const int* in_sizes, int n_in,
                              void* d_out, int out_size, void* d_ws, size_t ws_size,
                              hipStream_t stream) {
    const float* x    = (const float*)d_in[0];
    const int* types  = (const int*)d_in[1];
    const int* seql   = (const int*)d_in[2];
    const float* Wq   = (const float*)d_in[3];
    const float* Wk   = (const float*)d_in[4];
    const float* Wv   = (const float*)d_in[5];
    const float* Wu   = (const float*)d_in[6];
    const float* Wo   = (const float*)d_in[7];
    const float* ln1g = (const float*)d_in[8];
    const float* ln1b = (const float*)d_in[9];
    const float* W1   = (const float*)d_in[10];
    const float* b1   = (const float*)d_in[11];
    const float* W2   = (const float*)d_in[12];
    const float* b2   = (const float*)d_in[13];
    const float* ln2g = (const float*)d_in[14];
    const float* ln2b = (const float*)d_in[15];

    char* ws = (char*)d_ws;
    constexpr size_t OFF_WT  = 0;                                   // QKVU^T cat [4096][1024] bf16
    constexpr size_t OFF_WOT = OFF_WT  + (size_t)4096 * 1024 * 2;   // Wo^T [1024][1024] bf16
    constexpr size_t OFF_W1T = OFF_WOT + (size_t)1024 * 1024 * 2;   // W1^T [T][4096][1024] bf16
    constexpr size_t OFF_W2T = OFF_W1T + (size_t)T_ * 4096 * 1024 * 2; // W2^T [T][1024][4096] bf16
    constexpr size_t OFF_XB  = OFF_W2T + (size_t)T_ * 4096 * 1024 * 2; // x bf16 (later: AG)
    constexpr size_t OFF_CAT = OFF_XB  + (size_t)NTOK * D_ * 2;     // QKVU cat (later: FFN hidden)
    constexpr size_t OFF_H   = OFF_CAT + (size_t)NTOK * 4096 * 2;   // h f32 (later: h2)
    constexpr size_t OFF_X1  = OFF_H   + (size_t)NTOK * D_ * 4;     // x1 f32
    constexpr size_t OFF_X1B = OFF_X1  + (size_t)NTOK * D_ * 4;     // x1 bf16
    constexpr size_t OFF_INT = OFF_X1B + (size_t)NTOK * D_ * 2;     // cnt/off/cur + idx

    u16* WT   = (u16*)(ws + OFF_WT);
    u16* WOT  = (u16*)(ws + OFF_WOT);
    u16* W1T  = (u16*)(ws + OFF_W1T);
    u16* W2T  = (u16*)(ws + OFF_W2T);
    u16* XB   = (u16*)(ws + OFF_XB);      // also AG
    u16* CAT  = (u16*)(ws + OFF_CAT);     // also Hidden
    float* Hb = (float*)(ws + OFF_H);
    float* X1 = (float*)(ws + OFF_X1);
    u16* X1B  = (u16*)(ws + OFF_X1B);
    int* ibase = (int*)(ws + OFF_INT);    // cnt[4] off[4] cur[4] pad[4] idx[4096]
    int* cnt = ibase, *off = ibase + 4, *cur = ibase + 8, *idxb = ibase + 16;

    dim3 blk(256), blk512(512), tb(32, 8);

    // 1. casts / transposes
    k_cast_bf16<<<NTOK * D_ / 4 / 256, blk, 0, stream>>>(x, XB, NTOK * D_ / 4);
    k_tcast<<<dim3(32, 32, 1), tb, 0, stream>>>(Wq, WT + 0 * 1048576, 1024, 1024, 0, 0);
    k_tcast<<<dim3(32, 32, 1), tb, 0, stream>>>(Wk, WT + 1 * 1048576, 1024, 1024, 0, 0);
    k_tcast<<<dim3(32, 32, 1), tb, 0, stream>>>(Wv, WT + 2 * 1048576, 1024, 1024, 0, 0);
    k_tcast<<<dim3(32, 32, 1), tb, 0, stream>>>(Wu, WT + 3 * 1048576, 1024, 1024, 0, 0);
    k_tcast<<<dim3(32, 32, 1), tb, 0, stream>>>(Wo, WOT, 1024, 1024, 0, 0);
    k_tcast<<<dim3(128, 32, T_), tb, 0, stream>>>(W1, W1T, 1024, 4096, (long)1024 * 4096, (long)4096 * 1024);
    k_tcast<<<dim3(32, 128, T_), tb, 0, stream>>>(W2, W2T, 4096, 1024, (long)4096 * 1024, (long)1024 * 4096);

    // 2. QKVU = x @ [Wq|Wk|Wv|Wu]   (M=4096 N=4096 K=1024)
    k_gemm256<EP_BF16, false, false, false><<<dim3(16, 16), blk512, 0, stream>>>(
        XB, WT, CAT, nullptr, nullptr, nullptr, nullptr, NTOK, 1024, 1024, 1024, 4096, 0, 0);

    // 3. attention -> gated output AG (reuses XB)
    k_attn<<<dim3(L_ / 64, H_, B_), blk, 0, stream>>>(CAT, types, seql, XB);

    // 4. h = AG @ Wo   (M=4096 N=1024 K=1024), f32
    k_gemm256<EP_F32, false, false, false><<<dim3(16, 4), blk512, 0, stream>>>(
        XB, WOT, Hb, nullptr, nullptr, nullptr, nullptr, NTOK, 1024, 1024, 1024, 1024, 0, 0);

    // 5. x1 = LN1(x + h)
    k_ln<true><<<NTOK, blk, 0, stream>>>(x, Hb, ln1g, ln1b, types, X1, X1B);

    // 6. bucket tokens by type
    hipMemsetAsync(cnt, 0, 48, stream);
    k_count<<<NTOK / 256, blk, 0, stream>>>(types, cnt);
    k_scan<<<1, 64, 0, stream>>>(ibase);
    k_fill<<<NTOK / 256, blk, 0, stream>>>(types, cur, idxb);

    // 7. Hidden = gelu(x1[idx] @ W1[t] + b1[t])   (grouped, A indexed, C by position)
    k_gemm256<EP_GELU_BF16, true, false, true><<<dim3(16, 16, T_), blk512, 0, stream>>>(
        X1B, W1T, CAT, b1, idxb, off, cnt, NTOK, 1024, 1024, 1024, 4096,
        (long)4096 * 1024, 4096);

    // 8. h2 = Hidden @ W2[t] + b2[t]  (grouped, A by position, C scattered to token rows)
    k_gemm256<EP_BIAS_F32, false, true, true><<<dim3(16, 4, T_), blk512, 0, stream>>>(
        CAT, W2T, Hb, b2, idxb, off, cnt, NTOK, 4096, 4096, 4096, 1024,
        (long)1024 * 4096, 1024);

    // 9. out = LN2(x1 + h2)
    k_ln<false><<<NTOK, blk, 0, stream>>>(X1, Hb, ln2g, ln2b, types, (float*)d_out, nullptr);
}

// Round 5
// 664.350 us; speedup vs baseline: 1.2278x; 1.0072x over previous
//
#include <hip/hip_runtime.h>
#include <hip/hip_bf16.h>
#include <math.h>

#define B_   2
#define L_   2048
#define D_   1024
#define H_   16
#define DK_  64
#define T_   4
#define F_   4096
#define NTOK (B_ * L_)   // 4096

typedef __bf16 bf16_t;
typedef bf16_t bf16x8 __attribute__((ext_vector_type(8)));
typedef float  f32x4  __attribute__((ext_vector_type(4)));
typedef unsigned short u16;
typedef u16 u16x8 __attribute__((ext_vector_type(8)));

static __device__ __forceinline__ u16 f2b(float f) {
    __hip_bfloat16 h = __float2bfloat16(f);
    return *reinterpret_cast<u16*>(&h);
}
static __device__ __forceinline__ float b2f(u16 u) {
    __hip_bfloat16 h;
    *reinterpret_cast<u16*>(&h) = u;
    return __bfloat162float(h);
}

// async global->LDS, 16B per lane; LDS dest must be linear (uniform base + lane*16)
static __device__ __forceinline__ void gld16(void* lds, const void* g) {
    __builtin_amdgcn_global_load_lds(
        (const __attribute__((address_space(1))) unsigned int*)g,
        (__attribute__((address_space(3))) unsigned int*)lds,
        16, 0, 0);
}

#define VMW(N) do { asm volatile("s_waitcnt vmcnt(" #N ")" ::: "memory"); \
                    __builtin_amdgcn_sched_barrier(0); } while (0)
#define BARR() do { __builtin_amdgcn_sched_barrier(0); \
                    __builtin_amdgcn_s_barrier();      \
                    __builtin_amdgcn_sched_barrier(0); } while (0)

// ---------------------------------------------------------------- cast x -> bf16
__global__ void k_cast_bf16(const float* __restrict__ in, u16* __restrict__ out, int n4) {
    int i = blockIdx.x * 256 + threadIdx.x;
    if (i >= n4) return;
    float4 v = reinterpret_cast<const float4*>(in)[i];
    ushort4 o;
    o.x = f2b(v.x); o.y = f2b(v.y); o.z = f2b(v.z); o.w = f2b(v.w);
    reinterpret_cast<ushort4*>(out)[i] = o;
}

// --------------------------------------------- transpose-cast W (KxN f32) -> Wt (NxK bf16)
__global__ void k_tcast(const float* __restrict__ W, u16* __restrict__ Wt,
                        int K, int N, long sW, long sWt) {
    __shared__ float tile[32][33];
    int z = blockIdx.z;
    W  += (long)z * sW;
    Wt += (long)z * sWt;
    int n0 = blockIdx.x * 32, k0 = blockIdx.y * 32;
    int tx = threadIdx.x, ty = threadIdx.y;   // block (32,8)
#pragma unroll
    for (int i = 0; i < 4; i++)
        tile[ty + 8 * i][tx] = W[(long)(k0 + ty + 8 * i) * N + n0 + tx];
    __syncthreads();
#pragma unroll
    for (int i = 0; i < 4; i++)
        Wt[(long)(n0 + ty + 8 * i) * K + k0 + tx] = f2b(tile[tx][ty + 8 * i]);
}

// ---------------------------------------------------------------- 256x256 8-wave GEMM
// (unchanged from round 4 -- see comments there)
enum { EP_BF16 = 0, EP_F32 = 1, EP_GELU_BF16 = 2, EP_BIAS_F32 = 3 };

#define PHASE(QA, QB) do {                                                        \
    const u16* Ah_ = ldsb + (QA) * 4096;                                          \
    const u16* Bh_ = ldsb + (2 + (QB)) * 4096;                                    \
    bf16x8 av[4], bv[2];                                                          \
    _Pragma("unroll")                                                             \
    for (int mfi = 0; mfi < 4; mfi++)                                             \
        av[mfi] = *reinterpret_cast<const bf16x8*>(                               \
            Ah_ + (wr2 * 64 + mfi * 16 + lr) * 32 + achnk);                       \
    _Pragma("unroll")                                                             \
    for (int nfi = 0; nfi < 2; nfi++)                                             \
        bv[nfi] = *reinterpret_cast<const bf16x8*>(                               \
            Bh_ + (wc2 * 32 + nfi * 16 + lr) * 32 + achnk);                       \
    __builtin_amdgcn_s_setprio(1);                                                \
    _Pragma("unroll")                                                             \
    for (int mfi = 0; mfi < 4; mfi++)                                             \
        _Pragma("unroll")                                                         \
        for (int nfi = 0; nfi < 2; nfi++)                                         \
            acc[QA][QB][mfi][nfi] = __builtin_amdgcn_mfma_f32_16x16x32_bf16(      \
                av[mfi], bv[nfi], acc[QA][QB][mfi][nfi], 0, 0, 0);                \
    __builtin_amdgcn_s_setprio(0);                                                \
} while (0)

template <int MODE, bool AIDX, bool CIDX, bool GROUPED>
__global__ __launch_bounds__(512, 2)
void k_gemm256(const u16* __restrict__ A, const u16* __restrict__ Bt,
               void* __restrict__ Cv, const float* __restrict__ bias,
               const int* __restrict__ idxb, const int* __restrict__ boff,
               const int* __restrict__ bcnt,
               int M, int K, int lda, int ldb, int ldc,
               long strideB, int biasStride)
{
    int p0 = 0, pend = M;
    if (GROUPED) {
        int z = blockIdx.z;
        int c = bcnt[z];
        p0 = boff[z]; pend = p0 + c;
        Bt += (long)z * strideB;
        bias += (long)z * biasStride;
    }
    const int gx = gridDim.x;
    const int nwg = gx * gridDim.y;
    const int id = blockIdx.y * gx + blockIdx.x;
    const int q8 = nwg >> 3, r8 = nwg & 7, xcd = id & 7, sub = id >> 3;
    const int id2 = (xcd < r8 ? xcd * (q8 + 1) : r8 * (q8 + 1) + (xcd - r8) * q8) + sub;
    const int tm = id2 % gx, tn = id2 / gx;
    if (GROUPED && tm * 256 >= (pend - p0)) return;
    const int bm = tm * 256, bn = tn * 256;

    const int tid = threadIdx.x;
    const int wid = tid >> 6, lane = tid & 63;
    const int lg = lane >> 4, lr = lane & 15;
    const int wr2 = wid >> 2, wc2 = wid & 3;      // 2x4 wave grid within a quadrant
    const int achnk = (lg ^ (lr & 3)) * 8;        // swizzled 16B chunk (u16 units)

    __shared__ u16 lds[8 * 4096];                 // 8 regions x 8KB

    const int srow = tid >> 2;                    // 0..127
    const int schunk = (tid & 3) ^ (srow & 3);    // inverse (=same) chunk swizzle
    long ra0, ra1;
    {
        int pa0 = p0 + bm + srow, pa1 = p0 + bm + 128 + srow;
        if (GROUPED) { pa0 = min(pa0, pend - 1); pa1 = min(pa1, pend - 1); }
        ra0 = AIDX ? (long)idxb[pa0] : (long)pa0;
        ra1 = AIDX ? (long)idxb[pa1] : (long)pa1;
    }
    const u16* gA0 = A + ra0 * lda + schunk * 8;
    const u16* gA1 = A + ra1 * lda + schunk * 8;
    const u16* gB0 = Bt + (long)(bn + srow) * ldb + schunk * 8;
    const u16* gB1 = Bt + (long)(bn + 128 + srow) * ldb + schunk * 8;
    u16* const dA0 = lds + tid * 8;               // region offsets added per buf
    const int R = 4096;                           // region stride (u16)

    const f32x4 zero = {0.f, 0.f, 0.f, 0.f};
    f32x4 acc[2][2][4][2];
#pragma unroll
    for (int qa = 0; qa < 2; qa++)
#pragma unroll
        for (int qb = 0; qb < 2; qb++)
#pragma unroll
            for (int m = 0; m < 4; m++)
#pragma unroll
                for (int n = 0; n < 2; n++) acc[qa][qb][m][n] = zero;

    const int NT = K >> 5;

    gld16(dA0 + 0 * R, gA0);
    gld16(dA0 + 2 * R, gB0);
    gld16(dA0 + 3 * R, gB1);
    gld16(dA0 + 1 * R, gA1);

    for (int t = 0; t < NT - 1; t++) {
        const int buf = t & 1;
        const u16* ldsb = lds + buf * 4 * R;
        u16* dstn = dA0 + (buf ^ 1) * 4 * R;
        const long ko = (long)(t + 1) * 32;

        gld16(dstn + 0 * R, gA0 + ko);
        VMW(3); BARR();
        PHASE(0, 0);
        BARR();

        gld16(dstn + 2 * R, gB0 + ko);
        VMW(3); BARR();
        PHASE(0, 1);
        BARR();

        gld16(dstn + 3 * R, gB1 + ko);
        VMW(3); BARR();
        PHASE(1, 0);
        BARR();

        gld16(dstn + 1 * R, gA1 + ko);
        VMW(3); BARR();
        PHASE(1, 1);
        BARR();
    }
    {   // peeled last tile
        const u16* ldsb = lds + ((NT - 1) & 1) * 4 * R;
        VMW(2); BARR();
        PHASE(0, 0);
        BARR();
        VMW(1); BARR();
        PHASE(0, 1);
        BARR();
        VMW(0); BARR();
        PHASE(1, 0);
        BARR();
        PHASE(1, 1);
    }

#pragma unroll
    for (int qa = 0; qa < 2; qa++) {
#pragma unroll
        for (int mfi = 0; mfi < 4; mfi++) {
#pragma unroll
            for (int r = 0; r < 4; r++) {
                int prow = p0 + bm + qa * 128 + wr2 * 64 + mfi * 16 + lg * 4 + r;
                if (GROUPED && prow >= pend) continue;
                long crow = CIDX ? (long)idxb[prow] : (long)prow;
#pragma unroll
                for (int qb = 0; qb < 2; qb++) {
#pragma unroll
                    for (int nfi = 0; nfi < 2; nfi++) {
                        int gn = bn + qb * 128 + wc2 * 32 + nfi * 16 + lr;
                        float v = acc[qa][qb][mfi][nfi][r];
                        if (MODE == EP_GELU_BF16) {
                            v += bias[gn];
                            v = 0.5f * v * (1.0f + erff(v * 0.70710678118654752f));
                        }
                        if (MODE == EP_BIAS_F32) v += bias[gn];
                        long off = crow * (long)ldc + gn;
                        if (MODE == EP_BF16 || MODE == EP_GELU_BF16)
                            ((u16*)Cv)[off] = f2b(v);
                        else
                            ((float*)Cv)[off] = v;
                    }
                }
            }
        }
    }
}

// ---------------------------------------------------------------- attention
// cat layout: [NTOK][4096] bf16 : cols [0,1024)=Q [1024,2048)=K [2048,3072)=V [3072,4096)=U
// block = (qtile of 64 rows, head, batch); 4 waves x 16 q-rows; KBLK=64.
// All LDS tiles use a 16B-chunk XOR swizzle: physical chunk = logical ^ (row&7).
// sK is staged by global_load_lds (linear dest) with the PRE-SWIZZLED global
// source (rule: swizzle both sides or neither); sV/sP swizzle write+read.
__global__ __launch_bounds__(256)
void k_attn(const u16* __restrict__ cat, const int* __restrict__ types,
            const int* __restrict__ seql, u16* __restrict__ AG)
{
    const int qt = blockIdx.x, h = blockIdx.y, b = blockIdx.z;
    const int tid = threadIdx.x, w = tid >> 6, lane = tid & 63;
    const int lg = lane >> 4, lr = lane & 15;
    const int qbase = qt * 64;

    __shared__ u16 sK[64 * 64];        // [key][dk], chunk-swizzled
    __shared__ u16 sV[64 * 64];        // [dk][key], chunk-swizzled
    __shared__ u16 sP[4 * 16 * 64];    // per-wave [16 q][64 key], chunk-swizzled
    __shared__ unsigned long long smask[2];

    const int seqlen = seql[b];

    const long qrow = (long)(b * L_ + qbase + w * 16 + lr);
    const u16* qp = cat + qrow * 4096 + h * 64;
    bf16x8 qf0 = *reinterpret_cast<const bf16x8*>(qp + lg * 8);
    bf16x8 qf1 = *reinterpret_cast<const bf16x8*>(qp + 32 + lg * 8);

    const f32x4 zero = {0.f, 0.f, 0.f, 0.f};
    f32x4 o[4] = {zero, zero, zero, zero};
    float mrow[4] = {-1e30f, -1e30f, -1e30f, -1e30f};
    float lsum[4] = {0.f, 0.f, 0.f, 0.f};

    for (int kb = 0; kb < L_; kb += 64) {
        if (kb >= seqlen) break;   // uniform per block (b fixed)
        // stage K tile: linear LDS dest, source chunk pre-swizzled
        {
            int c0 = tid, c1 = 256 + tid;
            int r0_ = c0 >> 3, s0_ = (c0 & 7) ^ (r0_ & 7);
            int r1_ = c1 >> 3, s1_ = (c1 & 7) ^ (r1_ & 7);
            gld16(sK + c0 * 8, cat + (long)(b * L_ + kb + r0_) * 4096 + 1024 + h * 64 + s0_ * 8);
            gld16(sK + c1 * 8, cat + (long)(b * L_ + kb + r1_) * 4096 + 1024 + h * 64 + s1_ * 8);
        }
        // stage V transposed (register path), swizzled write
        {
            int key = tid & 63, dkb = (tid >> 6) * 16;
            const u16* vs = cat + (long)(b * L_ + kb + key) * 4096 + 2048 + h * 64 + dkb;
            u16x8 v0 = *reinterpret_cast<const u16x8*>(vs);
            u16x8 v1 = *reinterpret_cast<const u16x8*>(vs + 8);
            int kc = key >> 3, kb7 = key & 7;
#pragma unroll
            for (int e = 0; e < 8; e++)
                sV[(dkb + e) * 64 + (kc ^ (e & 7)) * 8 + kb7] = v0[e];
#pragma unroll
            for (int e = 0; e < 8; e++)
                sV[(dkb + 8 + e) * 64 + (kc ^ (e & 7)) * 8 + kb7] = v1[e];
        }
        if (w == 0) {
            int j = kb + lane;
            bool pad = (j >= seqlen);
            bool prompt = types[b * L_ + j] < 3;
            unsigned long long pm = __ballot(pad);
            unsigned long long rm = __ballot(prompt);
            if (lane == 0) { smask[0] = pm; smask[1] = rm; }
        }
        __syncthreads();
        const unsigned long long padm = smask[0], prm = smask[1];

        // S = Q K^T  (16 q-rows x 64 keys per wave); swizzled K reads
        f32x4 s[4];
#pragma unroll
        for (int n = 0; n < 4; n++) {
            int row = n * 16 + lr, m7 = row & 7;
            bf16x8 bk0 = *reinterpret_cast<const bf16x8*>(sK + row * 64 + (lg ^ m7) * 8);
            bf16x8 bk1 = *reinterpret_cast<const bf16x8*>(sK + row * 64 + ((lg ^ 4) ^ m7) * 8);
            f32x4 t4 = zero;
            t4 = __builtin_amdgcn_mfma_f32_16x16x32_bf16(qf0, bk0, t4, 0, 0, 0);
            t4 = __builtin_amdgcn_mfma_f32_16x16x32_bf16(qf1, bk1, t4, 0, 0, 0);
            s[n] = t4;
        }
        // dead-mask words: bit j = padded | (causal-dead & !prompt)
        unsigned long long dmask[4];
#pragma unroll
        for (int r = 0; r < 4; r++) {
            int ig = qbase + w * 16 + 4 * lg + r;
            int d = ig - kb;
            unsigned long long him = (d >= 63) ? 0ull
                                   : ((d < 0) ? ~0ull : (~0ull << (d + 1)));
            dmask[r] = padm | (~prm & him);
        }
        float tmax[4] = {-1e30f, -1e30f, -1e30f, -1e30f};
#pragma unroll
        for (int n = 0; n < 4; n++) {
            int jloc = n * 16 + lr;
#pragma unroll
            for (int r = 0; r < 4; r++) {
                bool dead = (dmask[r] >> jloc) & 1ull;
                float sv = dead ? -1e30f : s[n][r] * 0.125f;
                s[n][r] = sv;
                tmax[r] = fmaxf(tmax[r], sv);
            }
        }
#pragma unroll
        for (int r = 0; r < 4; r++) {
#pragma unroll
            for (int d = 1; d < 16; d <<= 1)
                tmax[r] = fmaxf(tmax[r], __shfl_xor(tmax[r], d, 64));
        }
        float corr[4], rsum[4];
#pragma unroll
        for (int r = 0; r < 4; r++) {
            float mnew = fmaxf(mrow[r], tmax[r]);
            corr[r] = __expf(mrow[r] - mnew);
            mrow[r] = mnew;
            rsum[r] = 0.f;
        }
#pragma unroll
        for (int n = 0; n < 4; n++)
#pragma unroll
            for (int r = 0; r < 4; r++) {
                float p = __expf(s[n][r] - mrow[r]);
                s[n][r] = p;
                rsum[r] += p;
            }
#pragma unroll
        for (int r = 0; r < 4; r++) {
#pragma unroll
            for (int d = 1; d < 16; d <<= 1) rsum[r] += __shfl_xor(rsum[r], d, 64);
            lsum[r] = lsum[r] * corr[r] + rsum[r];
        }
#pragma unroll
        for (int n2 = 0; n2 < 4; n2++) {
            f32x4 t4 = o[n2];
#pragma unroll
            for (int r = 0; r < 4; r++) t4[r] *= corr[r];
            o[n2] = t4;
        }
        // P -> LDS (per-wave region), swizzled write
        u16* Pw = sP + w * 1024;
#pragma unroll
        for (int n = 0; n < 4; n++) {
            int pc = n * 2 + (lr >> 3), p7 = lr & 7;
#pragma unroll
            for (int r = 0; r < 4; r++) {
                int q = 4 * lg + r;
                Pw[q * 64 + (pc ^ (q & 7)) * 8 + p7] = f2b(s[n][r]);
            }
        }
        // PV; swizzled P and V reads
        int l7 = lr & 7;
        bf16x8 pa0 = *reinterpret_cast<const bf16x8*>(Pw + lr * 64 + (lg ^ l7) * 8);
        bf16x8 pa1 = *reinterpret_cast<const bf16x8*>(Pw + lr * 64 + ((lg ^ 4) ^ l7) * 8);
#pragma unroll
        for (int n2 = 0; n2 < 4; n2++) {
            int drow = n2 * 16 + lr, d7 = drow & 7;
            bf16x8 vb0 = *reinterpret_cast<const bf16x8*>(sV + drow * 64 + (lg ^ d7) * 8);
            bf16x8 vb1 = *reinterpret_cast<const bf16x8*>(sV + drow * 64 + ((lg ^ 4) ^ d7) * 8);
            o[n2] = __builtin_amdgcn_mfma_f32_16x16x32_bf16(pa0, vb0, o[n2], 0, 0, 0);
            o[n2] = __builtin_amdgcn_mfma_f32_16x16x32_bf16(pa1, vb1, o[n2], 0, 0, 0);
        }
        __syncthreads();
    }
    // epilogue: normalize, U-gate, store bf16
#pragma unroll
    for (int n2 = 0; n2 < 4; n2++) {
#pragma unroll
        for (int r = 0; r < 4; r++) {
            int ig = qbase + w * 16 + 4 * lg + r;
            long orow = (long)(b * L_ + ig);
            int j = n2 * 16 + lr;
            float u = b2f(cat[orow * 4096 + 3072 + h * 64 + j]);
            float val = o[n2][r] / lsum[r] * u;
            AG[orow * 1024 + h * 64 + j] = f2b(val);
        }
    }
}

// ---------------------------------------------------------------- layernorm (per token)
template <bool WB>
__global__ __launch_bounds__(256)
void k_ln(const float* __restrict__ xa, const float* __restrict__ ha,
          const float* __restrict__ g, const float* __restrict__ bb,
          const int* __restrict__ types,
          float* __restrict__ of, u16* __restrict__ ob)
{
    const int tok = blockIdx.x, tid = threadIdx.x;
    const long base = (long)tok * D_;
    float4 va = reinterpret_cast<const float4*>(xa + base)[tid];
    float4 vh = reinterpret_cast<const float4*>(ha + base)[tid];
    float v0 = va.x + vh.x, v1 = va.y + vh.y, v2 = va.z + vh.z, v3 = va.w + vh.w;
    float s = v0 + v1 + v2 + v3;
    float ss = v0 * v0 + v1 * v1 + v2 * v2 + v3 * v3;
#pragma unroll
    for (int d = 1; d < 64; d <<= 1) { s += __shfl_xor(s, d, 64); ss += __shfl_xor(ss, d, 64); }
    __shared__ float red[8];
    if ((tid & 63) == 0) { red[tid >> 6] = s; red[4 + (tid >> 6)] = ss; }
    __syncthreads();
    s  = red[0] + red[1] + red[2] + red[3];
    ss = red[4] + red[5] + red[6] + red[7];
    const float mu  = s * (1.f / D_);
    const float var = ss * (1.f / D_) - mu * mu;
    const float inv = rsqrtf(var + 1e-5f);
    const int t = types[tok];
    const float* gp = g + (long)t * D_ + tid * 4;
    const float* bp = bb + (long)t * D_ + tid * 4;
    float o0 = (v0 - mu) * inv * gp[0] + bp[0];
    float o1 = (v1 - mu) * inv * gp[1] + bp[1];
    float o2 = (v2 - mu) * inv * gp[2] + bp[2];
    float o3 = (v3 - mu) * inv * gp[3] + bp[3];
    reinterpret_cast<float4*>(of + base)[tid] = make_float4(o0, o1, o2, o3);
    if (WB) {
        ushort4 u4;
        u4.x = f2b(o0); u4.y = f2b(o1); u4.z = f2b(o2); u4.w = f2b(o3);
        reinterpret_cast<ushort4*>(ob + base)[tid] = u4;
    }
}

// ---------------------------------------------------------------- token-type bucketing
__global__ void k_count(const int* __restrict__ types, int* __restrict__ cnt) {
    int i = blockIdx.x * 256 + threadIdx.x;
    if (i < NTOK) atomicAdd(&cnt[types[i]], 1);
}
__global__ void k_scan(int* __restrict__ base) {
    if (threadIdx.x == 0) {
        int a = 0;
        for (int t = 0; t < T_; t++) { base[4 + t] = a; base[8 + t] = a; a += base[t]; }
    }
}
__global__ void k_fill(const int* __restrict__ types, int* __restrict__ cur, int* __restrict__ idxb) {
    int i = blockIdx.x * 256 + threadIdx.x;
    if (i < NTOK) {
        int p = atomicAdd(&cur[types[i]], 1);
        idxb[p] = i;
    }
}

// ---------------------------------------------------------------- launch
extern "C" void kernel_launch(void* const* d_in, const int* in_sizes, int n_in,
                              void* d_out, int out_size, void* d_ws, size_t ws_size,
                              hipStream_t stream) {
    const float* x    = (const float*)d_in[0];
    const int* types  = (const int*)d_in[1];
    const int* seql   = (const int*)d_in[2];
    const float* Wq   = (const float*)d_in[3];
    const float* Wk   = (const float*)d_in[4];
    const float* Wv   = (const float*)d_in[5];
    const float* Wu   = (const float*)d_in[6];
    const float* Wo   = (const float*)d_in[7];
    const float* ln1g = (const float*)d_in[8];
    const float* ln1b = (const float*)d_in[9];
    const float* W1   = (const float*)d_in[10];
    const float* b1   = (const float*)d_in[11];
    const float* W2   = (const float*)d_in[12];
    const float* b2   = (const float*)d_in[13];
    const float* ln2g = (const float*)d_in[14];
    const float* ln2b = (const float*)d_in[15];

    char* ws = (char*)d_ws;
    constexpr size_t OFF_WT  = 0;                                   // QKVU^T cat [4096][1024] bf16
    constexpr size_t OFF_WOT = OFF_WT  + (size_t)4096 * 1024 * 2;   // Wo^T [1024][1024] bf16
    constexpr size_t OFF_W1T = OFF_WOT + (size_t)1024 * 1024 * 2;   // W1^T [T][4096][1024] bf16
    constexpr size_t OFF_W2T = OFF_W1T + (size_t)T_ * 4096 * 1024 * 2; // W2^T [T][1024][4096] bf16
    constexpr size_t OFF_XB  = OFF_W2T + (size_t)T_ * 4096 * 1024 * 2; // x bf16 (later: AG)
    constexpr size_t OFF_CAT = OFF_XB  + (size_t)NTOK * D_ * 2;     // QKVU cat (later: FFN hidden)
    constexpr size_t OFF_H   = OFF_CAT + (size_t)NTOK * 4096 * 2;   // h f32 (later: h2)
    constexpr size_t OFF_X1  = OFF_H   + (size_t)NTOK * D_ * 4;     // x1 f32
    constexpr size_t OFF_X1B = OFF_X1  + (size_t)NTOK * D_ * 4;     // x1 bf16
    constexpr size_t OFF_INT = OFF_X1B + (size_t)NTOK * D_ * 2;     // cnt/off/cur + idx

    u16* WT   = (u16*)(ws + OFF_WT);
    u16* WOT  = (u16*)(ws + OFF_WOT);
    u16* W1T  = (u16*)(ws + OFF_W1T);
    u16* W2T  = (u16*)(ws + OFF_W2T);
    u16* XB   = (u16*)(ws + OFF_XB);      // also AG
    u16* CAT  = (u16*)(ws + OFF_CAT);     // also Hidden
    float* Hb = (float*)(ws + OFF_H);
    float* X1 = (float*)(ws + OFF_X1);
    u16* X1B  = (u16*)(ws + OFF_X1B);
    int* ibase = (int*)(ws + OFF_INT);    // cnt[4] off[4] cur[4] pad[4] idx[4096]
    int* cnt = ibase, *off = ibase + 4, *cur = ibase + 8, *idxb = ibase + 16;

    dim3 blk(256), blk512(512), tb(32, 8);

    // 1. casts / transposes
    k_cast_bf16<<<NTOK * D_ / 4 / 256, blk, 0, stream>>>(x, XB, NTOK * D_ / 4);
    k_tcast<<<dim3(32, 32, 1), tb, 0, stream>>>(Wq, WT + 0 * 1048576, 1024, 1024, 0, 0);
    k_tcast<<<dim3(32, 32, 1), tb, 0, stream>>>(Wk, WT + 1 * 1048576, 1024, 1024, 0, 0);
    k_tcast<<<dim3(32, 32, 1), tb, 0, stream>>>(Wv, WT + 2 * 1048576, 1024, 1024, 0, 0);
    k_tcast<<<dim3(32, 32, 1), tb, 0, stream>>>(Wu, WT + 3 * 1048576, 1024, 1024, 0, 0);
    k_tcast<<<dim3(32, 32, 1), tb, 0, stream>>>(Wo, WOT, 1024, 1024, 0, 0);
    k_tcast<<<dim3(128, 32, T_), tb, 0, stream>>>(W1, W1T, 1024, 4096, (long)1024 * 4096, (long)4096 * 1024);
    k_tcast<<<dim3(32, 128, T_), tb, 0, stream>>>(W2, W2T, 4096, 1024, (long)4096 * 1024, (long)1024 * 4096);

    // 2. QKVU = x @ [Wq|Wk|Wv|Wu]   (M=4096 N=4096 K=1024)
    k_gemm256<EP_BF16, false, false, false><<<dim3(16, 16), blk512, 0, stream>>>(
        XB, WT, CAT, nullptr, nullptr, nullptr, nullptr, NTOK, 1024, 1024, 1024, 4096, 0, 0);

    // 3. attention -> gated output AG (reuses XB)
    k_attn<<<dim3(L_ / 64, H_, B_), blk, 0, stream>>>(CAT, types, seql, XB);

    // 4. h = AG @ Wo   (M=4096 N=1024 K=1024), f32
    k_gemm256<EP_F32, false, false, false><<<dim3(16, 4), blk512, 0, stream>>>(
        XB, WOT, Hb, nullptr, nullptr, nullptr, nullptr, NTOK, 1024, 1024, 1024, 1024, 0, 0);

    // 5. x1 = LN1(x + h)
    k_ln<true><<<NTOK, blk, 0, stream>>>(x, Hb, ln1g, ln1b, types, X1, X1B);

    // 6. bucket tokens by type
    hipMemsetAsync(cnt, 0, 48, stream);
    k_count<<<NTOK / 256, blk, 0, stream>>>(types, cnt);
    k_scan<<<1, 64, 0, stream>>>(ibase);
    k_fill<<<NTOK / 256, blk, 0, stream>>>(types, cur, idxb);

    // 7. Hidden = gelu(x1[idx] @ W1[t] + b1[t])   (grouped, A indexed, C by position)
    k_gemm256<EP_GELU_BF16, true, false, true><<<dim3(16, 16, T_), blk512, 0, stream>>>(
        X1B, W1T, CAT, b1, idxb, off, cnt, NTOK, 1024, 1024, 1024, 4096,
        (long)4096 * 1024, 4096);

    // 8. h2 = Hidden @ W2[t] + b2[t]  (grouped, A by position, C scattered to token rows)
    k_gemm256<EP_BIAS_F32, false, true, true><<<dim3(16, 4, T_), blk512, 0, stream>>>(
        CAT, W2T, Hb, b2, idxb, off, cnt, NTOK, 4096, 4096, 4096, 1024,
        (long)1024 * 4096, 1024);

    // 9. out = LN2(x1 + h2)
    k_ln<false><<<NTOK, blk, 0, stream>>>(X1, Hb, ln2g, ln2b, types, (float*)d_out, nullptr);
}

// Round 6
// 597.195 us; speedup vs baseline: 1.3659x; 1.1125x over previous
//
#include <hip/hip_runtime.h>
#include <hip/hip_bf16.h>
#include <math.h>

#define B_   2
#define L_   2048
#define D_   1024
#define H_   16
#define DK_  64
#define T_   4
#define F_   4096
#define NTOK (B_ * L_)   // 4096

typedef __bf16 bf16_t;
typedef bf16_t bf16x8 __attribute__((ext_vector_type(8)));
typedef float  f32x4  __attribute__((ext_vector_type(4)));
typedef unsigned short u16;
typedef u16 u16x8 __attribute__((ext_vector_type(8)));

static __device__ __forceinline__ u16 f2b(float f) {
    __hip_bfloat16 h = __float2bfloat16(f);
    return *reinterpret_cast<u16*>(&h);
}
static __device__ __forceinline__ float b2f(u16 u) {
    __hip_bfloat16 h;
    *reinterpret_cast<u16*>(&h) = u;
    return __bfloat162float(h);
}

// async global->LDS, 16B per lane; LDS dest is linear (uniform base + lane*16)
static __device__ __forceinline__ void gld16(void* lds, const void* g) {
    __builtin_amdgcn_global_load_lds(
        (const __attribute__((address_space(1))) unsigned int*)g,
        (__attribute__((address_space(3))) unsigned int*)lds,
        16, 0, 0);
}

#define VMW(N) do { asm volatile("s_waitcnt vmcnt(" #N ")" ::: "memory"); \
                    __builtin_amdgcn_sched_barrier(0); } while (0)
#define BARR() do { __builtin_amdgcn_sched_barrier(0); \
                    __builtin_amdgcn_s_barrier();      \
                    __builtin_amdgcn_sched_barrier(0); } while (0)

// ---------------------------------------------------------------- cast x -> bf16
__global__ void k_cast_bf16(const float* __restrict__ in, u16* __restrict__ out, int n4) {
    int i = blockIdx.x * 256 + threadIdx.x;
    if (i >= n4) return;
    float4 v = reinterpret_cast<const float4*>(in)[i];
    ushort4 o;
    o.x = f2b(v.x); o.y = f2b(v.y); o.z = f2b(v.z); o.w = f2b(v.w);
    reinterpret_cast<ushort4*>(out)[i] = o;
}

// --------------------------------------------- transpose-cast W (KxN f32) -> Wt (NxK bf16)
__global__ void k_tcast(const float* __restrict__ W, u16* __restrict__ Wt,
                        int K, int N, long sW, long sWt) {
    __shared__ float tile[32][33];
    int z = blockIdx.z;
    W  += (long)z * sW;
    Wt += (long)z * sWt;
    int n0 = blockIdx.x * 32, k0 = blockIdx.y * 32;
    int tx = threadIdx.x, ty = threadIdx.y;   // block (32,8)
#pragma unroll
    for (int i = 0; i < 4; i++)
        tile[ty + 8 * i][tx] = W[(long)(k0 + ty + 8 * i) * N + n0 + tx];
    __syncthreads();
#pragma unroll
    for (int i = 0; i < 4; i++)
        Wt[(long)(n0 + ty + 8 * i) * K + k0 + tx] = f2b(tile[tx][ty + 8 * i]);
}

// ---------------------------------------------------------------- 256x256 8-wave GEMM v2
// C[M x N] = A[M x K] * Bt[N x K]^T ; BM=BN=256, BK=32, 512 threads (8 waves, 2x4).
// LDS: 2 buf x 4 regions (A0 rows0-127, A1 rows128-255, B0 cols0-127, B1) x 8KB.
// Per K-tile: one vmcnt(2), two barriers. Wave (wr,wc)=(wid>>2, wid&3) computes
// rows {qa*128 + wr*64 + mfi*16} x cols {wc*64 + nfi*16}; B-frags bv[4] are read
// ONCE per tile and reused for both A-halves (12 ds_read_b128/wave/tile).
// Swizzle: phys_chunk = k_chunk ^ ((row>>1)&3) -> 2-way max bank aliasing (free).
// Staging ring per tile: ph0 issues A0,B0(t+1); ph1 issues A1,B1(t+1); vmcnt(2)
// at ph0 drains A1,B1(t) (all 4 regions of tile t then resident).
enum { EP_BF16 = 0, EP_F32 = 1, EP_GELU_BF16 = 2, EP_BIAS_F32 = 3 };

template <int MODE, bool AIDX, bool CIDX, bool GROUPED, int KS>
__global__ __launch_bounds__(512, 2)
void k_g2(const u16* __restrict__ A, const u16* __restrict__ Bt,
          void* __restrict__ Cv, float* __restrict__ Cpart, long partStride,
          const float* __restrict__ bias,
          const int* __restrict__ idxb, const int* __restrict__ boff,
          const int* __restrict__ bcnt,
          int M, int K, int lda, int ldb, int ldc,
          long strideB, int biasStride)
{
    int p0 = 0, pend = M, ks = 0;
    if (KS > 1) ks = (int)blockIdx.z % KS;
    if (GROUPED) {
        int g = (KS > 1) ? ((int)blockIdx.z / KS) : (int)blockIdx.z;
        int c = bcnt[g];
        p0 = boff[g]; pend = p0 + c;
        Bt += (long)g * strideB;
        bias += (long)g * biasStride;
    }
    int kBeg = 0, kEnd = K;
    if (KS > 1) {
        int Kc = ((K / KS) + 31) & ~31;
        kBeg = ks * Kc;
        kEnd = min(K, kBeg + Kc);
    }
    // XCD-bijective block swizzle (m204)
    const int gx = gridDim.x;
    const int nwg = gx * gridDim.y;
    const int id = blockIdx.y * gx + blockIdx.x;
    const int q8 = nwg >> 3, r8 = nwg & 7, xcd = id & 7, sub = id >> 3;
    const int id2 = (xcd < r8 ? xcd * (q8 + 1) : r8 * (q8 + 1) + (xcd - r8) * q8) + sub;
    const int tm = id2 % gx, tn = id2 / gx;
    if (GROUPED && tm * 256 >= (pend - p0)) return;
    const int bm = tm * 256, bn = tn * 256;

    const int tid = threadIdx.x;
    const int wid = tid >> 6, lane = tid & 63;
    const int lg = lane >> 4, lr = lane & 15;
    const int wr = wid >> 2, wc = wid & 3;

    __shared__ u16 lds[8 * 4096];          // [buf0: A0 A1 B0 B1][buf1: ...]

    // ---- staging (1 gld16/thread/region) ----
    const int srow = tid >> 2;                               // 0..127
    const int sch  = (tid & 3) ^ ((srow >> 1) & 3);          // logical chunk for slot
    long ra0, ra1;
    {
        int pa0 = p0 + bm + srow, pa1 = p0 + bm + 128 + srow;
        if (GROUPED) { pa0 = min(pa0, pend - 1); pa1 = min(pa1, pend - 1); }
        ra0 = AIDX ? (long)idxb[pa0] : (long)pa0;
        ra1 = AIDX ? (long)idxb[pa1] : (long)pa1;
    }
    const u16* gA0 = A + ra0 * lda + kBeg + sch * 8;
    const u16* gA1 = A + ra1 * lda + kBeg + sch * 8;
    const u16* gB0 = Bt + (long)(bn + srow) * ldb + kBeg + sch * 8;
    const u16* gB1 = Bt + (long)(bn + 128 + srow) * ldb + kBeg + sch * 8;
    u16* const d0 = lds + tid * 8;
    const int R = 4096;                                      // region stride (u16)

    // ---- fragment read offsets (u16 units within a region) ----
    int offA[4], offB[4];
#pragma unroll
    for (int i = 0; i < 4; i++) {
        int raf = wr * 64 + i * 16 + lr;                     // A row in region
        offA[i] = raf * 32 + ((lg ^ ((raf >> 1) & 3)) * 8);
        int rbf = (wc & 1) * 64 + i * 16 + lr;               // B row in region
        offB[i] = rbf * 32 + ((lg ^ ((rbf >> 1) & 3)) * 8);
    }
    const int regB = 2 + (wc >> 1);

    const f32x4 zero = {0.f, 0.f, 0.f, 0.f};
    f32x4 acc[2][4][4];
#pragma unroll
    for (int qa = 0; qa < 2; qa++)
#pragma unroll
        for (int m = 0; m < 4; m++)
#pragma unroll
            for (int n = 0; n < 4; n++) acc[qa][m][n] = zero;

    const int NT = (kEnd - kBeg) >> 5;

    // prologue: tile 0 -> buf0 (order A0,B0 then A1,B1 for vmcnt ring)
    gld16(d0 + 0 * R, gA0);
    gld16(d0 + 2 * R, gB0);
    gld16(d0 + 1 * R, gA1);
    gld16(d0 + 3 * R, gB1);

    for (int t = 0; t < NT; t++) {
        const int buf = t & 1;
        const u16* bb_ = lds + buf * 4 * R;
        u16* dn = d0 + (buf ^ 1) * 4 * R;
        const long ko = (long)(t + 1) * 32;

        if (t + 1 < NT) {
            gld16(dn + 0 * R, gA0 + ko);
            gld16(dn + 2 * R, gB0 + ko);
            VMW(2);                      // drain A1,B1(t) -> tile t fully resident
        } else {
            VMW(0);
        }
        BARR();

        bf16x8 bv[4], av[4];
#pragma unroll
        for (int n = 0; n < 4; n++)
            bv[n] = *reinterpret_cast<const bf16x8*>(bb_ + regB * R + offB[n]);
#pragma unroll
        for (int m = 0; m < 4; m++)
            av[m] = *reinterpret_cast<const bf16x8*>(bb_ + 0 * R + offA[m]);
        __builtin_amdgcn_s_setprio(1);
#pragma unroll
        for (int m = 0; m < 4; m++)
#pragma unroll
            for (int n = 0; n < 4; n++)
                acc[0][m][n] = __builtin_amdgcn_mfma_f32_16x16x32_bf16(av[m], bv[n], acc[0][m][n], 0, 0, 0);
        __builtin_amdgcn_s_setprio(0);

        if (t + 1 < NT) {
            gld16(dn + 1 * R, gA1 + ko);
            gld16(dn + 3 * R, gB1 + ko);
        }
#pragma unroll
        for (int m = 0; m < 4; m++)
            av[m] = *reinterpret_cast<const bf16x8*>(bb_ + 1 * R + offA[m]);
        __builtin_amdgcn_s_setprio(1);
#pragma unroll
        for (int m = 0; m < 4; m++)
#pragma unroll
            for (int n = 0; n < 4; n++)
                acc[1][m][n] = __builtin_amdgcn_mfma_f32_16x16x32_bf16(av[m], bv[n], acc[1][m][n], 0, 0, 0);
        __builtin_amdgcn_s_setprio(0);
        BARR();
    }

    // ---- epilogue ----
#pragma unroll
    for (int qa = 0; qa < 2; qa++) {
#pragma unroll
        for (int m = 0; m < 4; m++) {
#pragma unroll
            for (int r = 0; r < 4; r++) {
                int prow = p0 + bm + qa * 128 + wr * 64 + m * 16 + lg * 4 + r;
                if (GROUPED && prow >= pend) continue;
                long crow = CIDX ? (long)idxb[prow] : (long)prow;
#pragma unroll
                for (int n = 0; n < 4; n++) {
                    int gn = bn + wc * 64 + n * 16 + lr;
                    float v = acc[qa][m][n][r];
                    long off = crow * (long)ldc + gn;
                    if (KS > 1 && ks > 0) {
                        Cpart[(long)(ks - 1) * partStride + off] = v;
                    } else {
                        if (MODE == EP_GELU_BF16) {
                            v += bias[gn];
                            v = 0.5f * v * (1.0f + erff(v * 0.70710678118654752f));
                        }
                        if (MODE == EP_BIAS_F32) v += bias[gn];
                        if (MODE == EP_BF16 || MODE == EP_GELU_BF16)
                            ((u16*)Cv)[off] = f2b(v);
                        else
                            ((float*)Cv)[off] = v;
                    }
                }
            }
        }
    }
}

// ---------------------------------------------------------------- split-K reduce
__global__ void k_red2(float* __restrict__ H, const float* __restrict__ P1,
                       const float* __restrict__ P2, int n4) {
    int i = blockIdx.x * 256 + threadIdx.x;
    if (i >= n4) return;
    float4 h = reinterpret_cast<float4*>(H)[i];
    float4 a = reinterpret_cast<const float4*>(P1)[i];
    float4 b = reinterpret_cast<const float4*>(P2)[i];
    h.x += a.x + b.x; h.y += a.y + b.y; h.z += a.z + b.z; h.w += a.w + b.w;
    reinterpret_cast<float4*>(H)[i] = h;
}

// ---------------------------------------------------------------- attention
// (unchanged from round 5: chunk-XOR swizzled sK/sV/sP, 64-bit dead-masks)
__global__ __launch_bounds__(256)
void k_attn(const u16* __restrict__ cat, const int* __restrict__ types,
            const int* __restrict__ seql, u16* __restrict__ AG)
{
    const int qt = blockIdx.x, h = blockIdx.y, b = blockIdx.z;
    const int tid = threadIdx.x, w = tid >> 6, lane = tid & 63;
    const int lg = lane >> 4, lr = lane & 15;
    const int qbase = qt * 64;

    __shared__ u16 sK[64 * 64];
    __shared__ u16 sV[64 * 64];
    __shared__ u16 sP[4 * 16 * 64];
    __shared__ unsigned long long smask[2];

    const int seqlen = seql[b];

    const long qrow = (long)(b * L_ + qbase + w * 16 + lr);
    const u16* qp = cat + qrow * 4096 + h * 64;
    bf16x8 qf0 = *reinterpret_cast<const bf16x8*>(qp + lg * 8);
    bf16x8 qf1 = *reinterpret_cast<const bf16x8*>(qp + 32 + lg * 8);

    const f32x4 zero = {0.f, 0.f, 0.f, 0.f};
    f32x4 o[4] = {zero, zero, zero, zero};
    float mrow[4] = {-1e30f, -1e30f, -1e30f, -1e30f};
    float lsum[4] = {0.f, 0.f, 0.f, 0.f};

    for (int kb = 0; kb < L_; kb += 64) {
        if (kb >= seqlen) break;
        {
            int c0 = tid, c1 = 256 + tid;
            int r0_ = c0 >> 3, s0_ = (c0 & 7) ^ (r0_ & 7);
            int r1_ = c1 >> 3, s1_ = (c1 & 7) ^ (r1_ & 7);
            gld16(sK + c0 * 8, cat + (long)(b * L_ + kb + r0_) * 4096 + 1024 + h * 64 + s0_ * 8);
            gld16(sK + c1 * 8, cat + (long)(b * L_ + kb + r1_) * 4096 + 1024 + h * 64 + s1_ * 8);
        }
        {
            int key = tid & 63, dkb = (tid >> 6) * 16;
            const u16* vs = cat + (long)(b * L_ + kb + key) * 4096 + 2048 + h * 64 + dkb;
            u16x8 v0 = *reinterpret_cast<const u16x8*>(vs);
            u16x8 v1 = *reinterpret_cast<const u16x8*>(vs + 8);
            int kc = key >> 3, kb7 = key & 7;
#pragma unroll
            for (int e = 0; e < 8; e++)
                sV[(dkb + e) * 64 + (kc ^ (e & 7)) * 8 + kb7] = v0[e];
#pragma unroll
            for (int e = 0; e < 8; e++)
                sV[(dkb + 8 + e) * 64 + (kc ^ (e & 7)) * 8 + kb7] = v1[e];
        }
        if (w == 0) {
            int j = kb + lane;
            bool pad = (j >= seqlen);
            bool prompt = types[b * L_ + j] < 3;
            unsigned long long pm = __ballot(pad);
            unsigned long long rm = __ballot(prompt);
            if (lane == 0) { smask[0] = pm; smask[1] = rm; }
        }
        __syncthreads();
        const unsigned long long padm = smask[0], prm = smask[1];

        f32x4 s[4];
#pragma unroll
        for (int n = 0; n < 4; n++) {
            int row = n * 16 + lr, m7 = row & 7;
            bf16x8 bk0 = *reinterpret_cast<const bf16x8*>(sK + row * 64 + (lg ^ m7) * 8);
            bf16x8 bk1 = *reinterpret_cast<const bf16x8*>(sK + row * 64 + ((lg ^ 4) ^ m7) * 8);
            f32x4 t4 = zero;
            t4 = __builtin_amdgcn_mfma_f32_16x16x32_bf16(qf0, bk0, t4, 0, 0, 0);
            t4 = __builtin_amdgcn_mfma_f32_16x16x32_bf16(qf1, bk1, t4, 0, 0, 0);
            s[n] = t4;
        }
        unsigned long long dmask[4];
#pragma unroll
        for (int r = 0; r < 4; r++) {
            int ig = qbase + w * 16 + 4 * lg + r;
            int d = ig - kb;
            unsigned long long him = (d >= 63) ? 0ull
                                   : ((d < 0) ? ~0ull : (~0ull << (d + 1)));
            dmask[r] = padm | (~prm & him);
        }
        float tmax[4] = {-1e30f, -1e30f, -1e30f, -1e30f};
#pragma unroll
        for (int n = 0; n < 4; n++) {
            int jloc = n * 16 + lr;
#pragma unroll
            for (int r = 0; r < 4; r++) {
                bool dead = (dmask[r] >> jloc) & 1ull;
                float sv = dead ? -1e30f : s[n][r] * 0.125f;
                s[n][r] = sv;
                tmax[r] = fmaxf(tmax[r], sv);
            }
        }
#pragma unroll
        for (int r = 0; r < 4; r++) {
#pragma unroll
            for (int d = 1; d < 16; d <<= 1)
                tmax[r] = fmaxf(tmax[r], __shfl_xor(tmax[r], d, 64));
        }
        float corr[4], rsum[4];
#pragma unroll
        for (int r = 0; r < 4; r++) {
            float mnew = fmaxf(mrow[r], tmax[r]);
            corr[r] = __expf(mrow[r] - mnew);
            mrow[r] = mnew;
            rsum[r] = 0.f;
        }
#pragma unroll
        for (int n = 0; n < 4; n++)
#pragma unroll
            for (int r = 0; r < 4; r++) {
                float p = __expf(s[n][r] - mrow[r]);
                s[n][r] = p;
                rsum[r] += p;
            }
#pragma unroll
        for (int r = 0; r < 4; r++) {
#pragma unroll
            for (int d = 1; d < 16; d <<= 1) rsum[r] += __shfl_xor(rsum[r], d, 64);
            lsum[r] = lsum[r] * corr[r] + rsum[r];
        }
#pragma unroll
        for (int n2 = 0; n2 < 4; n2++) {
            f32x4 t4 = o[n2];
#pragma unroll
            for (int r = 0; r < 4; r++) t4[r] *= corr[r];
            o[n2] = t4;
        }
        u16* Pw = sP + w * 1024;
#pragma unroll
        for (int n = 0; n < 4; n++) {
            int pc = n * 2 + (lr >> 3), p7 = lr & 7;
#pragma unroll
            for (int r = 0; r < 4; r++) {
                int q = 4 * lg + r;
                Pw[q * 64 + (pc ^ (q & 7)) * 8 + p7] = f2b(s[n][r]);
            }
        }
        int l7 = lr & 7;
        bf16x8 pa0 = *reinterpret_cast<const bf16x8*>(Pw + lr * 64 + (lg ^ l7) * 8);
        bf16x8 pa1 = *reinterpret_cast<const bf16x8*>(Pw + lr * 64 + ((lg ^ 4) ^ l7) * 8);
#pragma unroll
        for (int n2 = 0; n2 < 4; n2++) {
            int drow = n2 * 16 + lr, d7 = drow & 7;
            bf16x8 vb0 = *reinterpret_cast<const bf16x8*>(sV + drow * 64 + (lg ^ d7) * 8);
            bf16x8 vb1 = *reinterpret_cast<const bf16x8*>(sV + drow * 64 + ((lg ^ 4) ^ d7) * 8);
            o[n2] = __builtin_amdgcn_mfma_f32_16x16x32_bf16(pa0, vb0, o[n2], 0, 0, 0);
            o[n2] = __builtin_amdgcn_mfma_f32_16x16x32_bf16(pa1, vb1, o[n2], 0, 0, 0);
        }
        __syncthreads();
    }
#pragma unroll
    for (int n2 = 0; n2 < 4; n2++) {
#pragma unroll
        for (int r = 0; r < 4; r++) {
            int ig = qbase + w * 16 + 4 * lg + r;
            long orow = (long)(b * L_ + ig);
            int j = n2 * 16 + lr;
            float u = b2f(cat[orow * 4096 + 3072 + h * 64 + j]);
            float val = o[n2][r] / lsum[r] * u;
            AG[orow * 1024 + h * 64 + j] = f2b(val);
        }
    }
}

// ---------------------------------------------------------------- layernorm (per token)
template <bool WB>
__global__ __launch_bounds__(256)
void k_ln(const float* __restrict__ xa, const float* __restrict__ ha,
          const float* __restrict__ g, const float* __restrict__ bb,
          const int* __restrict__ types,
          float* __restrict__ of, u16* __restrict__ ob)
{
    const int tok = blockIdx.x, tid = threadIdx.x;
    const long base = (long)tok * D_;
    float4 va = reinterpret_cast<const float4*>(xa + base)[tid];
    float4 vh = reinterpret_cast<const float4*>(ha + base)[tid];
    float v0 = va.x + vh.x, v1 = va.y + vh.y, v2 = va.z + vh.z, v3 = va.w + vh.w;
    float s = v0 + v1 + v2 + v3;
    float ss = v0 * v0 + v1 * v1 + v2 * v2 + v3 * v3;
#pragma unroll
    for (int d = 1; d < 64; d <<= 1) { s += __shfl_xor(s, d, 64); ss += __shfl_xor(ss, d, 64); }
    __shared__ float red[8];
    if ((tid & 63) == 0) { red[tid >> 6] = s; red[4 + (tid >> 6)] = ss; }
    __syncthreads();
    s  = red[0] + red[1] + red[2] + red[3];
    ss = red[4] + red[5] + red[6] + red[7];
    const float mu  = s * (1.f / D_);
    const float var = ss * (1.f / D_) - mu * mu;
    const float inv = rsqrtf(var + 1e-5f);
    const int t = types[tok];
    const float* gp = g + (long)t * D_ + tid * 4;
    const float* bp = bb + (long)t * D_ + tid * 4;
    float o0 = (v0 - mu) * inv * gp[0] + bp[0];
    float o1 = (v1 - mu) * inv * gp[1] + bp[1];
    float o2 = (v2 - mu) * inv * gp[2] + bp[2];
    float o3 = (v3 - mu) * inv * gp[3] + bp[3];
    reinterpret_cast<float4*>(of + base)[tid] = make_float4(o0, o1, o2, o3);
    if (WB) {
        ushort4 u4;
        u4.x = f2b(o0); u4.y = f2b(o1); u4.z = f2b(o2); u4.w = f2b(o3);
        reinterpret_cast<ushort4*>(ob + base)[tid] = u4;
    }
}

// ---------------------------------------------------------------- token-type bucketing
__global__ void k_count(const int* __restrict__ types, int* __restrict__ cnt) {
    int i = blockIdx.x * 256 + threadIdx.x;
    if (i < NTOK) atomicAdd(&cnt[types[i]], 1);
}
__global__ void k_scan(int* __restrict__ base) {
    if (threadIdx.x == 0) {
        int a = 0;
        for (int t = 0; t < T_; t++) { base[4 + t] = a; base[8 + t] = a; a += base[t]; }
    }
}
__global__ void k_fill(const int* __restrict__ types, int* __restrict__ cur, int* __restrict__ idxb) {
    int i = blockIdx.x * 256 + threadIdx.x;
    if (i < NTOK) {
        int p = atomicAdd(&cur[types[i]], 1);
        idxb[p] = i;
    }
}

// ---------------------------------------------------------------- launch
extern "C" void kernel_launch(void* const* d_in, const int* in_sizes, int n_in,
                              void* d_out, int out_size, void* d_ws, size_t ws_size,
                              hipStream_t stream) {
    const float* x    = (const float*)d_in[0];
    const int* types  = (const int*)d_in[1];
    const int* seql   = (const int*)d_in[2];
    const float* Wq   = (const float*)d_in[3];
    const float* Wk   = (const float*)d_in[4];
    const float* Wv   = (const float*)d_in[5];
    const float* Wu   = (const float*)d_in[6];
    const float* Wo   = (const float*)d_in[7];
    const float* ln1g = (const float*)d_in[8];
    const float* ln1b = (const float*)d_in[9];
    const float* W1   = (const float*)d_in[10];
    const float* b1   = (const float*)d_in[11];
    const float* W2   = (const float*)d_in[12];
    const float* b2   = (const float*)d_in[13];
    const float* ln2g = (const float*)d_in[14];
    const float* ln2b = (const float*)d_in[15];

    char* ws = (char*)d_ws;
    constexpr size_t OFF_WT  = 0;                                   // QKVU^T cat [4096][1024] bf16
    constexpr size_t OFF_WOT = OFF_WT  + (size_t)4096 * 1024 * 2;   // Wo^T [1024][1024] bf16
    constexpr size_t OFF_W1T = OFF_WOT + (size_t)1024 * 1024 * 2;   // W1^T [T][4096][1024] bf16; reused as FFN2 split-K partials (2 x 16MB)
    constexpr size_t OFF_W2T = OFF_W1T + (size_t)T_ * 4096 * 1024 * 2; // W2^T [T][1024][4096] bf16
    constexpr size_t OFF_XB  = OFF_W2T + (size_t)T_ * 4096 * 1024 * 2; // x bf16 (later: AG)
    constexpr size_t OFF_CAT = OFF_XB  + (size_t)NTOK * D_ * 2;     // QKVU cat (later: FFN hidden)
    constexpr size_t OFF_H   = OFF_CAT + (size_t)NTOK * 4096 * 2;   // h f32 (later: h2 / split-K P0)
    constexpr size_t OFF_X1  = OFF_H   + (size_t)NTOK * D_ * 4;     // x1 f32
    constexpr size_t OFF_X1B = OFF_X1  + (size_t)NTOK * D_ * 4;     // x1 bf16
    constexpr size_t OFF_INT = OFF_X1B + (size_t)NTOK * D_ * 2;     // cnt/off/cur + idx

    u16* WT   = (u16*)(ws + OFF_WT);
    u16* WOT  = (u16*)(ws + OFF_WOT);
    u16* W1T  = (u16*)(ws + OFF_W1T);
    u16* W2T  = (u16*)(ws + OFF_W2T);
    u16* XB   = (u16*)(ws + OFF_XB);      // also AG
    u16* CAT  = (u16*)(ws + OFF_CAT);     // also Hidden
    float* Hb = (float*)(ws + OFF_H);
    float* X1 = (float*)(ws + OFF_X1);
    u16* X1B  = (u16*)(ws + OFF_X1B);
    float* Pk = (float*)(ws + OFF_W1T);   // FFN2 split-K partials (aliases W1T)
    int* ibase = (int*)(ws + OFF_INT);
    int* cnt = ibase, *off = ibase + 4, *cur = ibase + 8, *idxb = ibase + 16;

    dim3 blk(256), blk512(512), tb(32, 8);
    const long PSTR = (long)NTOK * D_;    // 4M floats per partial

    // 1. casts / transposes
    k_cast_bf16<<<NTOK * D_ / 4 / 256, blk, 0, stream>>>(x, XB, NTOK * D_ / 4);
    k_tcast<<<dim3(32, 32, 1), tb, 0, stream>>>(Wq, WT + 0 * 1048576, 1024, 1024, 0, 0);
    k_tcast<<<dim3(32, 32, 1), tb, 0, stream>>>(Wk, WT + 1 * 1048576, 1024, 1024, 0, 0);
    k_tcast<<<dim3(32, 32, 1), tb, 0, stream>>>(Wv, WT + 2 * 1048576, 1024, 1024, 0, 0);
    k_tcast<<<dim3(32, 32, 1), tb, 0, stream>>>(Wu, WT + 3 * 1048576, 1024, 1024, 0, 0);
    k_tcast<<<dim3(32, 32, 1), tb, 0, stream>>>(Wo, WOT, 1024, 1024, 0, 0);
    k_tcast<<<dim3(128, 32, T_), tb, 0, stream>>>(W1, W1T, 1024, 4096, (long)1024 * 4096, (long)4096 * 1024);
    k_tcast<<<dim3(32, 128, T_), tb, 0, stream>>>(W2, W2T, 4096, 1024, (long)4096 * 1024, (long)1024 * 4096);

    // 2. QKVU = x @ [Wq|Wk|Wv|Wu]   (M=4096 N=4096 K=1024)
    k_g2<EP_BF16, false, false, false, 1><<<dim3(16, 16), blk512, 0, stream>>>(
        XB, WT, CAT, nullptr, 0, nullptr, nullptr, nullptr, nullptr,
        NTOK, 1024, 1024, 1024, 4096, 0, 0);

    // 3. attention -> gated output AG (reuses XB)
    k_attn<<<dim3(L_ / 64, H_, B_), blk, 0, stream>>>(CAT, types, seql, XB);

    // 4. h = AG @ Wo   (M=4096 N=1024 K=1024), f32
    k_g2<EP_F32, false, false, false, 1><<<dim3(16, 4), blk512, 0, stream>>>(
        XB, WOT, Hb, nullptr, 0, nullptr, nullptr, nullptr, nullptr,
        NTOK, 1024, 1024, 1024, 1024, 0, 0);

    // 5. x1 = LN1(x + h)
    k_ln<true><<<NTOK, blk, 0, stream>>>(x, Hb, ln1g, ln1b, types, X1, X1B);

    // 6. bucket tokens by type
    hipMemsetAsync(cnt, 0, 48, stream);
    k_count<<<NTOK / 256, blk, 0, stream>>>(types, cnt);
    k_scan<<<1, 64, 0, stream>>>(ibase);
    k_fill<<<NTOK / 256, blk, 0, stream>>>(types, cur, idxb);

    // 7. Hidden = gelu(x1[idx] @ W1[t] + b1[t])   (grouped, A indexed)
    k_g2<EP_GELU_BF16, true, false, true, 1><<<dim3(16, 16, T_), blk512, 0, stream>>>(
        X1B, W1T, CAT, nullptr, 0, b1, idxb, off, cnt,
        NTOK, 1024, 1024, 1024, 4096, (long)4096 * 1024, 4096);

    // 8. h2 = Hidden @ W2[t] + b2[t]  (grouped, C scattered, split-K=3; W1T now free -> partials)
    k_g2<EP_BIAS_F32, false, true, true, 3><<<dim3(16, 4, T_ * 3), blk512, 0, stream>>>(
        CAT, W2T, Hb, Pk, PSTR, b2, idxb, off, cnt,
        NTOK, 4096, 4096, 4096, 1024, (long)1024 * 4096, 1024);
    k_red2<<<NTOK * D_ / 4 / 256, blk, 0, stream>>>(Hb, Pk, Pk + PSTR, NTOK * D_ / 4);

    // 9. out = LN2(x1 + h2)
    k_ln<false><<<NTOK, blk, 0, stream>>>(X1, Hb, ln2g, ln2b, types, (float*)d_out, nullptr);
}

// Round 7
// 562.579 us; speedup vs baseline: 1.4499x; 1.0615x over previous
//
#include <hip/hip_runtime.h>
#include <hip/hip_bf16.h>
#include <math.h>

#define B_   2
#define L_   2048
#define D_   1024
#define H_   16
#define DK_  64
#define T_   4
#define F_   4096
#define NTOK (B_ * L_)   // 4096

typedef __bf16 bf16_t;
typedef bf16_t bf16x8 __attribute__((ext_vector_type(8)));
typedef float  f32x4  __attribute__((ext_vector_type(4)));
typedef unsigned short u16;
typedef u16 u16x8 __attribute__((ext_vector_type(8)));
typedef unsigned long long ull;

static __device__ __forceinline__ u16 f2b(float f) {
    __hip_bfloat16 h = __float2bfloat16(f);
    return *reinterpret_cast<u16*>(&h);
}
static __device__ __forceinline__ float b2f(u16 u) {
    __hip_bfloat16 h;
    *reinterpret_cast<u16*>(&h) = u;
    return __bfloat162float(h);
}

// async global->LDS, 16B per lane; LDS dest is linear (uniform base + lane*16)
static __device__ __forceinline__ void gld16(void* lds, const void* g) {
    __builtin_amdgcn_global_load_lds(
        (const __attribute__((address_space(1))) unsigned int*)g,
        (__attribute__((address_space(3))) unsigned int*)lds,
        16, 0, 0);
}

#define VMW(N) do { asm volatile("s_waitcnt vmcnt(" #N ")" ::: "memory"); \
                    __builtin_amdgcn_sched_barrier(0); } while (0)
#define BARR() do { __builtin_amdgcn_sched_barrier(0); \
                    __builtin_amdgcn_s_barrier();      \
                    __builtin_amdgcn_sched_barrier(0); } while (0)

// ---------------------------------------------------------------- cast x -> bf16
__global__ void k_cast_bf16(const float* __restrict__ in, u16* __restrict__ out, int n4) {
    int i = blockIdx.x * 256 + threadIdx.x;
    if (i >= n4) return;
    float4 v = reinterpret_cast<const float4*>(in)[i];
    ushort4 o;
    o.x = f2b(v.x); o.y = f2b(v.y); o.z = f2b(v.z); o.w = f2b(v.w);
    reinterpret_cast<ushort4*>(out)[i] = o;
}

// --------------------------------------------- transpose-cast W (KxN f32) -> Wt (NxK bf16)
__global__ void k_tcast(const float* __restrict__ W, u16* __restrict__ Wt,
                        int K, int N, long sW, long sWt) {
    __shared__ float tile[32][33];
    int z = blockIdx.z;
    W  += (long)z * sW;
    Wt += (long)z * sWt;
    int n0 = blockIdx.x * 32, k0 = blockIdx.y * 32;
    int tx = threadIdx.x, ty = threadIdx.y;   // block (32,8)
#pragma unroll
    for (int i = 0; i < 4; i++)
        tile[ty + 8 * i][tx] = W[(long)(k0 + ty + 8 * i) * N + n0 + tx];
    __syncthreads();
#pragma unroll
    for (int i = 0; i < 4; i++)
        Wt[(long)(n0 + ty + 8 * i) * K + k0 + tx] = f2b(tile[tx][ty + 8 * i]);
}

// ---------------------------------------------------------------- 256x256 8-wave GEMM v2
// (structure unchanged from round 6)
enum { EP_BF16 = 0, EP_F32 = 1, EP_GELU_BF16 = 2, EP_BIAS_F32 = 3 };

template <int MODE, bool AIDX, bool CIDX, bool GROUPED, int KS>
__global__ __launch_bounds__(512, 2)
void k_g2(const u16* __restrict__ A, const u16* __restrict__ Bt,
          void* __restrict__ Cv, float* __restrict__ Cpart, long partStride,
          const float* __restrict__ bias,
          const int* __restrict__ idxb, const int* __restrict__ boff,
          const int* __restrict__ bcnt,
          int M, int K, int lda, int ldb, int ldc,
          long strideB, int biasStride)
{
    int p0 = 0, pend = M, ks = 0;
    if (KS > 1) ks = (int)blockIdx.z % KS;
    if (GROUPED) {
        int g = (KS > 1) ? ((int)blockIdx.z / KS) : (int)blockIdx.z;
        int c = bcnt[g];
        p0 = boff[g]; pend = p0 + c;
        Bt += (long)g * strideB;
        bias += (long)g * biasStride;
    }
    int kBeg = 0, kEnd = K;
    if (KS > 1) {
        int Kc = ((K / KS) + 31) & ~31;
        kBeg = ks * Kc;
        kEnd = min(K, kBeg + Kc);
    }
    const int gx = gridDim.x;
    const int nwg = gx * gridDim.y;
    const int id = blockIdx.y * gx + blockIdx.x;
    const int q8 = nwg >> 3, r8 = nwg & 7, xcd = id & 7, sub = id >> 3;
    const int id2 = (xcd < r8 ? xcd * (q8 + 1) : r8 * (q8 + 1) + (xcd - r8) * q8) + sub;
    const int tm = id2 % gx, tn = id2 / gx;
    if (GROUPED && tm * 256 >= (pend - p0)) return;
    const int bm = tm * 256, bn = tn * 256;

    const int tid = threadIdx.x;
    const int wid = tid >> 6, lane = tid & 63;
    const int lg = lane >> 4, lr = lane & 15;
    const int wr = wid >> 2, wc = wid & 3;

    __shared__ u16 lds[8 * 4096];          // [buf0: A0 A1 B0 B1][buf1: ...]

    const int srow = tid >> 2;                               // 0..127
    const int sch  = (tid & 3) ^ ((srow >> 1) & 3);
    long ra0, ra1;
    {
        int pa0 = p0 + bm + srow, pa1 = p0 + bm + 128 + srow;
        if (GROUPED) { pa0 = min(pa0, pend - 1); pa1 = min(pa1, pend - 1); }
        ra0 = AIDX ? (long)idxb[pa0] : (long)pa0;
        ra1 = AIDX ? (long)idxb[pa1] : (long)pa1;
    }
    const u16* gA0 = A + ra0 * lda + kBeg + sch * 8;
    const u16* gA1 = A + ra1 * lda + kBeg + sch * 8;
    const u16* gB0 = Bt + (long)(bn + srow) * ldb + kBeg + sch * 8;
    const u16* gB1 = Bt + (long)(bn + 128 + srow) * ldb + kBeg + sch * 8;
    u16* const d0 = lds + tid * 8;
    const int R = 4096;

    int offA[4], offB[4];
#pragma unroll
    for (int i = 0; i < 4; i++) {
        int raf = wr * 64 + i * 16 + lr;
        offA[i] = raf * 32 + ((lg ^ ((raf >> 1) & 3)) * 8);
        int rbf = (wc & 1) * 64 + i * 16 + lr;
        offB[i] = rbf * 32 + ((lg ^ ((rbf >> 1) & 3)) * 8);
    }
    const int regB = 2 + (wc >> 1);

    const f32x4 zero = {0.f, 0.f, 0.f, 0.f};
    f32x4 acc[2][4][4];
#pragma unroll
    for (int qa = 0; qa < 2; qa++)
#pragma unroll
        for (int m = 0; m < 4; m++)
#pragma unroll
            for (int n = 0; n < 4; n++) acc[qa][m][n] = zero;

    const int NT = (kEnd - kBeg) >> 5;

    gld16(d0 + 0 * R, gA0);
    gld16(d0 + 2 * R, gB0);
    gld16(d0 + 1 * R, gA1);
    gld16(d0 + 3 * R, gB1);

    for (int t = 0; t < NT; t++) {
        const int buf = t & 1;
        const u16* bb_ = lds + buf * 4 * R;
        u16* dn = d0 + (buf ^ 1) * 4 * R;
        const long ko = (long)(t + 1) * 32;

        if (t + 1 < NT) {
            gld16(dn + 0 * R, gA0 + ko);
            gld16(dn + 2 * R, gB0 + ko);
            VMW(2);
        } else {
            VMW(0);
        }
        BARR();

        bf16x8 bv[4], av[4];
#pragma unroll
        for (int n = 0; n < 4; n++)
            bv[n] = *reinterpret_cast<const bf16x8*>(bb_ + regB * R + offB[n]);
#pragma unroll
        for (int m = 0; m < 4; m++)
            av[m] = *reinterpret_cast<const bf16x8*>(bb_ + 0 * R + offA[m]);
        __builtin_amdgcn_s_setprio(1);
#pragma unroll
        for (int m = 0; m < 4; m++)
#pragma unroll
            for (int n = 0; n < 4; n++)
                acc[0][m][n] = __builtin_amdgcn_mfma_f32_16x16x32_bf16(av[m], bv[n], acc[0][m][n], 0, 0, 0);
        __builtin_amdgcn_s_setprio(0);

        if (t + 1 < NT) {
            gld16(dn + 1 * R, gA1 + ko);
            gld16(dn + 3 * R, gB1 + ko);
        }
#pragma unroll
        for (int m = 0; m < 4; m++)
            av[m] = *reinterpret_cast<const bf16x8*>(bb_ + 1 * R + offA[m]);
        __builtin_amdgcn_s_setprio(1);
#pragma unroll
        for (int m = 0; m < 4; m++)
#pragma unroll
            for (int n = 0; n < 4; n++)
                acc[1][m][n] = __builtin_amdgcn_mfma_f32_16x16x32_bf16(av[m], bv[n], acc[1][m][n], 0, 0, 0);
        __builtin_amdgcn_s_setprio(0);
        BARR();
    }

#pragma unroll
    for (int qa = 0; qa < 2; qa++) {
#pragma unroll
        for (int m = 0; m < 4; m++) {
#pragma unroll
            for (int r = 0; r < 4; r++) {
                int prow = p0 + bm + qa * 128 + wr * 64 + m * 16 + lg * 4 + r;
                if (GROUPED && prow >= pend) continue;
                long crow = CIDX ? (long)idxb[prow] : (long)prow;
#pragma unroll
                for (int n = 0; n < 4; n++) {
                    int gn = bn + wc * 64 + n * 16 + lr;
                    float v = acc[qa][m][n][r];
                    long off = crow * (long)ldc + gn;
                    if (KS > 1 && ks > 0) {
                        Cpart[(long)(ks - 1) * partStride + off] = v;
                    } else {
                        if (MODE == EP_GELU_BF16) {
                            v += bias[gn];
                            v = 0.5f * v * (1.0f + erff(v * 0.70710678118654752f));
                        }
                        if (MODE == EP_BIAS_F32) v += bias[gn];
                        if (MODE == EP_BF16 || MODE == EP_GELU_BF16)
                            ((u16*)Cv)[off] = f2b(v);
                        else
                            ((float*)Cv)[off] = v;
                    }
                }
            }
        }
    }
}

// ---------------------------------------------------------------- split-K reduce
__global__ void k_red2(float* __restrict__ H, const float* __restrict__ P1,
                       const float* __restrict__ P2, int n4) {
    int i = blockIdx.x * 256 + threadIdx.x;
    if (i >= n4) return;
    float4 h = reinterpret_cast<float4*>(H)[i];
    float4 a = reinterpret_cast<const float4*>(P1)[i];
    float4 b = reinterpret_cast<const float4*>(P2)[i];
    h.x += a.x + b.x; h.y += a.y + b.y; h.z += a.z + b.z; h.w += a.w + b.w;
    reinterpret_cast<float4*>(H)[i] = h;
}

// ---------------------------------------------------------------- attention (v3)
// KVBLK=128; softmax in exp2 domain with Q pre-scaled by 0.125*log2(e);
// tile classes: interior (no mask), future (r-uniform mask), diagonal (full mask).
// All LDS tiles chunk-XOR swizzled (verified conflict-free in round 6).
#define KVB 128
__global__ __launch_bounds__(256)
void k_attn(const u16* __restrict__ cat, const int* __restrict__ types,
            const int* __restrict__ seql, u16* __restrict__ AG)
{
    const int qt = blockIdx.x, h = blockIdx.y, b = blockIdx.z;
    const int tid = threadIdx.x, w = tid >> 6, lane = tid & 63;
    const int lg = lane >> 4, lr = lane & 15;
    const int qbase = qt * 64;

    __shared__ u16 sK[KVB * 64];        // [key][dk], chunk = (c ^ (key&7))
    __shared__ u16 sV[64 * KVB];        // [dk][key], chunk = (c ^ (dk&15))
    __shared__ u16 sP[4 * 16 * KVB];    // per-wave [q][key], chunk = (c ^ q)
    __shared__ ull smask[4];            // pad0, pr0, pad1, pr1

    const int seqlen = seql[b];
    const float QSC = 0.125f * 1.44269504f;   // log2(e)/8

    // Q fragments, pre-scaled to exp2 domain
    const long qrow = (long)(b * L_ + qbase + w * 16 + lr);
    const u16* qp = cat + qrow * 4096 + h * 64;
    bf16x8 qf0, qf1;
    {
        u16x8 a0 = *reinterpret_cast<const u16x8*>(qp + lg * 8);
        u16x8 a1 = *reinterpret_cast<const u16x8*>(qp + 32 + lg * 8);
#pragma unroll
        for (int e = 0; e < 8; e++) {
            qf0[e] = (bf16_t)(b2f(a0[e]) * QSC);
            qf1[e] = (bf16_t)(b2f(a1[e]) * QSC);
        }
    }

    const f32x4 zero = {0.f, 0.f, 0.f, 0.f};
    f32x4 o[4] = {zero, zero, zero, zero};
    float mrow[4] = {-1e30f, -1e30f, -1e30f, -1e30f};
    float lsum[4] = {0.f, 0.f, 0.f, 0.f};

    for (int kb = 0; kb < L_; kb += KVB) {
        if (kb >= seqlen) break;   // uniform per block
        // stage K tile: linear LDS dest, pre-swizzled global source (4 gld16/thread)
        {
#pragma unroll
            for (int i = 0; i < 4; i++) {
                int c = tid + 256 * i;
                int row = c >> 3, sl = (c & 7) ^ (row & 7);
                gld16(sK + c * 8, cat + (long)(b * L_ + kb + row) * 4096 + 1024 + h * 64 + sl * 8);
            }
        }
        // stage V transposed (register path), swizzled write: 32 dk x 1 key per thread
        {
            int key = tid & 127, dkb = (tid >> 7) * 32;
            const u16* vs = cat + (long)(b * L_ + kb + key) * 4096 + 2048 + h * 64 + dkb;
            int kc = key >> 3, k7 = key & 7;
#pragma unroll
            for (int q = 0; q < 4; q++) {
                u16x8 v = *reinterpret_cast<const u16x8*>(vs + q * 8);
#pragma unroll
                for (int e = 0; e < 8; e++) {
                    int row = dkb + q * 8 + e;
                    sV[row * KVB + (kc ^ (row & 15)) * 8 + k7] = v[e];
                }
            }
        }
        if (w < 2) {
            int j = kb + w * 64 + lane;
            ull pm = __ballot(j >= seqlen);
            ull rm = __ballot(types[b * L_ + j] < 3);
            if (lane == 0) { smask[w * 2] = pm; smask[w * 2 + 1] = rm; }
        }
        __syncthreads();
        const ull pad0 = smask[0], pr0 = smask[1], pad1 = smask[2], pr1 = smask[3];

        // S = Q K^T  (16 q-rows x 128 keys per wave), exp2 domain
        f32x4 s[8];
#pragma unroll
        for (int n = 0; n < 8; n++) {
            int row = n * 16 + lr, r7 = row & 7;
            bf16x8 bk0 = *reinterpret_cast<const bf16x8*>(sK + row * 64 + ((lg ^ r7)) * 8);
            bf16x8 bk1 = *reinterpret_cast<const bf16x8*>(sK + row * 64 + (((lg ^ 4)) ^ r7) * 8);
            f32x4 t4 = zero;
            t4 = __builtin_amdgcn_mfma_f32_16x16x32_bf16(qf0, bk0, t4, 0, 0, 0);
            t4 = __builtin_amdgcn_mfma_f32_16x16x32_bf16(qf1, bk1, t4, 0, 0, 0);
            s[n] = t4;
        }

        // ---- masking with tile-class fast paths (block-uniform branch) ----
        float tmax[4] = {-1e30f, -1e30f, -1e30f, -1e30f};
        const bool interior = (kb + KVB <= qbase) && (kb + KVB <= seqlen);
        const bool future   = (kb > qbase + 63);
        if (interior) {
#pragma unroll
            for (int n = 0; n < 8; n++)
#pragma unroll
                for (int r = 0; r < 4; r++) tmax[r] = fmaxf(tmax[r], s[n][r]);
        } else if (future) {
            const ull d0 = pad0 | ~pr0, d1 = pad1 | ~pr1;   // r-uniform dead mask
#pragma unroll
            for (int n = 0; n < 8; n++) {
                bool dead = (((n < 4) ? d0 : d1) >> (((n & 3) * 16 + lr))) & 1ull;
#pragma unroll
                for (int r = 0; r < 4; r++) {
                    float sv = dead ? -1e30f : s[n][r];
                    s[n][r] = sv;
                    tmax[r] = fmaxf(tmax[r], sv);
                }
            }
        } else {
            ull dm0[4], dm1[4];
#pragma unroll
            for (int r = 0; r < 4; r++) {
                int d = qbase + w * 16 + 4 * lg + r - kb;
                ull h0 = (d < 0) ? ~0ull : ((d >= 63) ? 0ull : (~0ull << (d + 1)));
                ull h1 = (d < 64) ? ~0ull : ((d >= 127) ? 0ull : (~0ull << (d - 63)));
                dm0[r] = pad0 | (~pr0 & h0);
                dm1[r] = pad1 | (~pr1 & h1);
            }
#pragma unroll
            for (int n = 0; n < 8; n++) {
                int bp = (n & 3) * 16 + lr;
#pragma unroll
                for (int r = 0; r < 4; r++) {
                    bool dead = (((n < 4) ? dm0[r] : dm1[r]) >> bp) & 1ull;
                    float sv = dead ? -1e30f : s[n][r];
                    s[n][r] = sv;
                    tmax[r] = fmaxf(tmax[r], sv);
                }
            }
        }
#pragma unroll
        for (int r = 0; r < 4; r++) {
#pragma unroll
            for (int d = 1; d < 16; d <<= 1)
                tmax[r] = fmaxf(tmax[r], __shfl_xor(tmax[r], d, 64));
        }
        float corr[4], rsum[4];
#pragma unroll
        for (int r = 0; r < 4; r++) {
            float mnew = fmaxf(mrow[r], tmax[r]);
            corr[r] = __builtin_amdgcn_exp2f(mrow[r] - mnew);
            mrow[r] = mnew;
            rsum[r] = 0.f;
        }
#pragma unroll
        for (int n = 0; n < 8; n++)
#pragma unroll
            for (int r = 0; r < 4; r++) {
                float p = __builtin_amdgcn_exp2f(s[n][r] - mrow[r]);
                s[n][r] = p;
                rsum[r] += p;
            }
#pragma unroll
        for (int r = 0; r < 4; r++) {
#pragma unroll
            for (int d = 1; d < 16; d <<= 1) rsum[r] += __shfl_xor(rsum[r], d, 64);
            lsum[r] = lsum[r] * corr[r] + rsum[r];
        }
#pragma unroll
        for (int n2 = 0; n2 < 4; n2++) {
            f32x4 t4 = o[n2];
#pragma unroll
            for (int r = 0; r < 4; r++) t4[r] *= corr[r];
            o[n2] = t4;
        }
        // P -> LDS (per-wave region), swizzled write
        u16* Pw = sP + w * (16 * KVB);
#pragma unroll
        for (int n = 0; n < 8; n++) {
            int pc = n * 2 + (lr >> 3), p7 = lr & 7;
#pragma unroll
            for (int r = 0; r < 4; r++) {
                int q = 4 * lg + r;
                Pw[q * KVB + (pc ^ q) * 8 + p7] = f2b(s[n][r]);
            }
        }
        // PV: 4 k-steps of 32 keys
        bf16x8 pa[4];
#pragma unroll
        for (int st = 0; st < 4; st++)
            pa[st] = *reinterpret_cast<const bf16x8*>(Pw + lr * KVB + ((st * 4 + lg) ^ lr) * 8);
#pragma unroll
        for (int n2 = 0; n2 < 4; n2++) {
            int row = n2 * 16 + lr, r15 = row & 15;
            f32x4 t4 = o[n2];
#pragma unroll
            for (int st = 0; st < 4; st++) {
                bf16x8 vb = *reinterpret_cast<const bf16x8*>(sV + row * KVB + ((st * 4 + lg) ^ r15) * 8);
                t4 = __builtin_amdgcn_mfma_f32_16x16x32_bf16(pa[st], vb, t4, 0, 0, 0);
            }
            o[n2] = t4;
        }
        __syncthreads();
    }
    // epilogue: normalize, U-gate, store bf16
#pragma unroll
    for (int n2 = 0; n2 < 4; n2++) {
#pragma unroll
        for (int r = 0; r < 4; r++) {
            int ig = qbase + w * 16 + 4 * lg + r;
            long orow = (long)(b * L_ + ig);
            int j = n2 * 16 + lr;
            float u = b2f(cat[orow * 4096 + 3072 + h * 64 + j]);
            float val = o[n2][r] / lsum[r] * u;
            AG[orow * 1024 + h * 64 + j] = f2b(val);
        }
    }
}

// ---------------------------------------------------------------- layernorm (per token)
template <bool WB>
__global__ __launch_bounds__(256)
void k_ln(const float* __restrict__ xa, const float* __restrict__ ha,
          const float* __restrict__ g, const float* __restrict__ bb,
          const int* __restrict__ types,
          float* __restrict__ of, u16* __restrict__ ob)
{
    const int tok = blockIdx.x, tid = threadIdx.x;
    const long base = (long)tok * D_;
    float4 va = reinterpret_cast<const float4*>(xa + base)[tid];
    float4 vh = reinterpret_cast<const float4*>(ha + base)[tid];
    float v0 = va.x + vh.x, v1 = va.y + vh.y, v2 = va.z + vh.z, v3 = va.w + vh.w;
    float s = v0 + v1 + v2 + v3;
    float ss = v0 * v0 + v1 * v1 + v2 * v2 + v3 * v3;
#pragma unroll
    for (int d = 1; d < 64; d <<= 1) { s += __shfl_xor(s, d, 64); ss += __shfl_xor(ss, d, 64); }
    __shared__ float red[8];
    if ((tid & 63) == 0) { red[tid >> 6] = s; red[4 + (tid >> 6)] = ss; }
    __syncthreads();
    s  = red[0] + red[1] + red[2] + red[3];
    ss = red[4] + red[5] + red[6] + red[7];
    const float mu  = s * (1.f / D_);
    const float var = ss * (1.f / D_) - mu * mu;
    const float inv = rsqrtf(var + 1e-5f);
    const int t = types[tok];
    const float* gp = g + (long)t * D_ + tid * 4;
    const float* bp = bb + (long)t * D_ + tid * 4;
    float o0 = (v0 - mu) * inv * gp[0] + bp[0];
    float o1 = (v1 - mu) * inv * gp[1] + bp[1];
    float o2 = (v2 - mu) * inv * gp[2] + bp[2];
    float o3 = (v3 - mu) * inv * gp[3] + bp[3];
    reinterpret_cast<float4*>(of + base)[tid] = make_float4(o0, o1, o2, o3);
    if (WB) {
        ushort4 u4;
        u4.x = f2b(o0); u4.y = f2b(o1); u4.z = f2b(o2); u4.w = f2b(o3);
        reinterpret_cast<ushort4*>(ob + base)[tid] = u4;
    }
}

// ---------------------------------------------------------------- token-type bucketing
__global__ void k_count(const int* __restrict__ types, int* __restrict__ cnt) {
    int i = blockIdx.x * 256 + threadIdx.x;
    if (i < NTOK) atomicAdd(&cnt[types[i]], 1);
}
__global__ void k_scan(int* __restrict__ base) {
    if (threadIdx.x == 0) {
        int a = 0;
        for (int t = 0; t < T_; t++) { base[4 + t] = a; base[8 + t] = a; a += base[t]; }
    }
}
__global__ void k_fill(const int* __restrict__ types, int* __restrict__ cur, int* __restrict__ idxb) {
    int i = blockIdx.x * 256 + threadIdx.x;
    if (i < NTOK) {
        int p = atomicAdd(&cur[types[i]], 1);
        idxb[p] = i;
    }
}

// ---------------------------------------------------------------- launch
extern "C" void kernel_launch(void* const* d_in, const int* in_sizes, int n_in,
                              void* d_out, int out_size, void* d_ws, size_t ws_size,
                              hipStream_t stream) {
    const float* x    = (const float*)d_in[0];
    const int* types  = (const int*)d_in[1];
    const int* seql   = (const int*)d_in[2];
    const float* Wq   = (const float*)d_in[3];
    const float* Wk   = (const float*)d_in[4];
    const float* Wv   = (const float*)d_in[5];
    const float* Wu   = (const float*)d_in[6];
    const float* Wo   = (const float*)d_in[7];
    const float* ln1g = (const float*)d_in[8];
    const float* ln1b = (const float*)d_in[9];
    const float* W1   = (const float*)d_in[10];
    const float* b1   = (const float*)d_in[11];
    const float* W2   = (const float*)d_in[12];
    const float* b2   = (const float*)d_in[13];
    const float* ln2g = (const float*)d_in[14];
    const float* ln2b = (const float*)d_in[15];

    char* ws = (char*)d_ws;
    constexpr size_t OFF_WT  = 0;                                   // QKVU^T cat [4096][1024] bf16
    constexpr size_t OFF_WOT = OFF_WT  + (size_t)4096 * 1024 * 2;   // Wo^T [1024][1024] bf16
    constexpr size_t OFF_W1T = OFF_WOT + (size_t)1024 * 1024 * 2;   // W1^T; reused as FFN2 split-K partials
    constexpr size_t OFF_W2T = OFF_W1T + (size_t)T_ * 4096 * 1024 * 2; // W2^T
    constexpr size_t OFF_XB  = OFF_W2T + (size_t)T_ * 4096 * 1024 * 2; // x bf16 (later: AG)
    constexpr size_t OFF_CAT = OFF_XB  + (size_t)NTOK * D_ * 2;     // QKVU cat (later: Wo split-K partials, then FFN hidden)
    constexpr size_t OFF_H   = OFF_CAT + (size_t)NTOK * 4096 * 2;   // h f32
    constexpr size_t OFF_X1  = OFF_H   + (size_t)NTOK * D_ * 4;     // x1 f32
    constexpr size_t OFF_X1B = OFF_X1  + (size_t)NTOK * D_ * 4;     // x1 bf16
    constexpr size_t OFF_INT = OFF_X1B + (size_t)NTOK * D_ * 2;     // cnt/off/cur + idx

    u16* WT   = (u16*)(ws + OFF_WT);
    u16* WOT  = (u16*)(ws + OFF_WOT);
    u16* W1T  = (u16*)(ws + OFF_W1T);
    u16* W2T  = (u16*)(ws + OFF_W2T);
    u16* XB   = (u16*)(ws + OFF_XB);      // also AG
    u16* CAT  = (u16*)(ws + OFF_CAT);     // also Wo partials / Hidden
    float* Hb = (float*)(ws + OFF_H);
    float* X1 = (float*)(ws + OFF_X1);
    u16* X1B  = (u16*)(ws + OFF_X1B);
    float* PkF = (float*)(ws + OFF_W1T);  // FFN2 split-K partials (aliases W1T, free after FFN1)
    float* PkW = (float*)(ws + OFF_CAT);  // Wo split-K partials (CAT free between attn and FFN1)
    int* ibase = (int*)(ws + OFF_INT);
    int* cnt = ibase, *off = ibase + 4, *cur = ibase + 8, *idxb = ibase + 16;

    dim3 blk(256), blk512(512), tb(32, 8);
    const long PSTR = (long)NTOK * D_;    // 4M floats per partial

    // 1. casts / transposes
    k_cast_bf16<<<NTOK * D_ / 4 / 256, blk, 0, stream>>>(x, XB, NTOK * D_ / 4);
    k_tcast<<<dim3(32, 32, 1), tb, 0, stream>>>(Wq, WT + 0 * 1048576, 1024, 1024, 0, 0);
    k_tcast<<<dim3(32, 32, 1), tb, 0, stream>>>(Wk, WT + 1 * 1048576, 1024, 1024, 0, 0);
    k_tcast<<<dim3(32, 32, 1), tb, 0, stream>>>(Wv, WT + 2 * 1048576, 1024, 1024, 0, 0);
    k_tcast<<<dim3(32, 32, 1), tb, 0, stream>>>(Wu, WT + 3 * 1048576, 1024, 1024, 0, 0);
    k_tcast<<<dim3(32, 32, 1), tb, 0, stream>>>(Wo, WOT, 1024, 1024, 0, 0);
    k_tcast<<<dim3(128, 32, T_), tb, 0, stream>>>(W1, W1T, 1024, 4096, (long)1024 * 4096, (long)4096 * 1024);
    k_tcast<<<dim3(32, 128, T_), tb, 0, stream>>>(W2, W2T, 4096, 1024, (long)4096 * 1024, (long)1024 * 4096);

    // 2. QKVU = x @ [Wq|Wk|Wv|Wu]   (M=4096 N=4096 K=1024)
    k_g2<EP_BF16, false, false, false, 1><<<dim3(16, 16), blk512, 0, stream>>>(
        XB, WT, CAT, nullptr, 0, nullptr, nullptr, nullptr, nullptr,
        NTOK, 1024, 1024, 1024, 4096, 0, 0);

    // 3. attention -> gated output AG (reuses XB)
    k_attn<<<dim3(L_ / 64, H_, B_), blk, 0, stream>>>(CAT, types, seql, XB);

    // 4. h = AG @ Wo (split-K=3; partials in CAT, which is free until FFN1)
    k_g2<EP_F32, false, false, false, 3><<<dim3(16, 4, 3), blk512, 0, stream>>>(
        XB, WOT, Hb, PkW, PSTR, nullptr, nullptr, nullptr, nullptr,
        NTOK, 1024, 1024, 1024, 1024, 0, 0);
    k_red2<<<NTOK * D_ / 4 / 256, blk, 0, stream>>>(Hb, PkW, PkW + PSTR, NTOK * D_ / 4);

    // 5. x1 = LN1(x + h)
    k_ln<true><<<NTOK, blk, 0, stream>>>(x, Hb, ln1g, ln1b, types, X1, X1B);

    // 6. bucket tokens by type
    hipMemsetAsync(cnt, 0, 48, stream);
    k_count<<<NTOK / 256, blk, 0, stream>>>(types, cnt);
    k_scan<<<1, 64, 0, stream>>>(ibase);
    k_fill<<<NTOK / 256, blk, 0, stream>>>(types, cur, idxb);

    // 7. Hidden = gelu(x1[idx] @ W1[t] + b1[t])   (grouped, A indexed) -> CAT
    k_g2<EP_GELU_BF16, true, false, true, 1><<<dim3(16, 16, T_), blk512, 0, stream>>>(
        X1B, W1T, CAT, nullptr, 0, b1, idxb, off, cnt,
        NTOK, 1024, 1024, 1024, 4096, (long)4096 * 1024, 4096);

    // 8. h2 = Hidden @ W2[t] + b2[t]  (grouped, C scattered, split-K=3; W1T free -> partials)
    k_g2<EP_BIAS_F32, false, true, true, 3><<<dim3(16, 4, T_ * 3), blk512, 0, stream>>>(
        CAT, W2T, Hb, PkF, PSTR, b2, idxb, off, cnt,
        NTOK, 4096, 4096, 4096, 1024, (long)1024 * 4096, 1024);
    k_red2<<<NTOK * D_ / 4 / 256, blk, 0, stream>>>(Hb, PkF, PkF + PSTR, NTOK * D_ / 4);

    // 9. out = LN2(x1 + h2)
    k_ln<false><<<NTOK, blk, 0, stream>>>(X1, Hb, ln2g, ln2b, types, (float*)d_out, nullptr);
}

// Round 8
// 536.108 us; speedup vs baseline: 1.5215x; 1.0494x over previous
//
#include <hip/hip_runtime.h>
#include <hip/hip_bf16.h>
#include <math.h>

#define B_   2
#define L_   2048
#define D_   1024
#define H_   16
#define DK_  64
#define T_   4
#define F_   4096
#define NTOK (B_ * L_)   // 4096

typedef __bf16 bf16_t;
typedef bf16_t bf16x8 __attribute__((ext_vector_type(8)));
typedef float  f32x4  __attribute__((ext_vector_type(4)));
typedef unsigned short u16;
typedef u16 u16x8 __attribute__((ext_vector_type(8)));
typedef unsigned long long ull;

static __device__ __forceinline__ u16 f2b(float f) {
    __hip_bfloat16 h = __float2bfloat16(f);
    return *reinterpret_cast<u16*>(&h);
}
static __device__ __forceinline__ float b2f(u16 u) {
    __hip_bfloat16 h;
    *reinterpret_cast<u16*>(&h) = u;
    return __bfloat162float(h);
}

// async global->LDS, 16B per lane; LDS dest is linear (uniform base + lane*16)
static __device__ __forceinline__ void gld16(void* lds, const void* g) {
    __builtin_amdgcn_global_load_lds(
        (const __attribute__((address_space(1))) unsigned int*)g,
        (__attribute__((address_space(3))) unsigned int*)lds,
        16, 0, 0);
}

#define VMW(N) do { asm volatile("s_waitcnt vmcnt(" #N ")" ::: "memory"); \
                    __builtin_amdgcn_sched_barrier(0); } while (0)
#define BARR() do { __builtin_amdgcn_sched_barrier(0); \
                    __builtin_amdgcn_s_barrier();      \
                    __builtin_amdgcn_sched_barrier(0); } while (0)

// ---------------------------------------------------------------- cast x -> bf16
__global__ void k_cast_bf16(const float* __restrict__ in, u16* __restrict__ out, int n4) {
    int i = blockIdx.x * 256 + threadIdx.x;
    if (i >= n4) return;
    float4 v = reinterpret_cast<const float4*>(in)[i];
    ushort4 o;
    o.x = f2b(v.x); o.y = f2b(v.y); o.z = f2b(v.z); o.w = f2b(v.w);
    reinterpret_cast<ushort4*>(out)[i] = o;
}

// --------------------------------------------- transpose-cast W (KxN f32) -> Wt (NxK bf16)
__global__ void k_tcast(const float* __restrict__ W, u16* __restrict__ Wt,
                        int K, int N, long sW, long sWt) {
    __shared__ float tile[32][33];
    int z = blockIdx.z;
    W  += (long)z * sW;
    Wt += (long)z * sWt;
    int n0 = blockIdx.x * 32, k0 = blockIdx.y * 32;
    int tx = threadIdx.x, ty = threadIdx.y;   // block (32,8)
#pragma unroll
    for (int i = 0; i < 4; i++)
        tile[ty + 8 * i][tx] = W[(long)(k0 + ty + 8 * i) * N + n0 + tx];
    __syncthreads();
#pragma unroll
    for (int i = 0; i < 4; i++)
        Wt[(long)(n0 + ty + 8 * i) * K + k0 + tx] = f2b(tile[tx][ty + 8 * i]);
}

// ---------------------------------------------------------------- 256x256 8-wave GEMM v2
// VTOUT: blocks whose N-range lies in CAT's V columns [2048,3072) write a
// pre-transposed V^T buffer VT[(b*16+h)*64+dk][L] instead (lane stores ushort4
// of 4 consecutive tokens). This moves attention's V-transpose out of its loop.
enum { EP_BF16 = 0, EP_F32 = 1, EP_GELU_BF16 = 2, EP_BIAS_F32 = 3 };

template <int MODE, bool AIDX, bool CIDX, bool GROUPED, int KS, bool VTOUT>
__global__ __launch_bounds__(512, 2)
void k_g2(const u16* __restrict__ A, const u16* __restrict__ Bt,
          void* __restrict__ Cv, float* __restrict__ Cpart, long partStride,
          u16* __restrict__ VTbuf,
          const float* __restrict__ bias,
          const int* __restrict__ idxb, const int* __restrict__ boff,
          const int* __restrict__ bcnt,
          int M, int K, int lda, int ldb, int ldc,
          long strideB, int biasStride)
{
    int p0 = 0, pend = M, ks = 0;
    if (KS > 1) ks = (int)blockIdx.z % KS;
    if (GROUPED) {
        int g = (KS > 1) ? ((int)blockIdx.z / KS) : (int)blockIdx.z;
        int c = bcnt[g];
        p0 = boff[g]; pend = p0 + c;
        Bt += (long)g * strideB;
        bias += (long)g * biasStride;
    }
    int kBeg = 0, kEnd = K;
    if (KS > 1) {
        int Kc = ((K / KS) + 31) & ~31;
        kBeg = ks * Kc;
        kEnd = min(K, kBeg + Kc);
    }
    const int gx = gridDim.x;
    const int nwg = gx * gridDim.y;
    const int id = blockIdx.y * gx + blockIdx.x;
    const int q8 = nwg >> 3, r8 = nwg & 7, xcd = id & 7, sub = id >> 3;
    const int id2 = (xcd < r8 ? xcd * (q8 + 1) : r8 * (q8 + 1) + (xcd - r8) * q8) + sub;
    const int tm = id2 % gx, tn = id2 / gx;
    if (GROUPED && tm * 256 >= (pend - p0)) return;
    const int bm = tm * 256, bn = tn * 256;

    const int tid = threadIdx.x;
    const int wid = tid >> 6, lane = tid & 63;
    const int lg = lane >> 4, lr = lane & 15;
    const int wr = wid >> 2, wc = wid & 3;

    __shared__ u16 lds[8 * 4096];          // [buf0: A0 A1 B0 B1][buf1: ...]

    const int srow = tid >> 2;                               // 0..127
    const int sch  = (tid & 3) ^ ((srow >> 1) & 3);
    long ra0, ra1;
    {
        int pa0 = p0 + bm + srow, pa1 = p0 + bm + 128 + srow;
        if (GROUPED) { pa0 = min(pa0, pend - 1); pa1 = min(pa1, pend - 1); }
        ra0 = AIDX ? (long)idxb[pa0] : (long)pa0;
        ra1 = AIDX ? (long)idxb[pa1] : (long)pa1;
    }
    const u16* gA0 = A + ra0 * lda + kBeg + sch * 8;
    const u16* gA1 = A + ra1 * lda + kBeg + sch * 8;
    const u16* gB0 = Bt + (long)(bn + srow) * ldb + kBeg + sch * 8;
    const u16* gB1 = Bt + (long)(bn + 128 + srow) * ldb + kBeg + sch * 8;
    u16* const d0 = lds + tid * 8;
    const int R = 4096;

    int offA[4], offB[4];
#pragma unroll
    for (int i = 0; i < 4; i++) {
        int raf = wr * 64 + i * 16 + lr;
        offA[i] = raf * 32 + ((lg ^ ((raf >> 1) & 3)) * 8);
        int rbf = (wc & 1) * 64 + i * 16 + lr;
        offB[i] = rbf * 32 + ((lg ^ ((rbf >> 1) & 3)) * 8);
    }
    const int regB = 2 + (wc >> 1);

    const f32x4 zero = {0.f, 0.f, 0.f, 0.f};
    f32x4 acc[2][4][4];
#pragma unroll
    for (int qa = 0; qa < 2; qa++)
#pragma unroll
        for (int m = 0; m < 4; m++)
#pragma unroll
            for (int n = 0; n < 4; n++) acc[qa][m][n] = zero;

    const int NT = (kEnd - kBeg) >> 5;

    gld16(d0 + 0 * R, gA0);
    gld16(d0 + 2 * R, gB0);
    gld16(d0 + 1 * R, gA1);
    gld16(d0 + 3 * R, gB1);

    for (int t = 0; t < NT; t++) {
        const int buf = t & 1;
        const u16* bb_ = lds + buf * 4 * R;
        u16* dn = d0 + (buf ^ 1) * 4 * R;
        const long ko = (long)(t + 1) * 32;

        if (t + 1 < NT) {
            gld16(dn + 0 * R, gA0 + ko);
            gld16(dn + 2 * R, gB0 + ko);
            VMW(2);
        } else {
            VMW(0);
        }
        BARR();

        bf16x8 bv[4], av[4];
#pragma unroll
        for (int n = 0; n < 4; n++)
            bv[n] = *reinterpret_cast<const bf16x8*>(bb_ + regB * R + offB[n]);
#pragma unroll
        for (int m = 0; m < 4; m++)
            av[m] = *reinterpret_cast<const bf16x8*>(bb_ + 0 * R + offA[m]);
        __builtin_amdgcn_s_setprio(1);
#pragma unroll
        for (int m = 0; m < 4; m++)
#pragma unroll
            for (int n = 0; n < 4; n++)
                acc[0][m][n] = __builtin_amdgcn_mfma_f32_16x16x32_bf16(av[m], bv[n], acc[0][m][n], 0, 0, 0);
        __builtin_amdgcn_s_setprio(0);

        if (t + 1 < NT) {
            gld16(dn + 1 * R, gA1 + ko);
            gld16(dn + 3 * R, gB1 + ko);
        }
#pragma unroll
        for (int m = 0; m < 4; m++)
            av[m] = *reinterpret_cast<const bf16x8*>(bb_ + 1 * R + offA[m]);
        __builtin_amdgcn_s_setprio(1);
#pragma unroll
        for (int m = 0; m < 4; m++)
#pragma unroll
            for (int n = 0; n < 4; n++)
                acc[1][m][n] = __builtin_amdgcn_mfma_f32_16x16x32_bf16(av[m], bv[n], acc[1][m][n], 0, 0, 0);
        __builtin_amdgcn_s_setprio(0);
        BARR();
    }

    // ---- epilogue ----
    if (VTOUT && bn >= 2048 && bn < 3072) {
        // V columns: write pre-transposed VT[(b*16+h)*64+dk][2048]
#pragma unroll
        for (int qa = 0; qa < 2; qa++) {
#pragma unroll
            for (int m = 0; m < 4; m++) {
                int tok0 = bm + qa * 128 + wr * 64 + m * 16 + lg * 4;
                int bb2 = tok0 >> 11, tin = tok0 & 2047;
#pragma unroll
                for (int n = 0; n < 4; n++) {
                    int gn = bn + wc * 64 + n * 16 + lr;
                    int d = gn - 2048, hh = d >> 6, dk = d & 63;
                    ushort4 o4;
                    o4.x = f2b(acc[qa][m][n][0]); o4.y = f2b(acc[qa][m][n][1]);
                    o4.z = f2b(acc[qa][m][n][2]); o4.w = f2b(acc[qa][m][n][3]);
                    long vi = ((long)(bb2 * 16 + hh) * 64 + dk) * 2048 + tin;
                    *reinterpret_cast<ushort4*>(VTbuf + vi) = o4;
                }
            }
        }
        return;
    }
#pragma unroll
    for (int qa = 0; qa < 2; qa++) {
#pragma unroll
        for (int m = 0; m < 4; m++) {
#pragma unroll
            for (int r = 0; r < 4; r++) {
                int prow = p0 + bm + qa * 128 + wr * 64 + m * 16 + lg * 4 + r;
                if (GROUPED && prow >= pend) continue;
                long crow = CIDX ? (long)idxb[prow] : (long)prow;
#pragma unroll
                for (int n = 0; n < 4; n++) {
                    int gn = bn + wc * 64 + n * 16 + lr;
                    float v = acc[qa][m][n][r];
                    long off = crow * (long)ldc + gn;
                    if (KS > 1 && ks > 0) {
                        Cpart[(long)(ks - 1) * partStride + off] = v;
                    } else {
                        if (MODE == EP_GELU_BF16) {
                            v += bias[gn];
                            v = 0.5f * v * (1.0f + erff(v * 0.70710678118654752f));
                        }
                        if (MODE == EP_BIAS_F32) v += bias[gn];
                        if (MODE == EP_BF16 || MODE == EP_GELU_BF16)
                            ((u16*)Cv)[off] = f2b(v);
                        else
                            ((float*)Cv)[off] = v;
                    }
                }
            }
        }
    }
}

// ---------------------------------------------------------------- attention (v4)
// KVBLK=128; exp2-domain softmax; tile-class mask fast paths; V^T staged via
// gld16 from the pre-transposed VT buffer (zero VALU staging); defer-rescale.
#define KVB 128
__global__ __launch_bounds__(256)
void k_attn(const u16* __restrict__ cat, const u16* __restrict__ VT,
            const int* __restrict__ types, const int* __restrict__ seql,
            u16* __restrict__ AG)
{
    const int qt = blockIdx.x, h = blockIdx.y, b = blockIdx.z;
    const int tid = threadIdx.x, w = tid >> 6, lane = tid & 63;
    const int lg = lane >> 4, lr = lane & 15;
    const int qbase = qt * 64;

    __shared__ u16 sK[KVB * 64];        // [key][dk], chunk = (c ^ (key&7))
    __shared__ u16 sV[64 * KVB];        // [dk][key], chunk = (c ^ (dk&15))
    __shared__ u16 sP[4 * 16 * KVB];    // per-wave [q][key], chunk = (c ^ q)
    __shared__ ull smask[4];            // pad0, pr0, pad1, pr1

    const int seqlen = seql[b];
    const float QSC = 0.125f * 1.44269504f;   // log2(e)/8
    const u16* vtb = VT + (long)(b * 16 + h) * 64 * 2048;

    // Q fragments, pre-scaled to exp2 domain
    const long qrow = (long)(b * L_ + qbase + w * 16 + lr);
    const u16* qp = cat + qrow * 4096 + h * 64;
    bf16x8 qf0, qf1;
    {
        u16x8 a0 = *reinterpret_cast<const u16x8*>(qp + lg * 8);
        u16x8 a1 = *reinterpret_cast<const u16x8*>(qp + 32 + lg * 8);
#pragma unroll
        for (int e = 0; e < 8; e++) {
            qf0[e] = (bf16_t)(b2f(a0[e]) * QSC);
            qf1[e] = (bf16_t)(b2f(a1[e]) * QSC);
        }
    }

    const f32x4 zero = {0.f, 0.f, 0.f, 0.f};
    f32x4 o[4] = {zero, zero, zero, zero};
    float mrow[4] = {-1e30f, -1e30f, -1e30f, -1e30f};
    float lsum[4] = {0.f, 0.f, 0.f, 0.f};

    for (int kb = 0; kb < L_; kb += KVB) {
        if (kb >= seqlen) break;   // uniform per block
        // stage K tile: linear LDS dest, pre-swizzled global source (4 gld16/thread)
#pragma unroll
        for (int i = 0; i < 4; i++) {
            int c = tid + 256 * i;
            int row = c >> 3, sl = (c & 7) ^ (row & 7);
            gld16(sK + c * 8, cat + (long)(b * L_ + kb + row) * 4096 + 1024 + h * 64 + sl * 8);
        }
        // stage V^T tile from VT: [dk=64][key=128], pre-swizzled source (4 gld16/thread)
#pragma unroll
        for (int i = 0; i < 4; i++) {
            int c = tid + 256 * i;
            int row = c >> 4, ch = c & 15;
            int sl = ch ^ (row & 15);
            gld16(sV + c * 8, vtb + (long)row * 2048 + kb + sl * 8);
        }
        if (w < 2) {
            int j = kb + w * 64 + lane;
            ull pm = __ballot(j >= seqlen);
            ull rm = __ballot(types[b * L_ + j] < 3);
            if (lane == 0) { smask[w * 2] = pm; smask[w * 2 + 1] = rm; }
        }
        __syncthreads();
        const ull pad0 = smask[0], pr0 = smask[1], pad1 = smask[2], pr1 = smask[3];

        // S = Q K^T  (16 q-rows x 128 keys per wave), exp2 domain
        f32x4 s[8];
#pragma unroll
        for (int n = 0; n < 8; n++) {
            int row = n * 16 + lr, r7 = row & 7;
            bf16x8 bk0 = *reinterpret_cast<const bf16x8*>(sK + row * 64 + ((lg ^ r7)) * 8);
            bf16x8 bk1 = *reinterpret_cast<const bf16x8*>(sK + row * 64 + (((lg ^ 4)) ^ r7) * 8);
            f32x4 t4 = zero;
            t4 = __builtin_amdgcn_mfma_f32_16x16x32_bf16(qf0, bk0, t4, 0, 0, 0);
            t4 = __builtin_amdgcn_mfma_f32_16x16x32_bf16(qf1, bk1, t4, 0, 0, 0);
            s[n] = t4;
        }

        // ---- masking with tile-class fast paths (block-uniform branch) ----
        float tmax[4] = {-1e30f, -1e30f, -1e30f, -1e30f};
        const bool interior = (kb + KVB <= qbase) && (kb + KVB <= seqlen);
        const bool future   = (kb > qbase + 63);
        if (interior) {
#pragma unroll
            for (int n = 0; n < 8; n++)
#pragma unroll
                for (int r = 0; r < 4; r++) tmax[r] = fmaxf(tmax[r], s[n][r]);
        } else if (future) {
            const ull d0 = pad0 | ~pr0, d1 = pad1 | ~pr1;   // r-uniform dead mask
#pragma unroll
            for (int n = 0; n < 8; n++) {
                bool dead = (((n < 4) ? d0 : d1) >> (((n & 3) * 16 + lr))) & 1ull;
#pragma unroll
                for (int r = 0; r < 4; r++) {
                    float sv = dead ? -1e30f : s[n][r];
                    s[n][r] = sv;
                    tmax[r] = fmaxf(tmax[r], sv);
                }
            }
        } else {
            ull dm0[4], dm1[4];
#pragma unroll
            for (int r = 0; r < 4; r++) {
                int d = qbase + w * 16 + 4 * lg + r - kb;
                ull h0 = (d < 0) ? ~0ull : ((d >= 63) ? 0ull : (~0ull << (d + 1)));
                ull h1 = (d < 64) ? ~0ull : ((d >= 127) ? 0ull : (~0ull << (d - 63)));
                dm0[r] = pad0 | (~pr0 & h0);
                dm1[r] = pad1 | (~pr1 & h1);
            }
#pragma unroll
            for (int n = 0; n < 8; n++) {
                int bp = (n & 3) * 16 + lr;
#pragma unroll
                for (int r = 0; r < 4; r++) {
                    bool dead = (((n < 4) ? dm0[r] : dm1[r]) >> bp) & 1ull;
                    float sv = dead ? -1e30f : s[n][r];
                    s[n][r] = sv;
                    tmax[r] = fmaxf(tmax[r], sv);
                }
            }
        }
#pragma unroll
        for (int r = 0; r < 4; r++) {
#pragma unroll
            for (int d = 1; d < 16; d <<= 1)
                tmax[r] = fmaxf(tmax[r], __shfl_xor(tmax[r], d, 64));
        }
        // defer-rescale (T13): only rescale when some row's max grew
        bool grew = (tmax[0] > mrow[0]) || (tmax[1] > mrow[1]) ||
                    (tmax[2] > mrow[2]) || (tmax[3] > mrow[3]);
        if (__any(grew)) {
            float corr[4];
#pragma unroll
            for (int r = 0; r < 4; r++) {
                float mnew = fmaxf(mrow[r], tmax[r]);
                corr[r] = __builtin_amdgcn_exp2f(mrow[r] - mnew);
                mrow[r] = mnew;
                lsum[r] *= corr[r];
            }
#pragma unroll
            for (int n2 = 0; n2 < 4; n2++) {
                f32x4 t4 = o[n2];
#pragma unroll
                for (int r = 0; r < 4; r++) t4[r] *= corr[r];
                o[n2] = t4;
            }
        }
        float rsum[4] = {0.f, 0.f, 0.f, 0.f};
#pragma unroll
        for (int n = 0; n < 8; n++)
#pragma unroll
            for (int r = 0; r < 4; r++) {
                float p = __builtin_amdgcn_exp2f(s[n][r] - mrow[r]);
                s[n][r] = p;
                rsum[r] += p;
            }
#pragma unroll
        for (int r = 0; r < 4; r++) {
#pragma unroll
            for (int d = 1; d < 16; d <<= 1) rsum[r] += __shfl_xor(rsum[r], d, 64);
            lsum[r] += rsum[r];
        }
        // P -> LDS (per-wave region), swizzled write
        u16* Pw = sP + w * (16 * KVB);
#pragma unroll
        for (int n = 0; n < 8; n++) {
            int pc = n * 2 + (lr >> 3), p7 = lr & 7;
#pragma unroll
            for (int r = 0; r < 4; r++) {
                int q = 4 * lg + r;
                Pw[q * KVB + (pc ^ q) * 8 + p7] = f2b(s[n][r]);
            }
        }
        // PV: 4 k-steps of 32 keys
        bf16x8 pa[4];
#pragma unroll
        for (int st = 0; st < 4; st++)
            pa[st] = *reinterpret_cast<const bf16x8*>(Pw + lr * KVB + ((st * 4 + lg) ^ lr) * 8);
#pragma unroll
        for (int n2 = 0; n2 < 4; n2++) {
            int row = n2 * 16 + lr, r15 = row & 15;
            f32x4 t4 = o[n2];
#pragma unroll
            for (int st = 0; st < 4; st++) {
                bf16x8 vb = *reinterpret_cast<const bf16x8*>(sV + row * KVB + ((st * 4 + lg) ^ r15) * 8);
                t4 = __builtin_amdgcn_mfma_f32_16x16x32_bf16(pa[st], vb, t4, 0, 0, 0);
            }
            o[n2] = t4;
        }
        __syncthreads();
    }
    // epilogue: normalize, U-gate, store bf16
#pragma unroll
    for (int n2 = 0; n2 < 4; n2++) {
#pragma unroll
        for (int r = 0; r < 4; r++) {
            int ig = qbase + w * 16 + 4 * lg + r;
            long orow = (long)(b * L_ + ig);
            int j = n2 * 16 + lr;
            float u = b2f(cat[orow * 4096 + 3072 + h * 64 + j]);
            float val = o[n2][r] / lsum[r] * u;
            AG[orow * 1024 + h * 64 + j] = f2b(val);
        }
    }
}

// ---------------------------------------------------------------- layernorm (per token)
// NP==2: fuse the split-K partial reduction (h = ha + p1 + p2) into the LN read.
template <bool WB, int NP>
__global__ __launch_bounds__(256)
void k_ln(const float* __restrict__ xa, const float* __restrict__ ha,
          const float* __restrict__ p1, const float* __restrict__ p2,
          const float* __restrict__ g, const float* __restrict__ bb,
          const int* __restrict__ types,
          float* __restrict__ of, u16* __restrict__ ob)
{
    const int tok = blockIdx.x, tid = threadIdx.x;
    const long base = (long)tok * D_;
    float4 va = reinterpret_cast<const float4*>(xa + base)[tid];
    float4 vh = reinterpret_cast<const float4*>(ha + base)[tid];
    if (NP == 2) {
        float4 a = reinterpret_cast<const float4*>(p1 + base)[tid];
        float4 c = reinterpret_cast<const float4*>(p2 + base)[tid];
        vh.x += a.x + c.x; vh.y += a.y + c.y; vh.z += a.z + c.z; vh.w += a.w + c.w;
    }
    float v0 = va.x + vh.x, v1 = va.y + vh.y, v2 = va.z + vh.z, v3 = va.w + vh.w;
    float s = v0 + v1 + v2 + v3;
    float ss = v0 * v0 + v1 * v1 + v2 * v2 + v3 * v3;
#pragma unroll
    for (int d = 1; d < 64; d <<= 1) { s += __shfl_xor(s, d, 64); ss += __shfl_xor(ss, d, 64); }
    __shared__ float red[8];
    if ((tid & 63) == 0) { red[tid >> 6] = s; red[4 + (tid >> 6)] = ss; }
    __syncthreads();
    s  = red[0] + red[1] + red[2] + red[3];
    ss = red[4] + red[5] + red[6] + red[7];
    const float mu  = s * (1.f / D_);
    const float var = ss * (1.f / D_) - mu * mu;
    const float inv = rsqrtf(var + 1e-5f);
    const int t = types[tok];
    const float* gp = g + (long)t * D_ + tid * 4;
    const float* bp = bb + (long)t * D_ + tid * 4;
    float o0 = (v0 - mu) * inv * gp[0] + bp[0];
    float o1 = (v1 - mu) * inv * gp[1] + bp[1];
    float o2 = (v2 - mu) * inv * gp[2] + bp[2];
    float o3 = (v3 - mu) * inv * gp[3] + bp[3];
    reinterpret_cast<float4*>(of + base)[tid] = make_float4(o0, o1, o2, o3);
    if (WB) {
        ushort4 u4;
        u4.x = f2b(o0); u4.y = f2b(o1); u4.z = f2b(o2); u4.w = f2b(o3);
        reinterpret_cast<ushort4*>(ob + base)[tid] = u4;
    }
}

// ---------------------------------------------------------------- token-type bucketing
__global__ void k_count(const int* __restrict__ types, int* __restrict__ cnt) {
    int i = blockIdx.x * 256 + threadIdx.x;
    if (i < NTOK) atomicAdd(&cnt[types[i]], 1);
}
__global__ void k_scan(int* __restrict__ base) {
    if (threadIdx.x == 0) {
        int a = 0;
        for (int t = 0; t < T_; t++) { base[4 + t] = a; base[8 + t] = a; a += base[t]; }
    }
}
__global__ void k_fill(const int* __restrict__ types, int* __restrict__ cur, int* __restrict__ idxb) {
    int i = blockIdx.x * 256 + threadIdx.x;
    if (i < NTOK) {
        int p = atomicAdd(&cur[types[i]], 1);
        idxb[p] = i;
    }
}

// ---------------------------------------------------------------- launch
extern "C" void kernel_launch(void* const* d_in, const int* in_sizes, int n_in,
                              void* d_out, int out_size, void* d_ws, size_t ws_size,
                              hipStream_t stream) {
    const float* x    = (const float*)d_in[0];
    const int* types  = (const int*)d_in[1];
    const int* seql   = (const int*)d_in[2];
    const float* Wq   = (const float*)d_in[3];
    const float* Wk   = (const float*)d_in[4];
    const float* Wv   = (const float*)d_in[5];
    const float* Wu   = (const float*)d_in[6];
    const float* Wo   = (const float*)d_in[7];
    const float* ln1g = (const float*)d_in[8];
    const float* ln1b = (const float*)d_in[9];
    const float* W1   = (const float*)d_in[10];
    const float* b1   = (const float*)d_in[11];
    const float* W2   = (const float*)d_in[12];
    const float* b2   = (const float*)d_in[13];
    const float* ln2g = (const float*)d_in[14];
    const float* ln2b = (const float*)d_in[15];

    char* ws = (char*)d_ws;
    constexpr size_t OFF_WT  = 0;
    constexpr size_t OFF_WOT = OFF_WT  + (size_t)4096 * 1024 * 2;
    constexpr size_t OFF_W1T = OFF_WOT + (size_t)1024 * 1024 * 2;      // reused: FFN2 split-K partials
    constexpr size_t OFF_W2T = OFF_W1T + (size_t)T_ * 4096 * 1024 * 2;
    constexpr size_t OFF_XB  = OFF_W2T + (size_t)T_ * 4096 * 1024 * 2; // x bf16 (later: AG)
    constexpr size_t OFF_CAT = OFF_XB  + (size_t)NTOK * D_ * 2;        // QKVU cat (later: Wo partials, FFN hidden)
    constexpr size_t OFF_H   = OFF_CAT + (size_t)NTOK * 4096 * 2;      // VT (QKVU->attn), then h f32
    constexpr size_t OFF_X1  = OFF_H   + (size_t)NTOK * D_ * 4;
    constexpr size_t OFF_X1B = OFF_X1  + (size_t)NTOK * D_ * 4;
    constexpr size_t OFF_INT = OFF_X1B + (size_t)NTOK * D_ * 2;

    u16* WT   = (u16*)(ws + OFF_WT);
    u16* WOT  = (u16*)(ws + OFF_WOT);
    u16* W1T  = (u16*)(ws + OFF_W1T);
    u16* W2T  = (u16*)(ws + OFF_W2T);
    u16* XB   = (u16*)(ws + OFF_XB);      // also AG
    u16* CAT  = (u16*)(ws + OFF_CAT);     // also Wo partials / Hidden
    float* Hb = (float*)(ws + OFF_H);
    u16* VT   = (u16*)(ws + OFF_H);       // VT aliases Hb: live QKVU->attn, Hb written after
    float* X1 = (float*)(ws + OFF_X1);
    u16* X1B  = (u16*)(ws + OFF_X1B);
    float* PkF = (float*)(ws + OFF_W1T);  // FFN2 split-K partials
    float* PkW = (float*)(ws + OFF_CAT);  // Wo split-K partials
    int* ibase = (int*)(ws + OFF_INT);
    int* cnt = ibase, *off = ibase + 4, *cur = ibase + 8, *idxb = ibase + 16;

    dim3 blk(256), blk512(512), tb(32, 8);
    const long PSTR = (long)NTOK * D_;

    // 1. casts / transposes
    k_cast_bf16<<<NTOK * D_ / 4 / 256, blk, 0, stream>>>(x, XB, NTOK * D_ / 4);
    k_tcast<<<dim3(32, 32, 1), tb, 0, stream>>>(Wq, WT + 0 * 1048576, 1024, 1024, 0, 0);
    k_tcast<<<dim3(32, 32, 1), tb, 0, stream>>>(Wk, WT + 1 * 1048576, 1024, 1024, 0, 0);
    k_tcast<<<dim3(32, 32, 1), tb, 0, stream>>>(Wv, WT + 2 * 1048576, 1024, 1024, 0, 0);
    k_tcast<<<dim3(32, 32, 1), tb, 0, stream>>>(Wu, WT + 3 * 1048576, 1024, 1024, 0, 0);
    k_tcast<<<dim3(32, 32, 1), tb, 0, stream>>>(Wo, WOT, 1024, 1024, 0, 0);
    k_tcast<<<dim3(128, 32, T_), tb, 0, stream>>>(W1, W1T, 1024, 4096, (long)1024 * 4096, (long)4096 * 1024);
    k_tcast<<<dim3(32, 128, T_), tb, 0, stream>>>(W2, W2T, 4096, 1024, (long)4096 * 1024, (long)1024 * 4096);

    // 2. QKVU = x @ [Wq|Wk|Wv|Wu]; V-column blocks write transposed VT
    k_g2<EP_BF16, false, false, false, 1, true><<<dim3(16, 16), blk512, 0, stream>>>(
        XB, WT, CAT, nullptr, 0, VT, nullptr, nullptr, nullptr, nullptr,
        NTOK, 1024, 1024, 1024, 4096, 0, 0);

    // 3. attention -> gated output AG (reuses XB)
    k_attn<<<dim3(L_ / 64, H_, B_), blk, 0, stream>>>(CAT, VT, types, seql, XB);

    // 4. h = AG @ Wo (split-K=3; partials in CAT; P0 overwrites Hb/VT -- attn done)
    k_g2<EP_F32, false, false, false, 3, false><<<dim3(16, 4, 3), blk512, 0, stream>>>(
        XB, WOT, Hb, PkW, PSTR, nullptr, nullptr, nullptr, nullptr, nullptr,
        NTOK, 1024, 1024, 1024, 1024, 0, 0);

    // 5. x1 = LN1(x + h) with fused split-K reduce
    k_ln<true, 2><<<NTOK, blk, 0, stream>>>(x, Hb, PkW, PkW + PSTR, ln1g, ln1b, types, X1, X1B);

    // 6. bucket tokens by type
    hipMemsetAsync(cnt, 0, 48, stream);
    k_count<<<NTOK / 256, blk, 0, stream>>>(types, cnt);
    k_scan<<<1, 64, 0, stream>>>(ibase);
    k_fill<<<NTOK / 256, blk, 0, stream>>>(types, cur, idxb);

    // 7. Hidden = gelu(x1[idx] @ W1[t] + b1[t])   (grouped, A indexed) -> CAT
    k_g2<EP_GELU_BF16, true, false, true, 1, false><<<dim3(16, 16, T_), blk512, 0, stream>>>(
        X1B, W1T, CAT, nullptr, 0, nullptr, b1, idxb, off, cnt,
        NTOK, 1024, 1024, 1024, 4096, (long)4096 * 1024, 4096);

    // 8. h2 = Hidden @ W2[t] + b2[t]  (grouped, C scattered, split-K=3)
    k_g2<EP_BIAS_F32, false, true, true, 3, false><<<dim3(16, 4, T_ * 3), blk512, 0, stream>>>(
        CAT, W2T, Hb, PkF, PSTR, nullptr, b2, idxb, off, cnt,
        NTOK, 4096, 4096, 4096, 1024, (long)1024 * 4096, 1024);

    // 9. out = LN2(x1 + h2) with fused split-K reduce
    k_ln<false, 2><<<NTOK, blk, 0, stream>>>(X1, Hb, PkF, PkF + PSTR, ln2g, ln2b, types, (float*)d_out, nullptr);
}

// Round 10
// 521.511 us; speedup vs baseline: 1.5641x; 1.0280x over previous
//
#include <hip/hip_runtime.h>
#include <hip/hip_bf16.h>
#include <math.h>

#define B_   2
#define L_   2048
#define D_   1024
#define H_   16
#define DK_  64
#define T_   4
#define F_   4096
#define NTOK (B_ * L_)   // 4096

typedef __bf16 bf16_t;
typedef bf16_t bf16x8 __attribute__((ext_vector_type(8)));
typedef float  f32x4  __attribute__((ext_vector_type(4)));
typedef unsigned short u16;
typedef u16 u16x8 __attribute__((ext_vector_type(8)));
typedef unsigned long long ull;

static __device__ __forceinline__ u16 f2b(float f) {
    __hip_bfloat16 h = __float2bfloat16(f);
    return *reinterpret_cast<u16*>(&h);
}
static __device__ __forceinline__ float b2f(u16 u) {
    __hip_bfloat16 h;
    *reinterpret_cast<u16*>(&h) = u;
    return __bfloat162float(h);
}

// async global->LDS, 16B per lane; LDS dest is linear (uniform base + lane*16)
static __device__ __forceinline__ void gld16(void* lds, const void* g) {
    __builtin_amdgcn_global_load_lds(
        (const __attribute__((address_space(1))) unsigned int*)g,
        (__attribute__((address_space(3))) unsigned int*)lds,
        16, 0, 0);
}

#define VMW(N) do { asm volatile("s_waitcnt vmcnt(" #N ")" ::: "memory"); \
                    __builtin_amdgcn_sched_barrier(0); } while (0)
#define BARR() do { __builtin_amdgcn_sched_barrier(0); \
                    __builtin_amdgcn_s_barrier();      \
                    __builtin_amdgcn_sched_barrier(0); } while (0)

// ---------------------------------------------------------------- cast x -> bf16
__global__ void k_cast_bf16(const float* __restrict__ in, u16* __restrict__ out, int n4) {
    int i = blockIdx.x * 256 + threadIdx.x;
    if (i >= n4) return;
    float4 v = reinterpret_cast<const float4*>(in)[i];
    ushort4 o;
    o.x = f2b(v.x); o.y = f2b(v.y); o.z = f2b(v.z); o.w = f2b(v.w);
    reinterpret_cast<ushort4*>(out)[i] = o;
}

// --------------------------------------------- transpose-cast W (KxN f32) -> Wt (NxK bf16)
__global__ void k_tcast(const float* __restrict__ W, u16* __restrict__ Wt,
                        int K, int N, long sW, long sWt) {
    __shared__ float tile[32][33];
    int z = blockIdx.z;
    W  += (long)z * sW;
    Wt += (long)z * sWt;
    int n0 = blockIdx.x * 32, k0 = blockIdx.y * 32;
    int tx = threadIdx.x, ty = threadIdx.y;   // block (32,8)
#pragma unroll
    for (int i = 0; i < 4; i++)
        tile[ty + 8 * i][tx] = W[(long)(k0 + ty + 8 * i) * N + n0 + tx];
    __syncthreads();
#pragma unroll
    for (int i = 0; i < 4; i++)
        Wt[(long)(n0 + ty + 8 * i) * K + k0 + tx] = f2b(tile[tx][ty + 8 * i]);
}

// ---------------------------------------------------------------- 256x256 8-wave GEMM v3
// BM=BN=256, BK=64, 512 threads. LDS: 2 buf x {A0,A1,B0,B1} x 16KB = 128KB.
// Per K-tile: STAGE1(t+1: A0,B0) -> vmcnt(4) [all of tile t resident; STAGE1
// stays in flight] -> barrier -> compute kk=0 (32 MFMA/wave) -> STAGE2(t+1:
// A1,B1) -> compute kk=32 -> barrier. In-flight depth up to 12 loads (96KB).
// Swizzle (128B rows): phys 16B-chunk = (lg+4k) ^ (row&7); staging source
// pre-swizzled with the same involution (row&7 invariant across +64 slots).
enum { EP_BF16 = 0, EP_F32 = 1, EP_GELU_BF16 = 2, EP_BIAS_F32 = 3 };

#define RRG 8192   // region stride in u16 (16KB)

#define CLUSTER(BB, KK)  do {                                                   \
    bf16x8 bv[4], av[4];                                                        \
    _Pragma("unroll")                                                           \
    for (int n = 0; n < 4; n++)                                                 \
        bv[n] = *reinterpret_cast<const bf16x8*>((BB) + regB + offB[n][KK]);    \
    _Pragma("unroll")                                                           \
    for (int m = 0; m < 4; m++)                                                 \
        av[m] = *reinterpret_cast<const bf16x8*>((BB) + offA[m][KK]);           \
    __builtin_amdgcn_s_setprio(1);                                              \
    _Pragma("unroll")                                                           \
    for (int m = 0; m < 4; m++)                                                 \
        _Pragma("unroll")                                                       \
        for (int n = 0; n < 4; n++)                                             \
            acc[0][m][n] = __builtin_amdgcn_mfma_f32_16x16x32_bf16(             \
                av[m], bv[n], acc[0][m][n], 0, 0, 0);                           \
    __builtin_amdgcn_s_setprio(0);                                              \
    _Pragma("unroll")                                                           \
    for (int m = 0; m < 4; m++)                                                 \
        av[m] = *reinterpret_cast<const bf16x8*>((BB) + RRG + offA[m][KK]);     \
    __builtin_amdgcn_s_setprio(1);                                              \
    _Pragma("unroll")                                                           \
    for (int m = 0; m < 4; m++)                                                 \
        _Pragma("unroll")                                                       \
        for (int n = 0; n < 4; n++)                                             \
            acc[1][m][n] = __builtin_amdgcn_mfma_f32_16x16x32_bf16(             \
                av[m], bv[n], acc[1][m][n], 0, 0, 0);                           \
    __builtin_amdgcn_s_setprio(0);                                              \
} while (0)

template <int MODE, bool AIDX, bool CIDX, bool GROUPED, int KS, bool VTOUT>
__global__ __launch_bounds__(512, 1)
void k_g2(const u16* __restrict__ A, const u16* __restrict__ Bt,
          void* __restrict__ Cv, float* __restrict__ Cpart, long partStride,
          u16* __restrict__ VTbuf,
          const float* __restrict__ bias,
          const int* __restrict__ idxb, const int* __restrict__ boff,
          const int* __restrict__ bcnt,
          int M, int K, int lda, int ldb, int ldc,
          long strideB, int biasStride)
{
    int p0 = 0, pend = M, ks = 0;
    if (KS > 1) ks = (int)blockIdx.z % KS;
    if (GROUPED) {
        int g = (KS > 1) ? ((int)blockIdx.z / KS) : (int)blockIdx.z;
        int c = bcnt[g];
        p0 = boff[g]; pend = p0 + c;
        Bt += (long)g * strideB;
        bias += (long)g * biasStride;
    }
    int kBeg = 0, kEnd = K;
    if (KS > 1) {
        int Kc = ((K / KS) + 63) & ~63;
        kBeg = ks * Kc;
        kEnd = min(K, kBeg + Kc);
    }
    const int gx = gridDim.x;
    const int nwg = gx * gridDim.y;
    const int id = blockIdx.y * gx + blockIdx.x;
    const int q8 = nwg >> 3, r8 = nwg & 7, xcd = id & 7, sub = id >> 3;
    const int id2 = (xcd < r8 ? xcd * (q8 + 1) : r8 * (q8 + 1) + (xcd - r8) * q8) + sub;
    const int tm = id2 % gx, tn = id2 / gx;
    if (GROUPED && tm * 256 >= (pend - p0)) return;
    const int bm = tm * 256, bn = tn * 256;

    const int tid = threadIdx.x;
    const int wid = tid >> 6, lane = tid & 63;
    const int lg = lane >> 4, lr = lane & 15;
    const int wr = wid >> 2, wc = wid & 3;

    __shared__ u16 lds[8 * RRG];   // 128KB: [buf0: A0 A1 B0 B1][buf1: ...]

    // ---- staging: thread -> slots {tid, 512+tid} of each region ----
    const int srow = tid >> 3;                       // 0..63
    const int soff = ((tid & 7) ^ (srow & 7)) * 8;   // swizzled k-offset (u16)
    const u16* pAr[4];
    const u16* pBr[4];
#pragma unroll
    for (int j = 0; j < 4; j++) {
        int pa = p0 + bm + srow + j * 64;
        if (GROUPED) pa = min(pa, pend - 1);
        long ra = AIDX ? (long)idxb[pa] : (long)pa;
        pAr[j] = A + ra * lda + kBeg + soff;
        pBr[j] = Bt + (long)(bn + srow + j * 64) * ldb + kBeg + soff;
    }
    auto STAGE1 = [&](u16* dn, long ko) {   // A0 (rows 0..127), B0 (cols 0..127)
        gld16(dn + 0 * RRG + tid * 8,        pAr[0] + ko);
        gld16(dn + 0 * RRG + (512 + tid) * 8, pAr[1] + ko);
        gld16(dn + 2 * RRG + tid * 8,        pBr[0] + ko);
        gld16(dn + 2 * RRG + (512 + tid) * 8, pBr[1] + ko);
    };
    auto STAGE2 = [&](u16* dn, long ko) {   // A1 (rows 128..255), B1
        gld16(dn + 1 * RRG + tid * 8,        pAr[2] + ko);
        gld16(dn + 1 * RRG + (512 + tid) * 8, pAr[3] + ko);
        gld16(dn + 3 * RRG + tid * 8,        pBr[2] + ko);
        gld16(dn + 3 * RRG + (512 + tid) * 8, pBr[3] + ko);
    };

    // ---- fragment read offsets (u16 units within a region), per kk-half ----
    int offA[4][2], offB[4][2];
    const int regB = (2 + (wc >> 1)) * RRG;
#pragma unroll
    for (int i = 0; i < 4; i++) {
        int raf = wr * 64 + i * 16 + lr;
        int rbf = (wc & 1) * 64 + i * 16 + lr;
#pragma unroll
        for (int k = 0; k < 2; k++) {
            offA[i][k] = raf * 64 + (((lg + 4 * k) ^ (raf & 7)) * 8);
            offB[i][k] = rbf * 64 + (((lg + 4 * k) ^ (rbf & 7)) * 8);
        }
    }

    const f32x4 zero = {0.f, 0.f, 0.f, 0.f};
    f32x4 acc[2][4][4];
#pragma unroll
    for (int qa = 0; qa < 2; qa++)
#pragma unroll
        for (int m = 0; m < 4; m++)
#pragma unroll
            for (int n = 0; n < 4; n++) acc[qa][m][n] = zero;

    const int NT = (kEnd - kBeg) >> 6;

    STAGE1(lds, 0);
    STAGE2(lds, 0);

    for (int t = 0; t < NT; t++) {
        u16* bb_ = lds + (t & 1) * 4 * RRG;
        u16* dn  = lds + ((t & 1) ^ 1) * 4 * RRG;
        const long ko = (long)(t + 1) * 64;
        if (t + 1 < NT) {
            STAGE1(dn, ko);
            VMW(4);          // tile t fully resident; STAGE1(t+1) in flight
        } else {
            VMW(0);
        }
        BARR();
        CLUSTER(bb_, 0);
        if (t + 1 < NT) STAGE2(dn, ko);
        CLUSTER(bb_, 1);
        BARR();
    }

    // ---- epilogue ----
    if (VTOUT && bn >= 2048 && bn < 3072) {
        // V columns: write pre-transposed VT[(b*16+h)*64+dk][2048]
#pragma unroll
        for (int qa = 0; qa < 2; qa++) {
#pragma unroll
            for (int m = 0; m < 4; m++) {
                int tok0 = bm + qa * 128 + wr * 64 + m * 16 + lg * 4;
                int bb2 = tok0 >> 11, tin = tok0 & 2047;
#pragma unroll
                for (int n = 0; n < 4; n++) {
                    int gn = bn + wc * 64 + n * 16 + lr;
                    int d = gn - 2048, hh = d >> 6, dk = d & 63;
                    ushort4 o4;
                    o4.x = f2b(acc[qa][m][n][0]); o4.y = f2b(acc[qa][m][n][1]);
                    o4.z = f2b(acc[qa][m][n][2]); o4.w = f2b(acc[qa][m][n][3]);
                    long vi = ((long)(bb2 * 16 + hh) * 64 + dk) * 2048 + tin;
                    *reinterpret_cast<ushort4*>(VTbuf + vi) = o4;
                }
            }
        }
        return;
    }
#pragma unroll
    for (int qa = 0; qa < 2; qa++) {
#pragma unroll
        for (int m = 0; m < 4; m++) {
#pragma unroll
            for (int r = 0; r < 4; r++) {
                int prow = p0 + bm + qa * 128 + wr * 64 + m * 16 + lg * 4 + r;
                if (GROUPED && prow >= pend) continue;
                long crow = CIDX ? (long)idxb[prow] : (long)prow;
#pragma unroll
                for (int n = 0; n < 4; n++) {
                    int gn = bn + wc * 64 + n * 16 + lr;
                    float v = acc[qa][m][n][r];
                    long off = crow * (long)ldc + gn;
                    if (KS > 1 && ks > 0) {
                        Cpart[(long)(ks - 1) * partStride + off] = v;
                    } else {
                        if (MODE == EP_GELU_BF16) {
                            v += bias[gn];
                            v = 0.5f * v * (1.0f + erff(v * 0.70710678118654752f));
                        }
                        if (MODE == EP_BIAS_F32) v += bias[gn];
                        if (MODE == EP_BF16 || MODE == EP_GELU_BF16)
                            ((u16*)Cv)[off] = f2b(v);
                        else
                            ((float*)Cv)[off] = v;
                    }
                }
            }
        }
    }
}

// ---------------------------------------------------------------- attention (v4)
// KVBLK=128; exp2-domain softmax; tile-class mask fast paths; V^T staged via
// gld16 from the pre-transposed VT buffer (zero VALU staging); defer-rescale.
#define KVB 128
__global__ __launch_bounds__(256)
void k_attn(const u16* __restrict__ cat, const u16* __restrict__ VT,
            const int* __restrict__ types, const int* __restrict__ seql,
            u16* __restrict__ AG)
{
    const int qt = blockIdx.x, h = blockIdx.y, b = blockIdx.z;
    const int tid = threadIdx.x, w = tid >> 6, lane = tid & 63;
    const int lg = lane >> 4, lr = lane & 15;
    const int qbase = qt * 64;

    __shared__ u16 sK[KVB * 64];        // [key][dk], chunk = (c ^ (key&7))
    __shared__ u16 sV[64 * KVB];        // [dk][key], chunk = (c ^ (dk&15))
    __shared__ u16 sP[4 * 16 * KVB];    // per-wave [q][key], chunk = (c ^ q)
    __shared__ ull smask[4];            // pad0, pr0, pad1, pr1

    const int seqlen = seql[b];
    const float QSC = 0.125f * 1.44269504f;   // log2(e)/8
    const u16* vtb = VT + (long)(b * 16 + h) * 64 * 2048;

    // Q fragments, pre-scaled to exp2 domain
    const long qrow = (long)(b * L_ + qbase + w * 16 + lr);
    const u16* qp = cat + qrow * 4096 + h * 64;
    bf16x8 qf0, qf1;
    {
        u16x8 a0 = *reinterpret_cast<const u16x8*>(qp + lg * 8);
        u16x8 a1 = *reinterpret_cast<const u16x8*>(qp + 32 + lg * 8);
#pragma unroll
        for (int e = 0; e < 8; e++) {
            qf0[e] = (bf16_t)(b2f(a0[e]) * QSC);
            qf1[e] = (bf16_t)(b2f(a1[e]) * QSC);
        }
    }

    const f32x4 zero = {0.f, 0.f, 0.f, 0.f};
    f32x4 o[4] = {zero, zero, zero, zero};
    float mrow[4] = {-1e30f, -1e30f, -1e30f, -1e30f};
    float lsum[4] = {0.f, 0.f, 0.f, 0.f};

    for (int kb = 0; kb < L_; kb += KVB) {
        if (kb >= seqlen) break;   // uniform per block
#pragma unroll
        for (int i = 0; i < 4; i++) {
            int c = tid + 256 * i;
            int row = c >> 3, sl = (c & 7) ^ (row & 7);
            gld16(sK + c * 8, cat + (long)(b * L_ + kb + row) * 4096 + 1024 + h * 64 + sl * 8);
        }
#pragma unroll
        for (int i = 0; i < 4; i++) {
            int c = tid + 256 * i;
            int row = c >> 4, ch = c & 15;
            int sl = ch ^ (row & 15);
            gld16(sV + c * 8, vtb + (long)row * 2048 + kb + sl * 8);
        }
        if (w < 2) {
            int j = kb + w * 64 + lane;
            ull pm = __ballot(j >= seqlen);
            ull rm = __ballot(types[b * L_ + j] < 3);
            if (lane == 0) { smask[w * 2] = pm; smask[w * 2 + 1] = rm; }
        }
        __syncthreads();
        const ull pad0 = smask[0], pr0 = smask[1], pad1 = smask[2], pr1 = smask[3];

        // S = Q K^T  (16 q-rows x 128 keys per wave), exp2 domain
        f32x4 s[8];
#pragma unroll
        for (int n = 0; n < 8; n++) {
            int row = n * 16 + lr, r7 = row & 7;
            bf16x8 bk0 = *reinterpret_cast<const bf16x8*>(sK + row * 64 + ((lg ^ r7)) * 8);
            bf16x8 bk1 = *reinterpret_cast<const bf16x8*>(sK + row * 64 + (((lg ^ 4)) ^ r7) * 8);
            f32x4 t4 = zero;
            t4 = __builtin_amdgcn_mfma_f32_16x16x32_bf16(qf0, bk0, t4, 0, 0, 0);
            t4 = __builtin_amdgcn_mfma_f32_16x16x32_bf16(qf1, bk1, t4, 0, 0, 0);
            s[n] = t4;
        }

        // ---- masking with tile-class fast paths (block-uniform branch) ----
        float tmax[4] = {-1e30f, -1e30f, -1e30f, -1e30f};
        const bool interior = (kb + KVB <= qbase) && (kb + KVB <= seqlen);
        const bool future   = (kb > qbase + 63);
        if (interior) {
#pragma unroll
            for (int n = 0; n < 8; n++)
#pragma unroll
                for (int r = 0; r < 4; r++) tmax[r] = fmaxf(tmax[r], s[n][r]);
        } else if (future) {
            const ull d0 = pad0 | ~pr0, d1 = pad1 | ~pr1;   // r-uniform dead mask
#pragma unroll
            for (int n = 0; n < 8; n++) {
                bool dead = (((n < 4) ? d0 : d1) >> (((n & 3) * 16 + lr))) & 1ull;
#pragma unroll
                for (int r = 0; r < 4; r++) {
                    float sv = dead ? -1e30f : s[n][r];
                    s[n][r] = sv;
                    tmax[r] = fmaxf(tmax[r], sv);
                }
            }
        } else {
            ull dm0[4], dm1[4];
#pragma unroll
            for (int r = 0; r < 4; r++) {
                int d = qbase + w * 16 + 4 * lg + r - kb;
                ull h0 = (d < 0) ? ~0ull : ((d >= 63) ? 0ull : (~0ull << (d + 1)));
                ull h1 = (d < 64) ? ~0ull : ((d >= 127) ? 0ull : (~0ull << (d - 63)));
                dm0[r] = pad0 | (~pr0 & h0);
                dm1[r] = pad1 | (~pr1 & h1);
            }
#pragma unroll
            for (int n = 0; n < 8; n++) {
                int bp = (n & 3) * 16 + lr;
#pragma unroll
                for (int r = 0; r < 4; r++) {
                    bool dead = (((n < 4) ? dm0[r] : dm1[r]) >> bp) & 1ull;
                    float sv = dead ? -1e30f : s[n][r];
                    s[n][r] = sv;
                    tmax[r] = fmaxf(tmax[r], sv);
                }
            }
        }
#pragma unroll
        for (int r = 0; r < 4; r++) {
#pragma unroll
            for (int d = 1; d < 16; d <<= 1)
                tmax[r] = fmaxf(tmax[r], __shfl_xor(tmax[r], d, 64));
        }
        // defer-rescale (T13): only rescale when some row's max grew
        bool grew = (tmax[0] > mrow[0]) || (tmax[1] > mrow[1]) ||
                    (tmax[2] > mrow[2]) || (tmax[3] > mrow[3]);
        if (__any(grew)) {
            float corr[4];
#pragma unroll
            for (int r = 0; r < 4; r++) {
                float mnew = fmaxf(mrow[r], tmax[r]);
                corr[r] = __builtin_amdgcn_exp2f(mrow[r] - mnew);
                mrow[r] = mnew;
                lsum[r] *= corr[r];
            }
#pragma unroll
            for (int n2 = 0; n2 < 4; n2++) {
                f32x4 t4 = o[n2];
#pragma unroll
                for (int r = 0; r < 4; r++) t4[r] *= corr[r];
                o[n2] = t4;
            }
        }
        float rsum[4] = {0.f, 0.f, 0.f, 0.f};
#pragma unroll
        for (int n = 0; n < 8; n++)
#pragma unroll
            for (int r = 0; r < 4; r++) {
                float p = __builtin_amdgcn_exp2f(s[n][r] - mrow[r]);
                s[n][r] = p;
                rsum[r] += p;
            }
#pragma unroll
        for (int r = 0; r < 4; r++) {
#pragma unroll
            for (int d = 1; d < 16; d <<= 1) rsum[r] += __shfl_xor(rsum[r], d, 64);
            lsum[r] += rsum[r];
        }
        // P -> LDS (per-wave region), swizzled write
        u16* Pw = sP + w * (16 * KVB);
#pragma unroll
        for (int n = 0; n < 8; n++) {
            int pc = n * 2 + (lr >> 3), p7 = lr & 7;
#pragma unroll
            for (int r = 0; r < 4; r++) {
                int q = 4 * lg + r;
                Pw[q * KVB + (pc ^ q) * 8 + p7] = f2b(s[n][r]);
            }
        }
        // PV: 4 k-steps of 32 keys
        bf16x8 pa[4];
#pragma unroll
        for (int st = 0; st < 4; st++)
            pa[st] = *reinterpret_cast<const bf16x8*>(Pw + lr * KVB + ((st * 4 + lg) ^ lr) * 8);
#pragma unroll
        for (int n2 = 0; n2 < 4; n2++) {
            int row = n2 * 16 + lr, r15 = row & 15;
            f32x4 t4 = o[n2];
#pragma unroll
            for (int st = 0; st < 4; st++) {
                bf16x8 vb = *reinterpret_cast<const bf16x8*>(sV + row * KVB + ((st * 4 + lg) ^ r15) * 8);
                t4 = __builtin_amdgcn_mfma_f32_16x16x32_bf16(pa[st], vb, t4, 0, 0, 0);
            }
            o[n2] = t4;
        }
        __syncthreads();
    }
    // epilogue: normalize, U-gate, store bf16
#pragma unroll
    for (int n2 = 0; n2 < 4; n2++) {
#pragma unroll
        for (int r = 0; r < 4; r++) {
            int ig = qbase + w * 16 + 4 * lg + r;
            long orow = (long)(b * L_ + ig);
            int j = n2 * 16 + lr;
            float u = b2f(cat[orow * 4096 + 3072 + h * 64 + j]);
            float val = o[n2][r] / lsum[r] * u;
            AG[orow * 1024 + h * 64 + j] = f2b(val);
        }
    }
}

// ---------------------------------------------------------------- layernorm (per token)
// NP partials are added into ha (fused split-K reduce).
template <bool WB, int NP>
__global__ __launch_bounds__(256)
void k_ln(const float* __restrict__ xa, const float* __restrict__ ha,
          const float* __restrict__ p1, const float* __restrict__ p2,
          const float* __restrict__ p3,
          const float* __restrict__ g, const float* __restrict__ bb,
          const int* __restrict__ types,
          float* __restrict__ of, u16* __restrict__ ob)
{
    const int tok = blockIdx.x, tid = threadIdx.x;
    const long base = (long)tok * D_;
    float4 va = reinterpret_cast<const float4*>(xa + base)[tid];
    float4 vh = reinterpret_cast<const float4*>(ha + base)[tid];
    if (NP >= 2) {
        float4 a = reinterpret_cast<const float4*>(p1 + base)[tid];
        float4 c = reinterpret_cast<const float4*>(p2 + base)[tid];
        vh.x += a.x + c.x; vh.y += a.y + c.y; vh.z += a.z + c.z; vh.w += a.w + c.w;
    }
    if (NP >= 3) {
        float4 a = reinterpret_cast<const float4*>(p3 + base)[tid];
        vh.x += a.x; vh.y += a.y; vh.z += a.z; vh.w += a.w;
    }
    float v0 = va.x + vh.x, v1 = va.y + vh.y, v2 = va.z + vh.z, v3 = va.w + vh.w;
    float s = v0 + v1 + v2 + v3;
    float ss = v0 * v0 + v1 * v1 + v2 * v2 + v3 * v3;
#pragma unroll
    for (int d = 1; d < 64; d <<= 1) { s += __shfl_xor(s, d, 64); ss += __shfl_xor(ss, d, 64); }
    __shared__ float red[8];
    if ((tid & 63) == 0) { red[tid >> 6] = s; red[4 + (tid >> 6)] = ss; }
    __syncthreads();
    s  = red[0] + red[1] + red[2] + red[3];
    ss = red[4] + red[5] + red[6] + red[7];
    const float mu  = s * (1.f / D_);
    const float var = ss * (1.f / D_) - mu * mu;
    const float inv = rsqrtf(var + 1e-5f);
    const int t = types[tok];
    const float* gp = g + (long)t * D_ + tid * 4;
    const float* bp = bb + (long)t * D_ + tid * 4;
    float o0 = (v0 - mu) * inv * gp[0] + bp[0];
    float o1 = (v1 - mu) * inv * gp[1] + bp[1];
    float o2 = (v2 - mu) * inv * gp[2] + bp[2];
    float o3 = (v3 - mu) * inv * gp[3] + bp[3];
    reinterpret_cast<float4*>(of + base)[tid] = make_float4(o0, o1, o2, o3);
    if (WB) {
        ushort4 u4;
        u4.x = f2b(o0); u4.y = f2b(o1); u4.z = f2b(o2); u4.w = f2b(o3);
        reinterpret_cast<ushort4*>(ob + base)[tid] = u4;
    }
}

// ---------------------------------------------------------------- token-type bucketing
__global__ void k_count(const int* __restrict__ types, int* __restrict__ cnt) {
    int i = blockIdx.x * 256 + threadIdx.x;
    if (i < NTOK) atomicAdd(&cnt[types[i]], 1);
}
__global__ void k_scan(int* __restrict__ base) {
    if (threadIdx.x == 0) {
        int a = 0;
        for (int t = 0; t < T_; t++) { base[4 + t] = a; base[8 + t] = a; a += base[t]; }
    }
}
__global__ void k_fill(const int* __restrict__ types, int* __restrict__ cur, int* __restrict__ idxb) {
    int i = blockIdx.x * 256 + threadIdx.x;
    if (i < NTOK) {
        int p = atomicAdd(&cur[types[i]], 1);
        idxb[p] = i;
    }
}

// ---------------------------------------------------------------- launch
extern "C" void kernel_launch(void* const* d_in, const int* in_sizes, int n_in,
                              void* d_out, int out_size, void* d_ws, size_t ws_size,
                              hipStream_t stream) {
    const float* x    = (const float*)d_in[0];
    const int* types  = (const int*)d_in[1];
    const int* seql   = (const int*)d_in[2];
    const float* Wq   = (const float*)d_in[3];
    const float* Wk   = (const float*)d_in[4];
    const float* Wv   = (const float*)d_in[5];
    const float* Wu   = (const float*)d_in[6];
    const float* Wo   = (const float*)d_in[7];
    const float* ln1g = (const float*)d_in[8];
    const float* ln1b = (const float*)d_in[9];
    const float* W1   = (const float*)d_in[10];
    const float* b1   = (const float*)d_in[11];
    const float* W2   = (const float*)d_in[12];
    const float* b2   = (const float*)d_in[13];
    const float* ln2g = (const float*)d_in[14];
    const float* ln2b = (const float*)d_in[15];

    char* ws = (char*)d_ws;
    constexpr size_t OFF_WT  = 0;
    constexpr size_t OFF_WOT = OFF_WT  + (size_t)4096 * 1024 * 2;
    constexpr size_t OFF_W1T = OFF_WOT + (size_t)1024 * 1024 * 2;      // reused: FFN2 split-K partials (2x16MB = 32MB, fits exactly)
    constexpr size_t OFF_W2T = OFF_W1T + (size_t)T_ * 4096 * 1024 * 2;
    constexpr size_t OFF_XB  = OFF_W2T + (size_t)T_ * 4096 * 1024 * 2; // x bf16 (later: AG)
    constexpr size_t OFF_CAT = OFF_XB  + (size_t)NTOK * D_ * 2;        // QKVU cat (later: Wo partials, FFN hidden)
    constexpr size_t OFF_H   = OFF_CAT + (size_t)NTOK * 4096 * 2;      // VT (QKVU->attn), then h f32
    constexpr size_t OFF_X1  = OFF_H   + (size_t)NTOK * D_ * 4;
    constexpr size_t OFF_X1B = OFF_X1  + (size_t)NTOK * D_ * 4;
    constexpr size_t OFF_INT = OFF_X1B + (size_t)NTOK * D_ * 2;

    u16* WT   = (u16*)(ws + OFF_WT);
    u16* WOT  = (u16*)(ws + OFF_WOT);
    u16* W1T  = (u16*)(ws + OFF_W1T);
    u16* W2T  = (u16*)(ws + OFF_W2T);
    u16* XB   = (u16*)(ws + OFF_XB);      // also AG
    u16* CAT  = (u16*)(ws + OFF_CAT);     // also Wo partials / Hidden
    float* Hb = (float*)(ws + OFF_H);
    u16* VT   = (u16*)(ws + OFF_H);       // VT aliases Hb: live QKVU->attn, Hb written after
    float* X1 = (float*)(ws + OFF_X1);
    u16* X1B  = (u16*)(ws + OFF_X1B);
    float* PkF = (float*)(ws + OFF_W1T);  // FFN2 split-K partials (2x16MB, aliases W1T -- KS=3 ONLY; KS=4 would overflow into W2T (round-9 NaN))
    float* PkW = (float*)(ws + OFF_CAT);  // Wo split-K partials (2x, aliases CAT)
    int* ibase = (int*)(ws + OFF_INT);
    int* cnt = ibase, *off = ibase + 4, *cur = ibase + 8, *idxb = ibase + 16;

    dim3 blk(256), blk512(512), tb(32, 8);
    const long PSTR = (long)NTOK * D_;

    // 1. casts / transposes
    k_cast_bf16<<<NTOK * D_ / 4 / 256, blk, 0, stream>>>(x, XB, NTOK * D_ / 4);
    k_tcast<<<dim3(32, 32, 1), tb, 0, stream>>>(Wq, WT + 0 * 1048576, 1024, 1024, 0, 0);
    k_tcast<<<dim3(32, 32, 1), tb, 0, stream>>>(Wk, WT + 1 * 1048576, 1024, 1024, 0, 0);
    k_tcast<<<dim3(32, 32, 1), tb, 0, stream>>>(Wv, WT + 2 * 1048576, 1024, 1024, 0, 0);
    k_tcast<<<dim3(32, 32, 1), tb, 0, stream>>>(Wu, WT + 3 * 1048576, 1024, 1024, 0, 0);
    k_tcast<<<dim3(32, 32, 1), tb, 0, stream>>>(Wo, WOT, 1024, 1024, 0, 0);
    k_tcast<<<dim3(128, 32, T_), tb, 0, stream>>>(W1, W1T, 1024, 4096, (long)1024 * 4096, (long)4096 * 1024);
    k_tcast<<<dim3(32, 128, T_), tb, 0, stream>>>(W2, W2T, 4096, 1024, (long)4096 * 1024, (long)1024 * 4096);

    // 2. QKVU = x @ [Wq|Wk|Wv|Wu]; V-column blocks write transposed VT
    k_g2<EP_BF16, false, false, false, 1, true><<<dim3(16, 16), blk512, 0, stream>>>(
        XB, WT, CAT, nullptr, 0, VT, nullptr, nullptr, nullptr, nullptr,
        NTOK, 1024, 1024, 1024, 4096, 0, 0);

    // 3. attention -> gated output AG (reuses XB)
    k_attn<<<dim3(L_ / 64, H_, B_), blk, 0, stream>>>(CAT, VT, types, seql, XB);

    // 4. h = AG @ Wo (split-K=3; partials in CAT; P0 overwrites Hb/VT -- attn done)
    k_g2<EP_F32, false, false, false, 3, false><<<dim3(16, 4, 3), blk512, 0, stream>>>(
        XB, WOT, Hb, PkW, PSTR, nullptr, nullptr, nullptr, nullptr, nullptr,
        NTOK, 1024, 1024, 1024, 1024, 0, 0);

    // 5. x1 = LN1(x + h) with fused split-K reduce (2 partials)
    k_ln<true, 2><<<NTOK, blk, 0, stream>>>(x, Hb, PkW, PkW + PSTR, nullptr,
                                            ln1g, ln1b, types, X1, X1B);

    // 6. bucket tokens by type
    hipMemsetAsync(cnt, 0, 48, stream);
    k_count<<<NTOK / 256, blk, 0, stream>>>(types, cnt);
    k_scan<<<1, 64, 0, stream>>>(ibase);
    k_fill<<<NTOK / 256, blk, 0, stream>>>(types, cur, idxb);

    // 7. Hidden = gelu(x1[idx] @ W1[t] + b1[t])   (grouped, A indexed) -> CAT
    k_g2<EP_GELU_BF16, true, false, true, 1, false><<<dim3(16, 16, T_), blk512, 0, stream>>>(
        X1B, W1T, CAT, nullptr, 0, nullptr, b1, idxb, off, cnt,
        NTOK, 1024, 1024, 1024, 4096, (long)4096 * 1024, 4096);

    // 8. h2 = Hidden @ W2[t] + b2[t]  (grouped, C scattered, split-K=3; 2 partials fit W1T)
    k_g2<EP_BIAS_F32, false, true, true, 3, false><<<dim3(16, 4, T_ * 3), blk512, 0, stream>>>(
        CAT, W2T, Hb, PkF, PSTR, nullptr, b2, idxb, off, cnt,
        NTOK, 4096, 4096, 4096, 1024, (long)1024 * 4096, 1024);

    // 9. out = LN2(x1 + h2) with fused split-K reduce (2 partials)
    k_ln<false, 2><<<NTOK, blk, 0, stream>>>(X1, Hb, PkF, PkF + PSTR, nullptr,
                                             ln2g, ln2b, types, (float*)d_out, nullptr);
}

// Round 11
// 453.710 us; speedup vs baseline: 1.7979x; 1.1494x over previous
//
#include <hip/hip_runtime.h>
#include <hip/hip_bf16.h>
#include <math.h>

#define B_   2
#define L_   2048
#define D_   1024
#define H_   16
#define DK_  64
#define T_   4
#define F_   4096
#define NTOK (B_ * L_)   // 4096

typedef __bf16 bf16_t;
typedef bf16_t bf16x8 __attribute__((ext_vector_type(8)));
typedef float  f32x4  __attribute__((ext_vector_type(4)));
typedef unsigned short u16;
typedef u16 u16x8 __attribute__((ext_vector_type(8)));
typedef unsigned long long ull;

static __device__ __forceinline__ u16 f2b(float f) {
    __hip_bfloat16 h = __float2bfloat16(f);
    return *reinterpret_cast<u16*>(&h);
}
static __device__ __forceinline__ float b2f(u16 u) {
    __hip_bfloat16 h;
    *reinterpret_cast<u16*>(&h) = u;
    return __bfloat162float(h);
}

// async global->LDS, 16B per lane; LDS dest is linear (uniform base + lane*16)
static __device__ __forceinline__ void gld16(void* lds, const void* g) {
    __builtin_amdgcn_global_load_lds(
        (const __attribute__((address_space(1))) unsigned int*)g,
        (__attribute__((address_space(3))) unsigned int*)lds,
        16, 0, 0);
}

#define VMW(N) do { asm volatile("s_waitcnt vmcnt(" #N ")" ::: "memory"); \
                    __builtin_amdgcn_sched_barrier(0); } while (0)
#define BARR() do { __builtin_amdgcn_sched_barrier(0); \
                    __builtin_amdgcn_s_barrier();      \
                    __builtin_amdgcn_sched_barrier(0); } while (0)

// ---------------------------------------------------------------- cast x -> bf16
__global__ void k_cast_bf16(const float* __restrict__ in, u16* __restrict__ out, int n4) {
    int i = blockIdx.x * 256 + threadIdx.x;
    if (i >= n4) return;
    float4 v = reinterpret_cast<const float4*>(in)[i];
    ushort4 o;
    o.x = f2b(v.x); o.y = f2b(v.y); o.z = f2b(v.z); o.w = f2b(v.w);
    reinterpret_cast<ushort4*>(out)[i] = o;
}

// --------------------------------------------- transpose-cast W (KxN f32) -> Wt (NxK bf16)
__global__ void k_tcast(const float* __restrict__ W, u16* __restrict__ Wt,
                        int K, int N, long sW, long sWt) {
    __shared__ float tile[32][33];
    int z = blockIdx.z;
    W  += (long)z * sW;
    Wt += (long)z * sWt;
    int n0 = blockIdx.x * 32, k0 = blockIdx.y * 32;
    int tx = threadIdx.x, ty = threadIdx.y;   // block (32,8)
#pragma unroll
    for (int i = 0; i < 4; i++)
        tile[ty + 8 * i][tx] = W[(long)(k0 + ty + 8 * i) * N + n0 + tx];
    __syncthreads();
#pragma unroll
    for (int i = 0; i < 4; i++)
        Wt[(long)(n0 + ty + 8 * i) * K + k0 + tx] = f2b(tile[tx][ty + 8 * i]);
}

// ---------------------------------------------------------------- 256x256 8-wave GEMM v3
// BM=BN=256, BK=64, 512 threads, LDS 128KB double-buffered (see round-10 notes).
// GROUPED now uses PADDED bucketing: group offsets are multiples of 256, so every
// M-tile belongs to exactly one group; blockIdx.x is the GLOBAL padded M-tile and
// the group is found by scanning the 4 boundaries. No dead early-exit blocks ->
// no worker-collision serialization (round-10 diagnosis: 75% dead blocks caused
// 2-3x stacking of workers on CUs at 1 block/CU).
enum { EP_BF16 = 0, EP_F32 = 1, EP_GELU_BF16 = 2, EP_BIAS_F32 = 3 };

#define RRG 8192   // region stride in u16 (16KB)

#define CLUSTER(BB, KK)  do {                                                   \
    bf16x8 bv[4], av[4];                                                        \
    _Pragma("unroll")                                                           \
    for (int n = 0; n < 4; n++)                                                 \
        bv[n] = *reinterpret_cast<const bf16x8*>((BB) + regB + offB[n][KK]);    \
    _Pragma("unroll")                                                           \
    for (int m = 0; m < 4; m++)                                                 \
        av[m] = *reinterpret_cast<const bf16x8*>((BB) + offA[m][KK]);           \
    __builtin_amdgcn_s_setprio(1);                                              \
    _Pragma("unroll")                                                           \
    for (int m = 0; m < 4; m++)                                                 \
        _Pragma("unroll")                                                       \
        for (int n = 0; n < 4; n++)                                             \
            acc[0][m][n] = __builtin_amdgcn_mfma_f32_16x16x32_bf16(             \
                av[m], bv[n], acc[0][m][n], 0, 0, 0);                           \
    __builtin_amdgcn_s_setprio(0);                                              \
    _Pragma("unroll")                                                           \
    for (int m = 0; m < 4; m++)                                                 \
        av[m] = *reinterpret_cast<const bf16x8*>((BB) + RRG + offA[m][KK]);     \
    __builtin_amdgcn_s_setprio(1);                                              \
    _Pragma("unroll")                                                           \
    for (int m = 0; m < 4; m++)                                                 \
        _Pragma("unroll")                                                       \
        for (int n = 0; n < 4; n++)                                             \
            acc[1][m][n] = __builtin_amdgcn_mfma_f32_16x16x32_bf16(             \
                av[m], bv[n], acc[1][m][n], 0, 0, 0);                           \
    __builtin_amdgcn_s_setprio(0);                                              \
} while (0)

template <int MODE, bool AIDX, bool CIDX, bool GROUPED, int KS, bool VTOUT>
__global__ __launch_bounds__(512, 1)
void k_g2(const u16* __restrict__ A, const u16* __restrict__ Bt,
          void* __restrict__ Cv, float* __restrict__ Cpart, long partStride,
          u16* __restrict__ VTbuf,
          const float* __restrict__ bias,
          const int* __restrict__ idxb, const int* __restrict__ boff,
          const int* __restrict__ bcnt,
          int M, int K, int lda, int ldb, int ldc,
          long strideB, int biasStride)
{
    const int ks = (KS > 1) ? (int)blockIdx.z : 0;
    int kBeg = 0, kEnd = K;
    if (KS > 1) {
        int Kc = ((K / KS) + 63) & ~63;
        kBeg = ks * Kc;
        kEnd = min(K, kBeg + Kc);
    }
    // XCD-bijective block swizzle (m204) over (x,y)
    const int gx = gridDim.x;
    const int nwg = gx * gridDim.y;
    const int id = blockIdx.y * gx + blockIdx.x;
    const int q8 = nwg >> 3, r8 = nwg & 7, xcd = id & 7, sub = id >> 3;
    const int id2 = (xcd < r8 ? xcd * (q8 + 1) : r8 * (q8 + 1) + (xcd - r8) * q8) + sub;
    const int tm = id2 % gx, tn = id2 / gx;
    const int bm = tm * 256, bn = tn * 256;

    int pend = M;
    if (GROUPED) {
        // find group from global padded M-tile (boundaries are multiples of 256)
        bool dead = true;
        int g = 0;
#pragma unroll
        for (int t = 0; t < T_; t++) {
            int o = boff[t], c = bcnt[t];
            int pe = o + (((c + 255) >> 8) << 8);   // padded end
            if (bm >= o && bm < pe) { g = t; pend = o + c; dead = false; }
        }
        if (dead) return;    // at most a couple of tail blocks
        Bt += (long)g * strideB;
        bias += (long)g * biasStride;
    }

    const int tid = threadIdx.x;
    const int wid = tid >> 6, lane = tid & 63;
    const int lg = lane >> 4, lr = lane & 15;
    const int wr = wid >> 2, wc = wid & 3;

    __shared__ u16 lds[8 * RRG];   // 128KB: [buf0: A0 A1 B0 B1][buf1: ...]

    // ---- staging: thread -> slots {tid, 512+tid} of each region ----
    const int srow = tid >> 3;                       // 0..63
    const int soff = ((tid & 7) ^ (srow & 7)) * 8;   // swizzled k-offset (u16)
    const u16* pAr[4];
    const u16* pBr[4];
#pragma unroll
    for (int j = 0; j < 4; j++) {
        int pa = bm + srow + j * 64;
        if (GROUPED) pa = min(pa, pend - 1);         // pad rows clamp to a real row
        long ra = AIDX ? (long)idxb[pa] : (long)pa;
        pAr[j] = A + ra * lda + kBeg + soff;
        pBr[j] = Bt + (long)(bn + srow + j * 64) * ldb + kBeg + soff;
    }
    auto STAGE1 = [&](u16* dn, long ko) {   // A0 (rows 0..127), B0 (cols 0..127)
        gld16(dn + 0 * RRG + tid * 8,        pAr[0] + ko);
        gld16(dn + 0 * RRG + (512 + tid) * 8, pAr[1] + ko);
        gld16(dn + 2 * RRG + tid * 8,        pBr[0] + ko);
        gld16(dn + 2 * RRG + (512 + tid) * 8, pBr[1] + ko);
    };
    auto STAGE2 = [&](u16* dn, long ko) {   // A1 (rows 128..255), B1
        gld16(dn + 1 * RRG + tid * 8,        pAr[2] + ko);
        gld16(dn + 1 * RRG + (512 + tid) * 8, pAr[3] + ko);
        gld16(dn + 3 * RRG + tid * 8,        pBr[2] + ko);
        gld16(dn + 3 * RRG + (512 + tid) * 8, pBr[3] + ko);
    };

    // ---- fragment read offsets (u16 units within a region), per kk-half ----
    int offA[4][2], offB[4][2];
    const int regB = (2 + (wc >> 1)) * RRG;
#pragma unroll
    for (int i = 0; i < 4; i++) {
        int raf = wr * 64 + i * 16 + lr;
        int rbf = (wc & 1) * 64 + i * 16 + lr;
#pragma unroll
        for (int k = 0; k < 2; k++) {
            offA[i][k] = raf * 64 + (((lg + 4 * k) ^ (raf & 7)) * 8);
            offB[i][k] = rbf * 64 + (((lg + 4 * k) ^ (rbf & 7)) * 8);
        }
    }

    const f32x4 zero = {0.f, 0.f, 0.f, 0.f};
    f32x4 acc[2][4][4];
#pragma unroll
    for (int qa = 0; qa < 2; qa++)
#pragma unroll
        for (int m = 0; m < 4; m++)
#pragma unroll
            for (int n = 0; n < 4; n++) acc[qa][m][n] = zero;

    const int NT = (kEnd - kBeg) >> 6;

    STAGE1(lds, 0);
    STAGE2(lds, 0);

    for (int t = 0; t < NT; t++) {
        u16* bb_ = lds + (t & 1) * 4 * RRG;
        u16* dn  = lds + ((t & 1) ^ 1) * 4 * RRG;
        const long ko = (long)(t + 1) * 64;
        if (t + 1 < NT) {
            STAGE1(dn, ko);
            VMW(4);          // tile t fully resident; STAGE1(t+1) in flight
        } else {
            VMW(0);
        }
        BARR();
        CLUSTER(bb_, 0);
        if (t + 1 < NT) STAGE2(dn, ko);
        CLUSTER(bb_, 1);
        BARR();
    }

    // ---- epilogue ----
    if (VTOUT && bn >= 2048 && bn < 3072) {
        // V columns: write pre-transposed VT[(b*16+h)*64+dk][2048]
#pragma unroll
        for (int qa = 0; qa < 2; qa++) {
#pragma unroll
            for (int m = 0; m < 4; m++) {
                int tok0 = bm + qa * 128 + wr * 64 + m * 16 + lg * 4;
                int bb2 = tok0 >> 11, tin = tok0 & 2047;
#pragma unroll
                for (int n = 0; n < 4; n++) {
                    int gn = bn + wc * 64 + n * 16 + lr;
                    int d = gn - 2048, hh = d >> 6, dk = d & 63;
                    ushort4 o4;
                    o4.x = f2b(acc[qa][m][n][0]); o4.y = f2b(acc[qa][m][n][1]);
                    o4.z = f2b(acc[qa][m][n][2]); o4.w = f2b(acc[qa][m][n][3]);
                    long vi = ((long)(bb2 * 16 + hh) * 64 + dk) * 2048 + tin;
                    *reinterpret_cast<ushort4*>(VTbuf + vi) = o4;
                }
            }
        }
        return;
    }
#pragma unroll
    for (int qa = 0; qa < 2; qa++) {
#pragma unroll
        for (int m = 0; m < 4; m++) {
#pragma unroll
            for (int r = 0; r < 4; r++) {
                int prow = bm + qa * 128 + wr * 64 + m * 16 + lg * 4 + r;
                if (GROUPED && prow >= pend) continue;
                long crow = CIDX ? (long)idxb[prow] : (long)prow;
#pragma unroll
                for (int n = 0; n < 4; n++) {
                    int gn = bn + wc * 64 + n * 16 + lr;
                    float v = acc[qa][m][n][r];
                    long off = crow * (long)ldc + gn;
                    if (KS > 1 && ks > 0) {
                        Cpart[(long)(ks - 1) * partStride + off] = v;
                    } else {
                        if (MODE == EP_GELU_BF16) {
                            v += bias[gn];
                            v = 0.5f * v * (1.0f + erff(v * 0.70710678118654752f));
                        }
                        if (MODE == EP_BIAS_F32) v += bias[gn];
                        if (MODE == EP_BF16 || MODE == EP_GELU_BF16)
                            ((u16*)Cv)[off] = f2b(v);
                        else
                            ((float*)Cv)[off] = v;
                    }
                }
            }
        }
    }
}

// ---------------------------------------------------------------- attention (v4)
// KVBLK=128; exp2-domain softmax; tile-class mask fast paths; V^T staged via
// gld16 from the pre-transposed VT buffer (zero VALU staging); defer-rescale.
#define KVB 128
__global__ __launch_bounds__(256)
void k_attn(const u16* __restrict__ cat, const u16* __restrict__ VT,
            const int* __restrict__ types, const int* __restrict__ seql,
            u16* __restrict__ AG)
{
    const int qt = blockIdx.x, h = blockIdx.y, b = blockIdx.z;
    const int tid = threadIdx.x, w = tid >> 6, lane = tid & 63;
    const int lg = lane >> 4, lr = lane & 15;
    const int qbase = qt * 64;

    __shared__ u16 sK[KVB * 64];        // [key][dk], chunk = (c ^ (key&7))
    __shared__ u16 sV[64 * KVB];        // [dk][key], chunk = (c ^ (dk&15))
    __shared__ u16 sP[4 * 16 * KVB];    // per-wave [q][key], chunk = (c ^ q)
    __shared__ ull smask[4];            // pad0, pr0, pad1, pr1

    const int seqlen = seql[b];
    const float QSC = 0.125f * 1.44269504f;   // log2(e)/8
    const u16* vtb = VT + (long)(b * 16 + h) * 64 * 2048;

    // Q fragments, pre-scaled to exp2 domain
    const long qrow = (long)(b * L_ + qbase + w * 16 + lr);
    const u16* qp = cat + qrow * 4096 + h * 64;
    bf16x8 qf0, qf1;
    {
        u16x8 a0 = *reinterpret_cast<const u16x8*>(qp + lg * 8);
        u16x8 a1 = *reinterpret_cast<const u16x8*>(qp + 32 + lg * 8);
#pragma unroll
        for (int e = 0; e < 8; e++) {
            qf0[e] = (bf16_t)(b2f(a0[e]) * QSC);
            qf1[e] = (bf16_t)(b2f(a1[e]) * QSC);
        }
    }

    const f32x4 zero = {0.f, 0.f, 0.f, 0.f};
    f32x4 o[4] = {zero, zero, zero, zero};
    float mrow[4] = {-1e30f, -1e30f, -1e30f, -1e30f};
    float lsum[4] = {0.f, 0.f, 0.f, 0.f};

    for (int kb = 0; kb < L_; kb += KVB) {
        if (kb >= seqlen) break;   // uniform per block
#pragma unroll
        for (int i = 0; i < 4; i++) {
            int c = tid + 256 * i;
            int row = c >> 3, sl = (c & 7) ^ (row & 7);
            gld16(sK + c * 8, cat + (long)(b * L_ + kb + row) * 4096 + 1024 + h * 64 + sl * 8);
        }
#pragma unroll
        for (int i = 0; i < 4; i++) {
            int c = tid + 256 * i;
            int row = c >> 4, ch = c & 15;
            int sl = ch ^ (row & 15);
            gld16(sV + c * 8, vtb + (long)row * 2048 + kb + sl * 8);
        }
        if (w < 2) {
            int j = kb + w * 64 + lane;
            ull pm = __ballot(j >= seqlen);
            ull rm = __ballot(types[b * L_ + j] < 3);
            if (lane == 0) { smask[w * 2] = pm; smask[w * 2 + 1] = rm; }
        }
        __syncthreads();
        const ull pad0 = smask[0], pr0 = smask[1], pad1 = smask[2], pr1 = smask[3];

        // S = Q K^T  (16 q-rows x 128 keys per wave), exp2 domain
        f32x4 s[8];
#pragma unroll
        for (int n = 0; n < 8; n++) {
            int row = n * 16 + lr, r7 = row & 7;
            bf16x8 bk0 = *reinterpret_cast<const bf16x8*>(sK + row * 64 + ((lg ^ r7)) * 8);
            bf16x8 bk1 = *reinterpret_cast<const bf16x8*>(sK + row * 64 + (((lg ^ 4)) ^ r7) * 8);
            f32x4 t4 = zero;
            t4 = __builtin_amdgcn_mfma_f32_16x16x32_bf16(qf0, bk0, t4, 0, 0, 0);
            t4 = __builtin_amdgcn_mfma_f32_16x16x32_bf16(qf1, bk1, t4, 0, 0, 0);
            s[n] = t4;
        }

        // ---- masking with tile-class fast paths (block-uniform branch) ----
        float tmax[4] = {-1e30f, -1e30f, -1e30f, -1e30f};
        const bool interior = (kb + KVB <= qbase) && (kb + KVB <= seqlen);
        const bool future   = (kb > qbase + 63);
        if (interior) {
#pragma unroll
            for (int n = 0; n < 8; n++)
#pragma unroll
                for (int r = 0; r < 4; r++) tmax[r] = fmaxf(tmax[r], s[n][r]);
        } else if (future) {
            const ull d0 = pad0 | ~pr0, d1 = pad1 | ~pr1;   // r-uniform dead mask
#pragma unroll
            for (int n = 0; n < 8; n++) {
                bool dead = (((n < 4) ? d0 : d1) >> (((n & 3) * 16 + lr))) & 1ull;
#pragma unroll
                for (int r = 0; r < 4; r++) {
                    float sv = dead ? -1e30f : s[n][r];
                    s[n][r] = sv;
                    tmax[r] = fmaxf(tmax[r], sv);
                }
            }
        } else {
            ull dm0[4], dm1[4];
#pragma unroll
            for (int r = 0; r < 4; r++) {
                int d = qbase + w * 16 + 4 * lg + r - kb;
                ull h0 = (d < 0) ? ~0ull : ((d >= 63) ? 0ull : (~0ull << (d + 1)));
                ull h1 = (d < 64) ? ~0ull : ((d >= 127) ? 0ull : (~0ull << (d - 63)));
                dm0[r] = pad0 | (~pr0 & h0);
                dm1[r] = pad1 | (~pr1 & h1);
            }
#pragma unroll
            for (int n = 0; n < 8; n++) {
                int bp = (n & 3) * 16 + lr;
#pragma unroll
                for (int r = 0; r < 4; r++) {
                    bool dead = (((n < 4) ? dm0[r] : dm1[r]) >> bp) & 1ull;
                    float sv = dead ? -1e30f : s[n][r];
                    s[n][r] = sv;
                    tmax[r] = fmaxf(tmax[r], sv);
                }
            }
        }
#pragma unroll
        for (int r = 0; r < 4; r++) {
#pragma unroll
            for (int d = 1; d < 16; d <<= 1)
                tmax[r] = fmaxf(tmax[r], __shfl_xor(tmax[r], d, 64));
        }
        // defer-rescale (T13): only rescale when some row's max grew
        bool grew = (tmax[0] > mrow[0]) || (tmax[1] > mrow[1]) ||
                    (tmax[2] > mrow[2]) || (tmax[3] > mrow[3]);
        if (__any(grew)) {
            float corr[4];
#pragma unroll
            for (int r = 0; r < 4; r++) {
                float mnew = fmaxf(mrow[r], tmax[r]);
                corr[r] = __builtin_amdgcn_exp2f(mrow[r] - mnew);
                mrow[r] = mnew;
                lsum[r] *= corr[r];
            }
#pragma unroll
            for (int n2 = 0; n2 < 4; n2++) {
                f32x4 t4 = o[n2];
#pragma unroll
                for (int r = 0; r < 4; r++) t4[r] *= corr[r];
                o[n2] = t4;
            }
        }
        float rsum[4] = {0.f, 0.f, 0.f, 0.f};
#pragma unroll
        for (int n = 0; n < 8; n++)
#pragma unroll
            for (int r = 0; r < 4; r++) {
                float p = __builtin_amdgcn_exp2f(s[n][r] - mrow[r]);
                s[n][r] = p;
                rsum[r] += p;
            }
#pragma unroll
        for (int r = 0; r < 4; r++) {
#pragma unroll
            for (int d = 1; d < 16; d <<= 1) rsum[r] += __shfl_xor(rsum[r], d, 64);
            lsum[r] += rsum[r];
        }
        // P -> LDS (per-wave region), swizzled write
        u16* Pw = sP + w * (16 * KVB);
#pragma unroll
        for (int n = 0; n < 8; n++) {
            int pc = n * 2 + (lr >> 3), p7 = lr & 7;
#pragma unroll
            for (int r = 0; r < 4; r++) {
                int q = 4 * lg + r;
                Pw[q * KVB + (pc ^ q) * 8 + p7] = f2b(s[n][r]);
            }
        }
        // PV: 4 k-steps of 32 keys
        bf16x8 pa[4];
#pragma unroll
        for (int st = 0; st < 4; st++)
            pa[st] = *reinterpret_cast<const bf16x8*>(Pw + lr * KVB + ((st * 4 + lg) ^ lr) * 8);
#pragma unroll
        for (int n2 = 0; n2 < 4; n2++) {
            int row = n2 * 16 + lr, r15 = row & 15;
            f32x4 t4 = o[n2];
#pragma unroll
            for (int st = 0; st < 4; st++) {
                bf16x8 vb = *reinterpret_cast<const bf16x8*>(sV + row * KVB + ((st * 4 + lg) ^ r15) * 8);
                t4 = __builtin_amdgcn_mfma_f32_16x16x32_bf16(pa[st], vb, t4, 0, 0, 0);
            }
            o[n2] = t4;
        }
        __syncthreads();
    }
    // epilogue: normalize, U-gate, store bf16
#pragma unroll
    for (int n2 = 0; n2 < 4; n2++) {
#pragma unroll
        for (int r = 0; r < 4; r++) {
            int ig = qbase + w * 16 + 4 * lg + r;
            long orow = (long)(b * L_ + ig);
            int j = n2 * 16 + lr;
            float u = b2f(cat[orow * 4096 + 3072 + h * 64 + j]);
            float val = o[n2][r] / lsum[r] * u;
            AG[orow * 1024 + h * 64 + j] = f2b(val);
        }
    }
}

// ---------------------------------------------------------------- layernorm (per token)
// NP partials are added into ha (fused split-K reduce).
template <bool WB, int NP>
__global__ __launch_bounds__(256)
void k_ln(const float* __restrict__ xa, const float* __restrict__ ha,
          const float* __restrict__ p1, const float* __restrict__ p2,
          const float* __restrict__ p3,
          const float* __restrict__ g, const float* __restrict__ bb,
          const int* __restrict__ types,
          float* __restrict__ of, u16* __restrict__ ob)
{
    const int tok = blockIdx.x, tid = threadIdx.x;
    const long base = (long)tok * D_;
    float4 va = reinterpret_cast<const float4*>(xa + base)[tid];
    float4 vh = reinterpret_cast<const float4*>(ha + base)[tid];
    if (NP >= 2) {
        float4 a = reinterpret_cast<const float4*>(p1 + base)[tid];
        float4 c = reinterpret_cast<const float4*>(p2 + base)[tid];
        vh.x += a.x + c.x; vh.y += a.y + c.y; vh.z += a.z + c.z; vh.w += a.w + c.w;
    }
    if (NP >= 3) {
        float4 a = reinterpret_cast<const float4*>(p3 + base)[tid];
        vh.x += a.x; vh.y += a.y; vh.z += a.z; vh.w += a.w;
    }
    float v0 = va.x + vh.x, v1 = va.y + vh.y, v2 = va.z + vh.z, v3 = va.w + vh.w;
    float s = v0 + v1 + v2 + v3;
    float ss = v0 * v0 + v1 * v1 + v2 * v2 + v3 * v3;
#pragma unroll
    for (int d = 1; d < 64; d <<= 1) { s += __shfl_xor(s, d, 64); ss += __shfl_xor(ss, d, 64); }
    __shared__ float red[8];
    if ((tid & 63) == 0) { red[tid >> 6] = s; red[4 + (tid >> 6)] = ss; }
    __syncthreads();
    s  = red[0] + red[1] + red[2] + red[3];
    ss = red[4] + red[5] + red[6] + red[7];
    const float mu  = s * (1.f / D_);
    const float var = ss * (1.f / D_) - mu * mu;
    const float inv = rsqrtf(var + 1e-5f);
    const int t = types[tok];
    const float* gp = g + (long)t * D_ + tid * 4;
    const float* bp = bb + (long)t * D_ + tid * 4;
    float o0 = (v0 - mu) * inv * gp[0] + bp[0];
    float o1 = (v1 - mu) * inv * gp[1] + bp[1];
    float o2 = (v2 - mu) * inv * gp[2] + bp[2];
    float o3 = (v3 - mu) * inv * gp[3] + bp[3];
    reinterpret_cast<float4*>(of + base)[tid] = make_float4(o0, o1, o2, o3);
    if (WB) {
        ushort4 u4;
        u4.x = f2b(o0); u4.y = f2b(o1); u4.z = f2b(o2); u4.w = f2b(o3);
        reinterpret_cast<ushort4*>(ob + base)[tid] = u4;
    }
}

// ---------------------------------------------------------------- token-type bucketing
__global__ void k_count(const int* __restrict__ types, int* __restrict__ cnt) {
    int i = blockIdx.x * 256 + threadIdx.x;
    if (i < NTOK) atomicAdd(&cnt[types[i]], 1);
}
// PADDED scan: each group's offset is a multiple of 256 so GEMM M-tiles never
// straddle groups. base: cnt[4], off[4], cur[4]
__global__ void k_scan(int* __restrict__ base) {
    if (threadIdx.x == 0) {
        int a = 0;
        for (int t = 0; t < T_; t++) {
            base[4 + t] = a;
            base[8 + t] = a;
            a += ((base[t] + 255) >> 8) << 8;
        }
    }
}
__global__ void k_fill(const int* __restrict__ types, int* __restrict__ cur, int* __restrict__ idxb) {
    int i = blockIdx.x * 256 + threadIdx.x;
    if (i < NTOK) {
        int p = atomicAdd(&cur[types[i]], 1);
        idxb[p] = i;
    }
}

// ---------------------------------------------------------------- launch
extern "C" void kernel_launch(void* const* d_in, const int* in_sizes, int n_in,
                              void* d_out, int out_size, void* d_ws, size_t ws_size,
                              hipStream_t stream) {
    const float* x    = (const float*)d_in[0];
    const int* types  = (const int*)d_in[1];
    const int* seql   = (const int*)d_in[2];
    const float* Wq   = (const float*)d_in[3];
    const float* Wk   = (const float*)d_in[4];
    const float* Wv   = (const float*)d_in[5];
    const float* Wu   = (const float*)d_in[6];
    const float* Wo   = (const float*)d_in[7];
    const float* ln1g = (const float*)d_in[8];
    const float* ln1b = (const float*)d_in[9];
    const float* W1   = (const float*)d_in[10];
    const float* b1   = (const float*)d_in[11];
    const float* W2   = (const float*)d_in[12];
    const float* b2   = (const float*)d_in[13];
    const float* ln2g = (const float*)d_in[14];
    const float* ln2b = (const float*)d_in[15];

    char* ws = (char*)d_ws;
    constexpr size_t OFF_WT  = 0;
    constexpr size_t OFF_WOT = OFF_WT  + (size_t)4096 * 1024 * 2;
    constexpr size_t OFF_W1T = OFF_WOT + (size_t)1024 * 1024 * 2;      // reused: FFN2 split-K partials (2x16MB = 32MB, fits exactly)
    constexpr size_t OFF_W2T = OFF_W1T + (size_t)T_ * 4096 * 1024 * 2;
    constexpr size_t OFF_XB  = OFF_W2T + (size_t)T_ * 4096 * 1024 * 2; // x bf16 (later: AG)
    constexpr size_t OFF_CAT = OFF_XB  + (size_t)NTOK * D_ * 2;        // QKVU cat (later: Wo partials, FFN hidden)
    constexpr size_t OFF_H   = OFF_CAT + (size_t)NTOK * 4096 * 2;      // VT (QKVU->attn), then h f32
    constexpr size_t OFF_X1  = OFF_H   + (size_t)NTOK * D_ * 4;
    constexpr size_t OFF_X1B = OFF_X1  + (size_t)NTOK * D_ * 4;
    constexpr size_t OFF_INT = OFF_X1B + (size_t)NTOK * D_ * 2;

    u16* WT   = (u16*)(ws + OFF_WT);
    u16* WOT  = (u16*)(ws + OFF_WOT);
    u16* W1T  = (u16*)(ws + OFF_W1T);
    u16* W2T  = (u16*)(ws + OFF_W2T);
    u16* XB   = (u16*)(ws + OFF_XB);      // also AG
    u16* CAT  = (u16*)(ws + OFF_CAT);     // also Wo partials / Hidden
    float* Hb = (float*)(ws + OFF_H);
    u16* VT   = (u16*)(ws + OFF_H);       // VT aliases Hb: live QKVU->attn, Hb written after
    float* X1 = (float*)(ws + OFF_X1);
    u16* X1B  = (u16*)(ws + OFF_X1B);
    float* PkF = (float*)(ws + OFF_W1T);  // FFN2 split-K partials (2x16MB, aliases W1T -- KS=3 ONLY; KS=4 would overflow into W2T (round-9 NaN))
    float* PkW = (float*)(ws + OFF_CAT);  // Wo split-K partials (2x, aliases CAT)
    int* ibase = (int*)(ws + OFF_INT);
    int* cnt = ibase, *off = ibase + 4, *cur = ibase + 8, *idxb = ibase + 16;

    dim3 blk(256), blk512(512), tb(32, 8);
    const long PSTR = (long)NTOK * D_;
    // padded M-tile count upper bound: 4096 + 4*255 rounded up -> 20 tiles
    const int MT_PAD = 20;

    // 1. casts / transposes
    k_cast_bf16<<<NTOK * D_ / 4 / 256, blk, 0, stream>>>(x, XB, NTOK * D_ / 4);
    k_tcast<<<dim3(32, 32, 1), tb, 0, stream>>>(Wq, WT + 0 * 1048576, 1024, 1024, 0, 0);
    k_tcast<<<dim3(32, 32, 1), tb, 0, stream>>>(Wk, WT + 1 * 1048576, 1024, 1024, 0, 0);
    k_tcast<<<dim3(32, 32, 1), tb, 0, stream>>>(Wv, WT + 2 * 1048576, 1024, 1024, 0, 0);
    k_tcast<<<dim3(32, 32, 1), tb, 0, stream>>>(Wu, WT + 3 * 1048576, 1024, 1024, 0, 0);
    k_tcast<<<dim3(32, 32, 1), tb, 0, stream>>>(Wo, WOT, 1024, 1024, 0, 0);
    k_tcast<<<dim3(128, 32, T_), tb, 0, stream>>>(W1, W1T, 1024, 4096, (long)1024 * 4096, (long)4096 * 1024);
    k_tcast<<<dim3(32, 128, T_), tb, 0, stream>>>(W2, W2T, 4096, 1024, (long)4096 * 1024, (long)1024 * 4096);

    // 2. QKVU = x @ [Wq|Wk|Wv|Wu]; V-column blocks write transposed VT
    k_g2<EP_BF16, false, false, false, 1, true><<<dim3(16, 16), blk512, 0, stream>>>(
        XB, WT, CAT, nullptr, 0, VT, nullptr, nullptr, nullptr, nullptr,
        NTOK, 1024, 1024, 1024, 4096, 0, 0);

    // 3. attention -> gated output AG (reuses XB)
    k_attn<<<dim3(L_ / 64, H_, B_), blk, 0, stream>>>(CAT, VT, types, seql, XB);

    // 4. h = AG @ Wo (split-K=3; partials in CAT; P0 overwrites Hb/VT -- attn done)
    k_g2<EP_F32, false, false, false, 3, false><<<dim3(16, 4, 3), blk512, 0, stream>>>(
        XB, WOT, Hb, PkW, PSTR, nullptr, nullptr, nullptr, nullptr, nullptr,
        NTOK, 1024, 1024, 1024, 1024, 0, 0);

    // 5. x1 = LN1(x + h) with fused split-K reduce (2 partials)
    k_ln<true, 2><<<NTOK, blk, 0, stream>>>(x, Hb, PkW, PkW + PSTR, nullptr,
                                            ln1g, ln1b, types, X1, X1B);

    // 6. bucket tokens by type (PADDED offsets: multiples of 256)
    hipMemsetAsync(cnt, 0, 48, stream);
    k_count<<<NTOK / 256, blk, 0, stream>>>(types, cnt);
    k_scan<<<1, 64, 0, stream>>>(ibase);
    k_fill<<<NTOK / 256, blk, 0, stream>>>(types, cur, idxb);

    // 7. Hidden = gelu(x1[idx] @ W1[t] + b1[t])  (grouped; global padded M-tiles, no dead blocks)
    k_g2<EP_GELU_BF16, true, false, true, 1, false><<<dim3(MT_PAD, 16), blk512, 0, stream>>>(
        X1B, W1T, CAT, nullptr, 0, nullptr, b1, idxb, off, cnt,
        NTOK, 1024, 1024, 1024, 4096, (long)4096 * 1024, 4096);

    // 8. h2 = Hidden @ W2[t] + b2[t]  (grouped, C scattered, split-K=3)
    k_g2<EP_BIAS_F32, false, true, true, 3, false><<<dim3(MT_PAD, 4, 3), blk512, 0, stream>>>(
        CAT, W2T, Hb, PkF, PSTR, nullptr, b2, idxb, off, cnt,
        NTOK, 4096, 4096, 4096, 1024, (long)1024 * 4096, 1024);

    // 9. out = LN2(x1 + h2) with fused split-K reduce (2 partials)
    k_ln<false, 2><<<NTOK, blk, 0, stream>>>(X1, Hb, PkF, PkF + PSTR, nullptr,
                                             ln2g, ln2b, types, (float*)d_out, nullptr);
}